// Round 6
// baseline (323.759 us; speedup 1.0000x reference)
//
#include <hip/hip_runtime.h>
#include <hip/hip_bf16.h>

// EncoderLayer on MI355X (gfx950).
// B=2, S=2048, D=1024, H=16, DK=64. M = B*S = 4096.
// R6: attention -> 8 waves / 512 threads / 256 q-rows per block (m214 8-warp
//     structure): staging + barrier cost amortized 2x; grid (bh=32, qblk=8) so
//     a head's q-blocks share wgid%8 -> same XCD -> K/V L2-resident.
//     FF2 sl=0 slice folds bias2+residual (EPI=5); reduce = p0+p1 overwrite.

using bf16 = __hip_bfloat16;
typedef __attribute__((ext_vector_type(4))) float f32x4;
typedef __attribute__((ext_vector_type(16))) float f32x16;
typedef __attribute__((ext_vector_type(8))) short bf16x8;

#define DEVI static __device__ __forceinline__

DEVI void async_copy16(const void* g, void* l) {
  __builtin_amdgcn_global_load_lds(
      (const __attribute__((address_space(1))) void*)g,
      (__attribute__((address_space(3))) void*)l, 16, 0, 0);
}

DEVI ushort f2bf_bits(float v) {
  __hip_bfloat16 h = __float2bfloat16(v);
  return *reinterpret_cast<ushort*>(&h);
}

DEVI float bfbits2f(ushort u) {
  union { float f; unsigned int i; } x;
  x.i = ((unsigned int)u) << 16;
  return x.f;
}

DEVI unsigned int pk2(float lo, float hi) {
  return (unsigned int)f2bf_bits(lo) | ((unsigned int)f2bf_bits(hi) << 16);
}

// ---------------- LayerNorm: f32 in (rows x 1024) -> bf16 out ----------------
__global__ __launch_bounds__(256) void ln_kernel(
    const float* __restrict__ in, const float* __restrict__ gamma,
    const float* __restrict__ beta, bf16* __restrict__ out) {
  const long row = blockIdx.x;
  const int t = threadIdx.x;
  float4 x = ((const float4*)(in + row * 1024))[t];
  float s = x.x + x.y + x.z + x.w;
  float s2 = x.x * x.x + x.y * x.y + x.z * x.z + x.w * x.w;
#pragma unroll
  for (int m = 1; m < 64; m <<= 1) {
    s += __shfl_xor(s, m);
    s2 += __shfl_xor(s2, m);
  }
  __shared__ float red[8];
  const int w = t >> 6, l = t & 63;
  if (l == 0) { red[w] = s; red[4 + w] = s2; }
  __syncthreads();
  s = red[0] + red[1] + red[2] + red[3];
  s2 = red[4] + red[5] + red[6] + red[7];
  const float mean = s * (1.0f / 1024.0f);
  const float var = s2 * (1.0f / 1024.0f) - mean * mean;
  const float rstd = rsqrtf(var + 1e-6f);
  float4 g4 = ((const float4*)gamma)[t];
  float4 b4 = ((const float4*)beta)[t];
  union { ushort h[4]; uint2 u; } o;
  o.h[0] = f2bf_bits(g4.x * (x.x - mean) * rstd + b4.x);
  o.h[1] = f2bf_bits(g4.y * (x.y - mean) * rstd + b4.y);
  o.h[2] = f2bf_bits(g4.z * (x.z - mean) * rstd + b4.z);
  o.h[3] = f2bf_bits(g4.w * (x.w - mean) * rstd + b4.w);
  ((uint2*)(out + row * 1024))[t] = o.u;
}

// ------------- transpose f32 (K x N) -> bf16 (N x K), 32x32 tiles -------------
__global__ __launch_bounds__(256) void transpose_to_bf16(
    const float* __restrict__ W, bf16* __restrict__ Wt, const int K, const int N) {
  __shared__ float tile[32][33];
  const int tx = threadIdx.x & 31, ty = threadIdx.x >> 5;
  const int n0 = blockIdx.x << 5, k0 = blockIdx.y << 5;
#pragma unroll
  for (int i = 0; i < 32; i += 8)
    tile[ty + i][tx] = W[(long)(k0 + ty + i) * N + n0 + tx];
  __syncthreads();
#pragma unroll
  for (int i = 0; i < 32; i += 8)
    Wt[(long)(n0 + ty + i) * K + k0 + tx] = __float2bfloat16(tile[tx][ty + i]);
}

// merged Q/K/V/O weight transpose (all 1024x1024), z selects source.
__global__ __launch_bounds__(256) void transpose_qkvo(
    const float* __restrict__ q, const float* __restrict__ k,
    const float* __restrict__ v, const float* __restrict__ o,
    bf16* __restrict__ dst) {
  const float* W = (blockIdx.z == 0) ? q : (blockIdx.z == 1) ? k
                   : (blockIdx.z == 2) ? v : o;
  bf16* Wt = dst + (size_t)blockIdx.z * 1024 * 1024;
  __shared__ float tile[32][33];
  const int tx = threadIdx.x & 31, ty = threadIdx.x >> 5;
  const int n0 = blockIdx.x << 5, k0 = blockIdx.y << 5;
#pragma unroll
  for (int i = 0; i < 32; i += 8)
    tile[ty + i][tx] = W[(long)(k0 + ty + i) * 1024 + n0 + tx];
  __syncthreads();
#pragma unroll
  for (int i = 0; i < 32; i += 8)
    Wt[(long)(n0 + ty + i) * 1024 + k0 + tx] = __float2bfloat16(tile[tx][ty + i]);
}

// ---------------- GEMM: C(MxN) = A(MxK,bf16) * Bt(NxK,bf16)^T ----------------
// 128x128 tile, BK=32, 4 waves, global_load_lds staging (m97 structure),
// XCD-aware bijective blockIdx swizzle. lda/ldb = row strides.
// KSPLIT=2: slice sl reads K-cols [sl*K,(sl+1)*K); sl0 -> Cout, sl1 -> pother.
// EPI: 0 = bf16; 1 = +res(f32) f32; 2 = +bias exact-GELU bf16;
//      4 = raw f32 partial; 5 = split-K partial, sl0 adds bias+res.
template <int EPI, int KSPLIT>
__global__ __launch_bounds__(256) void gemm_bt(
    const bf16* __restrict__ A, const bf16* __restrict__ Bt,
    const int M, const int N, const int K, const int lda, const int ldb,
    const float* __restrict__ bias, const float* __restrict__ res,
    float* __restrict__ pother, void* __restrict__ Cout) {
  __shared__ bf16 As[128 * 32];
  __shared__ bf16 Bs[128 * 32];
  const int t = threadIdx.x;
  const int w = t >> 6, l = t & 63;
  const int nb = N >> 7;
  const int cpx = gridDim.x >> 3;
  int bidx = (blockIdx.x & 7) * cpx + (blockIdx.x >> 3);
  int sl = 0;
  if (KSPLIT == 2) {
    const int half = gridDim.x >> 1;
    sl = bidx >= half;
    bidx -= sl * half;
  }
  const int bm = bidx / nb, bn = bidx % nb;
  const long row0 = (long)bm << 7, col0 = (long)bn << 7;
  const int wr = (w >> 1) << 6, wc = (w & 1) << 6;
  const int lr = l & 15, lk = (l >> 4) << 3;

  f32x4 acc[4][4];
#pragma unroll
  for (int m = 0; m < 4; ++m)
#pragma unroll
    for (int n = 0; n < 4; ++n) acc[m][n] = (f32x4){0.f, 0.f, 0.f, 0.f};

  const bf16* gA = A + (row0 + (t >> 2)) * (long)lda + (long)sl * K + ((t & 3) << 3);
  const bf16* gB = Bt + (col0 + (t >> 2)) * (long)ldb + (long)sl * K + ((t & 3) << 3);
  char* lA = (char*)As + (w << 10);
  char* lB = (char*)Bs + (w << 10);
  const long k64a = (long)64 * lda, k64b = (long)64 * ldb;

  for (int k0 = 0; k0 < K; k0 += 32) {
    __syncthreads();
    async_copy16(gA + k0, lA);
    async_copy16(gA + k64a + k0, lA + 4096);
    async_copy16(gB + k0, lB);
    async_copy16(gB + k64b + k0, lB + 4096);
    __syncthreads();
    bf16x8 af[4], bfr[4];
#pragma unroll
    for (int m = 0; m < 4; ++m)
      af[m] = *(const bf16x8*)&As[(wr + m * 16 + lr) * 32 + lk];
#pragma unroll
    for (int n = 0; n < 4; ++n)
      bfr[n] = *(const bf16x8*)&Bs[(wc + n * 16 + lr) * 32 + lk];
#pragma unroll
    for (int m = 0; m < 4; ++m)
#pragma unroll
      for (int n = 0; n < 4; ++n)
        acc[m][n] = __builtin_amdgcn_mfma_f32_16x16x32_bf16(af[m], bfr[n], acc[m][n], 0, 0, 0);
  }

  bf16* Cb = (bf16*)Cout;
  float* Cf = (float*)Cout;
  if ((EPI == 4 || EPI == 5) && sl == 1) Cf = pother;
#pragma unroll
  for (int m = 0; m < 4; ++m) {
#pragma unroll
    for (int r = 0; r < 4; ++r) {
      const long crow = row0 + wr + m * 16 + ((l >> 4) << 2) + r;
      const long rbase = crow * N;
#pragma unroll
      for (int n = 0; n < 4; ++n) {
        const long ccol = col0 + wc + n * 16 + lr;
        float v = acc[m][n][r];
        if (EPI == 2) {
          v += bias[ccol];
          v = 0.5f * v * (1.0f + erff(v * 0.70710678118654752f));
        }
        if (EPI == 1) v += res[rbase + ccol];
        if (EPI == 5 && sl == 0) v += bias[ccol] + res[rbase + ccol];
        if (EPI == 0 || EPI == 2)
          Cb[rbase + ccol] = __float2bfloat16(v);
        else
          Cf[rbase + ccol] = v;
      }
    }
  }
}

// ---- split-K reduce: out = p0 + p1 (p0 already holds bias+residual) ----
__global__ __launch_bounds__(256) void ff2_reduce(
    const float* __restrict__ p0, const float* __restrict__ p1,
    float* __restrict__ out) {
  const int idx = blockIdx.x * 256 + threadIdx.x;  // float4 index
  const float4 x = ((const float4*)p0)[idx];
  const float4 y = ((const float4*)p1)[idx];
  float4 a;
  a.x = x.x + y.x; a.y = x.y + y.y; a.z = x.z + y.z; a.w = x.w + y.w;
  ((float4*)out)[idx] = a;
}

// ---------------- flash attention: 8 waves, 256 q-rows/block ----------------
// Grid: x = B*H (32), y = S/256 (8)  -> all q-blocks of a head share wgid%8
// (same XCD -> K/V L2-resident). Wave w owns q rows [w*32, w*32+32).
// KVBLK=64, double-buffered, ONE barrier per tile. K staged via global_load_lds
// (pre-swizzled source); V staged global->reg->scatter (T14 split).
__global__ __launch_bounds__(512) void attn_kernel(
    const bf16* __restrict__ QKV, const int* __restrict__ pmask,
    bf16* __restrict__ Oout) {
  const int bh = blockIdx.x;
  const int b = bh >> 4, h = bh & 15;
  const int q0 = blockIdx.y << 8;  // 256 q rows per block
  const int t = threadIdx.x;
  const int w = t >> 6, l = t & 63;
  const int lq = l & 31, hi = l >> 5;

  __shared__ __align__(16) char smem[32768];  // [0,16K) K dbuf, [16K,32K) V dbuf

  const long base = (long)b * 2048 * 3072;
  const bf16* Qg = QKV + base + h * 64;
  const bf16* Kg = QKV + base + 1024 + h * 64;
  const bf16* Vg = QKV + base + 2048 + h * 64;

  // K: chunk c = w*64 + l -> row kr = w*8 + (l>>3), src col-group (l&7)^(kr&7).
  const int kr = w * 8 + (l >> 3);
  const int kSrc = kr * 3072 + (((l & 7) ^ (kr & 7)) << 3);
  // V: thread t loads row vr0, d = vsg*8..+8; scatters into Vt[d][k] swizzled.
  const int vr0 = t >> 3, vsg = t & 7;

  // Q fragments in registers, prescaled by 1/8 (exact).
  const int qw0 = q0 + w * 32;
  bf16x8 qf[4];
#pragma unroll
  for (int dc = 0; dc < 4; ++dc) {
    uint4 raw = *(const uint4*)(Qg + (long)(qw0 + lq) * 3072 + dc * 16 + hi * 8);
    union { uint4 u4; ushort us[8]; } in; in.u4 = raw;
    union { bf16x8 v; ushort us[8]; } o;
#pragma unroll
    for (int e = 0; e < 8; ++e) o.us[e] = f2bf_bits(0.125f * bfbits2f(in.us[e]));
    qf[dc] = o.v;
  }

  union { unsigned int u[4]; bf16x8 v; } bones;
  bones.u[0] = (hi == 0) ? 0x00003F80u : 0u;
  bones.u[1] = bones.u[2] = bones.u[3] = 0u;

  // prologue: stage tile 0
  uint4 vreg = *(const uint4*)(Vg + (long)vr0 * 3072 + vsg * 8);
  async_copy16(Kg + kSrc, smem + w * 1024);
  {
    const ushort* vs = (const ushort*)&vreg;
#pragma unroll
    for (int e = 0; e < 8; ++e) {
      const int d = vsg * 8 + e;
      *(ushort*)(smem + 16384 + d * 128 + ((vr0 * 2) ^ (((e ^ vsg) & 7) << 4))) = vs[e];
    }
  }

  f32x16 oacc[2];
#pragma unroll
  for (int nt = 0; nt < 2; ++nt)
#pragma unroll
    for (int r = 0; r < 16; ++r) oacc[nt][r] = 0.f;
  float mrun = -3.0e38f, lsum = 0.f;
  int cur = 0;

  __syncthreads();

  for (int ktg = 0; ktg < 32; ++ktg) {
    // issue next tile's loads early (T14): V->regs, K->LDS(other buf)
    if (ktg < 31) {
      const long nrow0 = (long)(ktg + 1) * 64 * 3072;
      vreg = *(const uint4*)(Vg + nrow0 + (long)vr0 * 3072 + vsg * 8);
      async_copy16(Kg + nrow0 + kSrc, smem + (cur ^ 1) * 8192 + w * 1024);
    }
    const int k0 = ktg << 6;
    const char* Ks = smem + cur * 8192;
    const char* Vt = smem + 16384 + cur * 8192;

    // S^T = K Q^T : lane holds S^T[k = kt*32 + crow(r,hi)][q = lq]
    f32x16 sacc[2];
#pragma unroll
    for (int kt = 0; kt < 2; ++kt) {
#pragma unroll
      for (int r = 0; r < 16; ++r) sacc[kt][r] = 0.f;
#pragma unroll
      for (int dc = 0; dc < 4; ++dc) {
        bf16x8 ka = *(const bf16x8*)(Ks +
            ((kt * 32 + lq) * 128 + ((dc * 32 + hi * 16) ^ ((lq & 7) << 4))));
        sacc[kt] = __builtin_amdgcn_mfma_f32_32x32x16_bf16(ka, qf[dc], sacc[kt], 0, 0, 0);
      }
      const int mv = pmask[b * 2048 + k0 + kt * 32 + lq];
      union { unsigned int u[4]; bf16x8 v; } aadd;
      aadd.u[0] = (hi == 0 && mv == 0) ? (unsigned int)f2bf_bits(-1.0e9f) : 0u;
      aadd.u[1] = aadd.u[2] = aadd.u[3] = 0u;
      sacc[kt] = __builtin_amdgcn_mfma_f32_32x32x16_bf16(aadd.v, bones.v, sacc[kt], 0, 0, 0);
    }

    // online softmax; lane pair (l, l^32) shares column lq
    float tmax = -3.0e38f;
#pragma unroll
    for (int kt = 0; kt < 2; ++kt)
#pragma unroll
      for (int r = 0; r < 16; ++r) tmax = fmaxf(tmax, sacc[kt][r]);
    tmax = fmaxf(tmax, __shfl_xor(tmax, 32));
    const bool need = (bool)__any(tmax > mrun);
    const float mnew = need ? fmaxf(mrun, tmax) : mrun;
    float psum = 0.f;
#pragma unroll
    for (int kt = 0; kt < 2; ++kt)
#pragma unroll
      for (int r = 0; r < 16; ++r) {
        const float p = __expf(sacc[kt][r] - mnew);
        sacc[kt][r] = p;
        psum += p;
      }
    psum += __shfl_xor(psum, 32);
    if (need) {
      const float alpha = __expf(mrun - mnew);
      mrun = mnew;
      lsum = lsum * alpha + psum;
#pragma unroll
      for (int r = 0; r < 16; ++r) {
        const float ar = __shfl(alpha, (r & 3) + 8 * (r >> 2) + 4 * hi);
        oacc[0][r] *= ar;
        oacc[1][r] *= ar;
      }
    } else {
      lsum += psum;
    }

    // P -> bf16 A-fragments via pack + lane^32 exchange
    union { unsigned int u[4]; bf16x8 v; } paE[2], paO[2];
#pragma unroll
    for (int kt = 0; kt < 2; ++kt) {
      const unsigned int cs0 = pk2(sacc[kt][0], sacc[kt][1]);
      const unsigned int cs1 = pk2(sacc[kt][2], sacc[kt][3]);
      const unsigned int cs2 = pk2(sacc[kt][4], sacc[kt][5]);
      const unsigned int cs3 = pk2(sacc[kt][6], sacc[kt][7]);
      const unsigned int cs4 = pk2(sacc[kt][8], sacc[kt][9]);
      const unsigned int cs5 = pk2(sacc[kt][10], sacc[kt][11]);
      const unsigned int cs6 = pk2(sacc[kt][12], sacc[kt][13]);
      const unsigned int cs7 = pk2(sacc[kt][14], sacc[kt][15]);
      const unsigned int es0 = __shfl_xor(cs0, 32);
      const unsigned int es1 = __shfl_xor(cs1, 32);
      const unsigned int es2 = __shfl_xor(cs2, 32);
      const unsigned int es3 = __shfl_xor(cs3, 32);
      const unsigned int es4 = __shfl_xor(cs4, 32);
      const unsigned int es5 = __shfl_xor(cs5, 32);
      const unsigned int es6 = __shfl_xor(cs6, 32);
      const unsigned int es7 = __shfl_xor(cs7, 32);
      paE[kt].u[0] = hi ? es2 : cs0;
      paE[kt].u[1] = hi ? es3 : cs1;
      paE[kt].u[2] = hi ? cs2 : es0;
      paE[kt].u[3] = hi ? cs3 : es1;
      paO[kt].u[0] = hi ? es6 : cs4;
      paO[kt].u[1] = hi ? es7 : cs5;
      paO[kt].u[2] = hi ? cs6 : es4;
      paO[kt].u[3] = hi ? cs7 : es5;
    }

    // O += P V
#pragma unroll
    for (int kt = 0; kt < 2; ++kt)
#pragma unroll
      for (int nt = 0; nt < 2; ++nt) {
        const int vrow = nt * 32 + lq;
        const int vsw = ((vrow & 7) ^ ((vrow >> 3) & 7)) << 4;
        bf16x8 vbE = *(const bf16x8*)(Vt + (vrow * 128 + ((kt * 64 + hi * 16) ^ vsw)));
        oacc[nt] = __builtin_amdgcn_mfma_f32_32x32x16_bf16(paE[kt].v, vbE, oacc[nt], 0, 0, 0);
        bf16x8 vbO = *(const bf16x8*)(Vt + (vrow * 128 + ((kt * 64 + 32 + hi * 16) ^ vsw)));
        oacc[nt] = __builtin_amdgcn_mfma_f32_32x32x16_bf16(paO[kt].v, vbO, oacc[nt], 0, 0, 0);
      }

    // late half of T14: scatter V-next regs into the other buffer
    if (ktg < 31) {
      char* VtN = smem + 16384 + (cur ^ 1) * 8192;
      const ushort* vs = (const ushort*)&vreg;
#pragma unroll
      for (int e = 0; e < 8; ++e) {
        const int d = vsg * 8 + e;
        *(ushort*)(VtN + d * 128 + ((vr0 * 2) ^ (((e ^ vsg) & 7) << 4))) = vs[e];
      }
    }

    __syncthreads();
    cur ^= 1;
  }

  const float inv = 1.0f / lsum;
#pragma unroll
  for (int r = 0; r < 16; ++r) {
    const int crow = (r & 3) + 8 * (r >> 2) + 4 * hi;
    const float ir = __shfl(inv, crow);
    const long orow = (long)b * 2048 + qw0 + crow;
#pragma unroll
    for (int nt = 0; nt < 2; ++nt)
      Oout[orow * 1024 + h * 64 + nt * 32 + lq] = __float2bfloat16(oacc[nt][r] * ir);
  }
}

extern "C" void kernel_launch(void* const* d_in, const int* in_sizes, int n_in,
                              void* d_out, int out_size, void* d_ws, size_t ws_size,
                              hipStream_t stream) {
  const float* X = (const float*)d_in[0];
  const int* pmask = (const int*)d_in[1];
  const float* W_Q = (const float*)d_in[2];
  const float* W_K = (const float*)d_in[3];
  const float* W_V = (const float*)d_in[4];
  const float* W_O = (const float*)d_in[5];
  const float* g1 = (const float*)d_in[6];
  const float* b1 = (const float*)d_in[7];
  const float* W1 = (const float*)d_in[8];
  const float* bias1 = (const float*)d_in[9];
  const float* W2 = (const float*)d_in[10];
  const float* bias2 = (const float*)d_in[11];
  const float* g2 = (const float*)d_in[12];
  const float* b2 = (const float*)d_in[13];
  (void)in_sizes; (void)n_in; (void)out_size; (void)ws_size;

  char* ws = (char*)d_ws;
  const size_t MB = 1ull << 20;
  // layout (80 MB):
  //   [0,8): W1_t (dead after FF1; p1 overlays [0,16) during FF2)
  //   [8,14): Wqkv_t  [14,16): Wo_t
  //   [16,24): W2_t
  //   [24,32): xn
  //   [32,56): QKV  [56,64): attnb;  ff1 (32MB) overlays [32,64) after attn
  //   [64,80): p0
  // post-attention residual lives in d_out (f32 4096x1024).
  bf16* W1_t   = (bf16*)(ws + 0);
  bf16* Wqkv_t = (bf16*)(ws + 8 * MB);
  bf16* Wo_t   = (bf16*)(ws + 14 * MB);
  bf16* W2_t   = (bf16*)(ws + 16 * MB);
  bf16* xn     = (bf16*)(ws + 24 * MB);
  bf16* QKV    = (bf16*)(ws + 32 * MB);
  bf16* attnb  = (bf16*)(ws + 56 * MB);
  bf16* ff1    = (bf16*)(ws + 32 * MB);
  float* p0    = (float*)(ws + 64 * MB);
  float* p1    = (float*)(ws + 0);
  float* res1  = (float*)d_out;

  transpose_qkvo<<<dim3(32, 32, 4), 256, 0, stream>>>(W_Q, W_K, W_V, W_O, Wqkv_t);
  transpose_to_bf16<<<dim3(128, 32), 256, 0, stream>>>(W1, W1_t, 1024, 4096);
  transpose_to_bf16<<<dim3(32, 128), 256, 0, stream>>>(W2, W2_t, 4096, 1024);

  ln_kernel<<<4096, 256, 0, stream>>>(X, g1, b1, xn);
  gemm_bt<0, 1><<<32 * 24, 256, 0, stream>>>(xn, Wqkv_t, 4096, 3072, 1024, 1024, 1024,
                                             nullptr, nullptr, nullptr, QKV);
  attn_kernel<<<dim3(32, 8), 512, 0, stream>>>(QKV, pmask, attnb);
  gemm_bt<1, 1><<<32 * 8, 256, 0, stream>>>(attnb, Wo_t, 4096, 1024, 1024, 1024, 1024,
                                            nullptr, X, nullptr, res1);
  ln_kernel<<<4096, 256, 0, stream>>>(res1, g2, b2, xn);
  gemm_bt<2, 1><<<32 * 32, 256, 0, stream>>>(xn, W1_t, 4096, 4096, 1024, 1024, 1024,
                                             bias1, nullptr, nullptr, ff1);
  gemm_bt<5, 2><<<2 * 32 * 8, 256, 0, stream>>>(ff1, W2_t, 4096, 1024, 2048, 4096, 4096,
                                                bias2, res1, p1, p0);
  ff2_reduce<<<4096, 256, 0, stream>>>(p0, p1, res1);
}

// Round 7
// 314.417 us; speedup vs baseline: 1.0297x; 1.0297x over previous
//
#include <hip/hip_runtime.h>
#include <hip/hip_bf16.h>

// EncoderLayer on MI355X (gfx950).
// B=2, S=2048, D=1024, H=16, DK=64. M = B*S = 4096.
// R7: attention KVBLK 64 -> 128 (barriers halved 32->16, prefetch window
//     doubled, per-tile fixed costs amortized). 8 waves / 256 q-rows per
//     block; grid (bh=32, qblk=8) keeps each head's K/V on one XCD's L2.
//     Everything else identical to R6 (proven paths).

using bf16 = __hip_bfloat16;
typedef __attribute__((ext_vector_type(4))) float f32x4;
typedef __attribute__((ext_vector_type(16))) float f32x16;
typedef __attribute__((ext_vector_type(8))) short bf16x8;

#define DEVI static __device__ __forceinline__

DEVI void async_copy16(const void* g, void* l) {
  __builtin_amdgcn_global_load_lds(
      (const __attribute__((address_space(1))) void*)g,
      (__attribute__((address_space(3))) void*)l, 16, 0, 0);
}

DEVI ushort f2bf_bits(float v) {
  __hip_bfloat16 h = __float2bfloat16(v);
  return *reinterpret_cast<ushort*>(&h);
}

DEVI float bfbits2f(ushort u) {
  union { float f; unsigned int i; } x;
  x.i = ((unsigned int)u) << 16;
  return x.f;
}

DEVI unsigned int pk2(float lo, float hi) {
  return (unsigned int)f2bf_bits(lo) | ((unsigned int)f2bf_bits(hi) << 16);
}

// ---------------- LayerNorm: f32 in (rows x 1024) -> bf16 out ----------------
__global__ __launch_bounds__(256) void ln_kernel(
    const float* __restrict__ in, const float* __restrict__ gamma,
    const float* __restrict__ beta, bf16* __restrict__ out) {
  const long row = blockIdx.x;
  const int t = threadIdx.x;
  float4 x = ((const float4*)(in + row * 1024))[t];
  float s = x.x + x.y + x.z + x.w;
  float s2 = x.x * x.x + x.y * x.y + x.z * x.z + x.w * x.w;
#pragma unroll
  for (int m = 1; m < 64; m <<= 1) {
    s += __shfl_xor(s, m);
    s2 += __shfl_xor(s2, m);
  }
  __shared__ float red[8];
  const int w = t >> 6, l = t & 63;
  if (l == 0) { red[w] = s; red[4 + w] = s2; }
  __syncthreads();
  s = red[0] + red[1] + red[2] + red[3];
  s2 = red[4] + red[5] + red[6] + red[7];
  const float mean = s * (1.0f / 1024.0f);
  const float var = s2 * (1.0f / 1024.0f) - mean * mean;
  const float rstd = rsqrtf(var + 1e-6f);
  float4 g4 = ((const float4*)gamma)[t];
  float4 b4 = ((const float4*)beta)[t];
  union { ushort h[4]; uint2 u; } o;
  o.h[0] = f2bf_bits(g4.x * (x.x - mean) * rstd + b4.x);
  o.h[1] = f2bf_bits(g4.y * (x.y - mean) * rstd + b4.y);
  o.h[2] = f2bf_bits(g4.z * (x.z - mean) * rstd + b4.z);
  o.h[3] = f2bf_bits(g4.w * (x.w - mean) * rstd + b4.w);
  ((uint2*)(out + row * 1024))[t] = o.u;
}

// ------------- transpose f32 (K x N) -> bf16 (N x K), 32x32 tiles -------------
__global__ __launch_bounds__(256) void transpose_to_bf16(
    const float* __restrict__ W, bf16* __restrict__ Wt, const int K, const int N) {
  __shared__ float tile[32][33];
  const int tx = threadIdx.x & 31, ty = threadIdx.x >> 5;
  const int n0 = blockIdx.x << 5, k0 = blockIdx.y << 5;
#pragma unroll
  for (int i = 0; i < 32; i += 8)
    tile[ty + i][tx] = W[(long)(k0 + ty + i) * N + n0 + tx];
  __syncthreads();
#pragma unroll
  for (int i = 0; i < 32; i += 8)
    Wt[(long)(n0 + ty + i) * K + k0 + tx] = __float2bfloat16(tile[tx][ty + i]);
}

// merged Q/K/V/O weight transpose (all 1024x1024), z selects source.
__global__ __launch_bounds__(256) void transpose_qkvo(
    const float* __restrict__ q, const float* __restrict__ k,
    const float* __restrict__ v, const float* __restrict__ o,
    bf16* __restrict__ dst) {
  const float* W = (blockIdx.z == 0) ? q : (blockIdx.z == 1) ? k
                   : (blockIdx.z == 2) ? v : o;
  bf16* Wt = dst + (size_t)blockIdx.z * 1024 * 1024;
  __shared__ float tile[32][33];
  const int tx = threadIdx.x & 31, ty = threadIdx.x >> 5;
  const int n0 = blockIdx.x << 5, k0 = blockIdx.y << 5;
#pragma unroll
  for (int i = 0; i < 32; i += 8)
    tile[ty + i][tx] = W[(long)(k0 + ty + i) * 1024 + n0 + tx];
  __syncthreads();
#pragma unroll
  for (int i = 0; i < 32; i += 8)
    Wt[(long)(n0 + ty + i) * 1024 + k0 + tx] = __float2bfloat16(tile[tx][ty + i]);
}

// ---------------- GEMM: C(MxN) = A(MxK,bf16) * Bt(NxK,bf16)^T ----------------
// 128x128 tile, BK=32, 4 waves, global_load_lds staging (m97 structure),
// XCD-aware bijective blockIdx swizzle. lda/ldb = row strides.
// KSPLIT=2: slice sl reads K-cols [sl*K,(sl+1)*K); sl0 -> Cout, sl1 -> pother.
// EPI: 0 = bf16; 1 = +res(f32) f32; 2 = +bias exact-GELU bf16;
//      4 = raw f32 partial; 5 = split-K partial, sl0 adds bias+res.
template <int EPI, int KSPLIT>
__global__ __launch_bounds__(256) void gemm_bt(
    const bf16* __restrict__ A, const bf16* __restrict__ Bt,
    const int M, const int N, const int K, const int lda, const int ldb,
    const float* __restrict__ bias, const float* __restrict__ res,
    float* __restrict__ pother, void* __restrict__ Cout) {
  __shared__ bf16 As[128 * 32];
  __shared__ bf16 Bs[128 * 32];
  const int t = threadIdx.x;
  const int w = t >> 6, l = t & 63;
  const int nb = N >> 7;
  const int cpx = gridDim.x >> 3;
  int bidx = (blockIdx.x & 7) * cpx + (blockIdx.x >> 3);
  int sl = 0;
  if (KSPLIT == 2) {
    const int half = gridDim.x >> 1;
    sl = bidx >= half;
    bidx -= sl * half;
  }
  const int bm = bidx / nb, bn = bidx % nb;
  const long row0 = (long)bm << 7, col0 = (long)bn << 7;
  const int wr = (w >> 1) << 6, wc = (w & 1) << 6;
  const int lr = l & 15, lk = (l >> 4) << 3;

  f32x4 acc[4][4];
#pragma unroll
  for (int m = 0; m < 4; ++m)
#pragma unroll
    for (int n = 0; n < 4; ++n) acc[m][n] = (f32x4){0.f, 0.f, 0.f, 0.f};

  const bf16* gA = A + (row0 + (t >> 2)) * (long)lda + (long)sl * K + ((t & 3) << 3);
  const bf16* gB = Bt + (col0 + (t >> 2)) * (long)ldb + (long)sl * K + ((t & 3) << 3);
  char* lA = (char*)As + (w << 10);
  char* lB = (char*)Bs + (w << 10);
  const long k64a = (long)64 * lda, k64b = (long)64 * ldb;

  for (int k0 = 0; k0 < K; k0 += 32) {
    __syncthreads();
    async_copy16(gA + k0, lA);
    async_copy16(gA + k64a + k0, lA + 4096);
    async_copy16(gB + k0, lB);
    async_copy16(gB + k64b + k0, lB + 4096);
    __syncthreads();
    bf16x8 af[4], bfr[4];
#pragma unroll
    for (int m = 0; m < 4; ++m)
      af[m] = *(const bf16x8*)&As[(wr + m * 16 + lr) * 32 + lk];
#pragma unroll
    for (int n = 0; n < 4; ++n)
      bfr[n] = *(const bf16x8*)&Bs[(wc + n * 16 + lr) * 32 + lk];
#pragma unroll
    for (int m = 0; m < 4; ++m)
#pragma unroll
      for (int n = 0; n < 4; ++n)
        acc[m][n] = __builtin_amdgcn_mfma_f32_16x16x32_bf16(af[m], bfr[n], acc[m][n], 0, 0, 0);
  }

  bf16* Cb = (bf16*)Cout;
  float* Cf = (float*)Cout;
  if ((EPI == 4 || EPI == 5) && sl == 1) Cf = pother;
#pragma unroll
  for (int m = 0; m < 4; ++m) {
#pragma unroll
    for (int r = 0; r < 4; ++r) {
      const long crow = row0 + wr + m * 16 + ((l >> 4) << 2) + r;
      const long rbase = crow * N;
#pragma unroll
      for (int n = 0; n < 4; ++n) {
        const long ccol = col0 + wc + n * 16 + lr;
        float v = acc[m][n][r];
        if (EPI == 2) {
          v += bias[ccol];
          v = 0.5f * v * (1.0f + erff(v * 0.70710678118654752f));
        }
        if (EPI == 1) v += res[rbase + ccol];
        if (EPI == 5 && sl == 0) v += bias[ccol] + res[rbase + ccol];
        if (EPI == 0 || EPI == 2)
          Cb[rbase + ccol] = __float2bfloat16(v);
        else
          Cf[rbase + ccol] = v;
      }
    }
  }
}

// ---- split-K reduce: out = p0 + p1 (p0 already holds bias+residual) ----
__global__ __launch_bounds__(256) void ff2_reduce(
    const float* __restrict__ p0, const float* __restrict__ p1,
    float* __restrict__ out) {
  const int idx = blockIdx.x * 256 + threadIdx.x;
  const float4 x = ((const float4*)p0)[idx];
  const float4 y = ((const float4*)p1)[idx];
  float4 a;
  a.x = x.x + y.x; a.y = x.y + y.y; a.z = x.z + y.z; a.w = x.w + y.w;
  ((float4*)out)[idx] = a;
}

// ---------------- flash attention: 8 waves, 256 q-rows, KVBLK=128 ------------
// Grid: x = B*H (32), y = S/256 (8). Wave w owns q rows [w*32, w*32+32).
// Double-buffered, ONE barrier per 128-kv tile (16 tiles total).
// LDS: [0,32K) K dbuf (2x16KB, row-major 128B rows, chunk-swizzled source),
//      [32K,64K) V^T dbuf (2x16KB, [d][k] 256B rows, XOR-swizzled scatter).
__global__ __launch_bounds__(512) void attn_kernel(
    const bf16* __restrict__ QKV, const int* __restrict__ pmask,
    bf16* __restrict__ Oout) {
  const int bh = blockIdx.x;
  const int b = bh >> 4, h = bh & 15;
  const int q0 = blockIdx.y << 8;
  const int t = threadIdx.x;
  const int w = t >> 6, l = t & 63;
  const int lq = l & 31, hi = l >> 5;

  __shared__ __align__(16) char smem[65536];

  const long base = (long)b * 2048 * 3072;
  const bf16* Qg = QKV + base + h * 64;
  const bf16* Kg = QKV + base + 1024 + h * 64;
  const bf16* Vg = QKV + base + 2048 + h * 64;

  // K: chunk c = p*512 + t -> row kr = c>>3 (0..127), src col-group (c&7)^(kr&7).
  // V: chunk c = p*512 + t -> k-row vk = c>>3 (0..127), col-group vsg = c&7.
  int kSrc[2], kDst[2], vk[2], vsg[2];
#pragma unroll
  for (int p = 0; p < 2; ++p) {
    const int c = p * 512 + t;
    const int kr = c >> 3;
    kSrc[p] = kr * 3072 + (((c & 7) ^ (kr & 7)) << 3);
    kDst[p] = c * 16;
    vk[p] = c >> 3;
    vsg[p] = c & 7;
  }

  // Q fragments in registers, prescaled by 1/8 (exact).
  const int qw0 = q0 + w * 32;
  bf16x8 qf[4];
#pragma unroll
  for (int dc = 0; dc < 4; ++dc) {
    uint4 raw = *(const uint4*)(Qg + (long)(qw0 + lq) * 3072 + dc * 16 + hi * 8);
    union { uint4 u4; ushort us[8]; } in; in.u4 = raw;
    union { bf16x8 v; ushort us[8]; } o;
#pragma unroll
    for (int e = 0; e < 8; ++e) o.us[e] = f2bf_bits(0.125f * bfbits2f(in.us[e]));
    qf[dc] = o.v;
  }

  union { unsigned int u[4]; bf16x8 v; } bones;
  bones.u[0] = (hi == 0) ? 0x00003F80u : 0u;
  bones.u[1] = bones.u[2] = bones.u[3] = 0u;

  // prologue: stage tile 0 (K async, V via reg scatter)
  uint4 vreg[2];
#pragma unroll
  for (int p = 0; p < 2; ++p) {
    vreg[p] = *(const uint4*)(Vg + (long)vk[p] * 3072 + vsg[p] * 8);
    async_copy16(Kg + kSrc[p], smem + kDst[p]);
  }
#pragma unroll
  for (int p = 0; p < 2; ++p) {
    const ushort* vs = (const ushort*)&vreg[p];
#pragma unroll
    for (int e = 0; e < 8; ++e) {
      const int d = vsg[p] * 8 + e;
      *(ushort*)(smem + 32768 + d * 256 +
                 ((vk[p] * 2) ^ (((e ^ vsg[p]) & 7) << 4))) = vs[e];
    }
  }

  f32x16 oacc[2];
#pragma unroll
  for (int nt = 0; nt < 2; ++nt)
#pragma unroll
    for (int r = 0; r < 16; ++r) oacc[nt][r] = 0.f;
  float mrun = -3.0e38f, lsum = 0.f;
  int cur = 0;

  __syncthreads();

  for (int ktg = 0; ktg < 16; ++ktg) {
    // issue next tile's loads early: V->regs, K->LDS(other buf)
    if (ktg < 15) {
      const long nrow0 = (long)(ktg + 1) * 128 * 3072;
#pragma unroll
      for (int p = 0; p < 2; ++p) {
        vreg[p] = *(const uint4*)(Vg + nrow0 + (long)vk[p] * 3072 + vsg[p] * 8);
        async_copy16(Kg + nrow0 + kSrc[p], smem + (cur ^ 1) * 16384 + kDst[p]);
      }
    }
    const int k0 = ktg << 7;
    const char* Ks = smem + cur * 16384;
    const char* Vt = smem + 32768 + cur * 16384;

    // S^T = K Q^T : lane holds S^T[k = kt*32 + crow(r,hi)][q = lq], kt 0..3
    f32x16 sacc[4];
#pragma unroll
    for (int kt = 0; kt < 4; ++kt) {
#pragma unroll
      for (int r = 0; r < 16; ++r) sacc[kt][r] = 0.f;
#pragma unroll
      for (int dc = 0; dc < 4; ++dc) {
        bf16x8 ka = *(const bf16x8*)(Ks +
            ((kt * 32 + lq) * 128 + ((dc * 32 + hi * 16) ^ ((lq & 7) << 4))));
        sacc[kt] = __builtin_amdgcn_mfma_f32_32x32x16_bf16(ka, qf[dc], sacc[kt], 0, 0, 0);
      }
      const int mv = pmask[b * 2048 + k0 + kt * 32 + lq];
      union { unsigned int u[4]; bf16x8 v; } aadd;
      aadd.u[0] = (hi == 0 && mv == 0) ? (unsigned int)f2bf_bits(-1.0e9f) : 0u;
      aadd.u[1] = aadd.u[2] = aadd.u[3] = 0u;
      sacc[kt] = __builtin_amdgcn_mfma_f32_32x32x16_bf16(aadd.v, bones.v, sacc[kt], 0, 0, 0);
    }

    // online softmax; lane pair (l, l^32) shares column lq
    float tmax = -3.0e38f;
#pragma unroll
    for (int kt = 0; kt < 4; ++kt)
#pragma unroll
      for (int r = 0; r < 16; ++r) tmax = fmaxf(tmax, sacc[kt][r]);
    tmax = fmaxf(tmax, __shfl_xor(tmax, 32));
    const bool need = (bool)__any(tmax > mrun);
    const float mnew = need ? fmaxf(mrun, tmax) : mrun;
    float psum = 0.f;
#pragma unroll
    for (int kt = 0; kt < 4; ++kt)
#pragma unroll
      for (int r = 0; r < 16; ++r) {
        const float p = __expf(sacc[kt][r] - mnew);
        sacc[kt][r] = p;
        psum += p;
      }
    psum += __shfl_xor(psum, 32);
    if (need) {
      const float alpha = __expf(mrun - mnew);
      mrun = mnew;
      lsum = lsum * alpha + psum;
#pragma unroll
      for (int r = 0; r < 16; ++r) {
        const float ar = __shfl(alpha, (r & 3) + 8 * (r >> 2) + 4 * hi);
        oacc[0][r] *= ar;
        oacc[1][r] *= ar;
      }
    } else {
      lsum += psum;
    }

    // P -> bf16 A-fragments via pack + lane^32 exchange
    union { unsigned int u[4]; bf16x8 v; } paE[4], paO[4];
#pragma unroll
    for (int kt = 0; kt < 4; ++kt) {
      const unsigned int cs0 = pk2(sacc[kt][0], sacc[kt][1]);
      const unsigned int cs1 = pk2(sacc[kt][2], sacc[kt][3]);
      const unsigned int cs2 = pk2(sacc[kt][4], sacc[kt][5]);
      const unsigned int cs3 = pk2(sacc[kt][6], sacc[kt][7]);
      const unsigned int cs4 = pk2(sacc[kt][8], sacc[kt][9]);
      const unsigned int cs5 = pk2(sacc[kt][10], sacc[kt][11]);
      const unsigned int cs6 = pk2(sacc[kt][12], sacc[kt][13]);
      const unsigned int cs7 = pk2(sacc[kt][14], sacc[kt][15]);
      const unsigned int es0 = __shfl_xor(cs0, 32);
      const unsigned int es1 = __shfl_xor(cs1, 32);
      const unsigned int es2 = __shfl_xor(cs2, 32);
      const unsigned int es3 = __shfl_xor(cs3, 32);
      const unsigned int es4 = __shfl_xor(cs4, 32);
      const unsigned int es5 = __shfl_xor(cs5, 32);
      const unsigned int es6 = __shfl_xor(cs6, 32);
      const unsigned int es7 = __shfl_xor(cs7, 32);
      paE[kt].u[0] = hi ? es2 : cs0;
      paE[kt].u[1] = hi ? es3 : cs1;
      paE[kt].u[2] = hi ? cs2 : es0;
      paE[kt].u[3] = hi ? cs3 : es1;
      paO[kt].u[0] = hi ? es6 : cs4;
      paO[kt].u[1] = hi ? es7 : cs5;
      paO[kt].u[2] = hi ? cs6 : es4;
      paO[kt].u[3] = hi ? cs7 : es5;
    }

    // O += P V  (V^T rows 256B; E-frag k=kt*32+hi*8, O-frag k=kt*32+16+hi*8)
#pragma unroll
    for (int kt = 0; kt < 4; ++kt)
#pragma unroll
      for (int nt = 0; nt < 2; ++nt) {
        const int vrow = nt * 32 + lq;
        const int vsw = ((vrow & 7) ^ ((vrow >> 3) & 7)) << 4;
        bf16x8 vbE = *(const bf16x8*)(Vt + (vrow * 256 + ((kt * 64 + hi * 16) ^ vsw)));
        oacc[nt] = __builtin_amdgcn_mfma_f32_32x32x16_bf16(paE[kt].v, vbE, oacc[nt], 0, 0, 0);
        bf16x8 vbO = *(const bf16x8*)(Vt + (vrow * 256 + ((kt * 64 + 32 + hi * 16) ^ vsw)));
        oacc[nt] = __builtin_amdgcn_mfma_f32_32x32x16_bf16(paO[kt].v, vbO, oacc[nt], 0, 0, 0);
      }

    // late half of T14: scatter V-next regs into the other buffer
    if (ktg < 15) {
      char* VtN = smem + 32768 + (cur ^ 1) * 16384;
#pragma unroll
      for (int p = 0; p < 2; ++p) {
        const ushort* vs = (const ushort*)&vreg[p];
#pragma unroll
        for (int e = 0; e < 8; ++e) {
          const int d = vsg[p] * 8 + e;
          *(ushort*)(VtN + d * 256 +
                     ((vk[p] * 2) ^ (((e ^ vsg[p]) & 7) << 4))) = vs[e];
        }
      }
    }

    __syncthreads();
    cur ^= 1;
  }

  const float inv = 1.0f / lsum;
#pragma unroll
  for (int r = 0; r < 16; ++r) {
    const int crow = (r & 3) + 8 * (r >> 2) + 4 * hi;
    const float ir = __shfl(inv, crow);
    const long orow = (long)b * 2048 + qw0 + crow;
#pragma unroll
    for (int nt = 0; nt < 2; ++nt)
      Oout[orow * 1024 + h * 64 + nt * 32 + lq] = __float2bfloat16(oacc[nt][r] * ir);
  }
}

extern "C" void kernel_launch(void* const* d_in, const int* in_sizes, int n_in,
                              void* d_out, int out_size, void* d_ws, size_t ws_size,
                              hipStream_t stream) {
  const float* X = (const float*)d_in[0];
  const int* pmask = (const int*)d_in[1];
  const float* W_Q = (const float*)d_in[2];
  const float* W_K = (const float*)d_in[3];
  const float* W_V = (const float*)d_in[4];
  const float* W_O = (const float*)d_in[5];
  const float* g1 = (const float*)d_in[6];
  const float* b1 = (const float*)d_in[7];
  const float* W1 = (const float*)d_in[8];
  const float* bias1 = (const float*)d_in[9];
  const float* W2 = (const float*)d_in[10];
  const float* bias2 = (const float*)d_in[11];
  const float* g2 = (const float*)d_in[12];
  const float* b2 = (const float*)d_in[13];
  (void)in_sizes; (void)n_in; (void)out_size; (void)ws_size;

  char* ws = (char*)d_ws;
  const size_t MB = 1ull << 20;
  bf16* W1_t   = (bf16*)(ws + 0);
  bf16* Wqkv_t = (bf16*)(ws + 8 * MB);
  bf16* Wo_t   = (bf16*)(ws + 14 * MB);
  bf16* W2_t   = (bf16*)(ws + 16 * MB);
  bf16* xn     = (bf16*)(ws + 24 * MB);
  bf16* QKV    = (bf16*)(ws + 32 * MB);
  bf16* attnb  = (bf16*)(ws + 56 * MB);
  bf16* ff1    = (bf16*)(ws + 32 * MB);
  float* p0    = (float*)(ws + 64 * MB);
  float* p1    = (float*)(ws + 0);
  float* res1  = (float*)d_out;

  transpose_qkvo<<<dim3(32, 32, 4), 256, 0, stream>>>(W_Q, W_K, W_V, W_O, Wqkv_t);
  transpose_to_bf16<<<dim3(128, 32), 256, 0, stream>>>(W1, W1_t, 1024, 4096);
  transpose_to_bf16<<<dim3(32, 128), 256, 0, stream>>>(W2, W2_t, 4096, 1024);

  ln_kernel<<<4096, 256, 0, stream>>>(X, g1, b1, xn);
  gemm_bt<0, 1><<<32 * 24, 256, 0, stream>>>(xn, Wqkv_t, 4096, 3072, 1024, 1024, 1024,
                                             nullptr, nullptr, nullptr, QKV);
  attn_kernel<<<dim3(32, 8), 512, 0, stream>>>(QKV, pmask, attnb);
  gemm_bt<1, 1><<<32 * 8, 256, 0, stream>>>(attnb, Wo_t, 4096, 1024, 1024, 1024, 1024,
                                            nullptr, X, nullptr, res1);
  ln_kernel<<<4096, 256, 0, stream>>>(res1, g2, b2, xn);
  gemm_bt<2, 1><<<32 * 32, 256, 0, stream>>>(xn, W1_t, 4096, 4096, 1024, 1024, 1024,
                                             bias1, nullptr, nullptr, ff1);
  gemm_bt<5, 2><<<2 * 32 * 8, 256, 0, stream>>>(ff1, W2_t, 4096, 1024, 2048, 4096, 4096,
                                                bias2, res1, p1, p0);
  ff2_reduce<<<4096, 256, 0, stream>>>(p0, p1, res1);
}

// Round 8
// 305.690 us; speedup vs baseline: 1.0591x; 1.0285x over previous
//
#include <hip/hip_runtime.h>
#include <hip/hip_bf16.h>

// EncoderLayer on MI355X (gfx950).
// B=2, S=2048, D=1024, H=16, DK=64. M = B*S = 4096.
// R8: FF1 GELU epilogue -> sigmoid-form tanh approx (erff poly ~30 VALU ops ->
//     ~8 ops + 2 transcendentals; epilogue was ~half of FF1's time at K=1024).
//     All weight transposes merged into ONE 12288-block dispatch.
//     Attention unchanged from R7 (8 waves, 256 q-rows, KVBLK=128).

using bf16 = __hip_bfloat16;
typedef __attribute__((ext_vector_type(4))) float f32x4;
typedef __attribute__((ext_vector_type(16))) float f32x16;
typedef __attribute__((ext_vector_type(8))) short bf16x8;

#define DEVI static __device__ __forceinline__

DEVI void async_copy16(const void* g, void* l) {
  __builtin_amdgcn_global_load_lds(
      (const __attribute__((address_space(1))) void*)g,
      (__attribute__((address_space(3))) void*)l, 16, 0, 0);
}

DEVI ushort f2bf_bits(float v) {
  __hip_bfloat16 h = __float2bfloat16(v);
  return *reinterpret_cast<ushort*>(&h);
}

DEVI float bfbits2f(ushort u) {
  union { float f; unsigned int i; } x;
  x.i = ((unsigned int)u) << 16;
  return x.f;
}

DEVI unsigned int pk2(float lo, float hi) {
  return (unsigned int)f2bf_bits(lo) | ((unsigned int)f2bf_bits(hi) << 16);
}

// ---------------- LayerNorm: f32 in (rows x 1024) -> bf16 out ----------------
__global__ __launch_bounds__(256) void ln_kernel(
    const float* __restrict__ in, const float* __restrict__ gamma,
    const float* __restrict__ beta, bf16* __restrict__ out) {
  const long row = blockIdx.x;
  const int t = threadIdx.x;
  float4 x = ((const float4*)(in + row * 1024))[t];
  float s = x.x + x.y + x.z + x.w;
  float s2 = x.x * x.x + x.y * x.y + x.z * x.z + x.w * x.w;
#pragma unroll
  for (int m = 1; m < 64; m <<= 1) {
    s += __shfl_xor(s, m);
    s2 += __shfl_xor(s2, m);
  }
  __shared__ float red[8];
  const int w = t >> 6, l = t & 63;
  if (l == 0) { red[w] = s; red[4 + w] = s2; }
  __syncthreads();
  s = red[0] + red[1] + red[2] + red[3];
  s2 = red[4] + red[5] + red[6] + red[7];
  const float mean = s * (1.0f / 1024.0f);
  const float var = s2 * (1.0f / 1024.0f) - mean * mean;
  const float rstd = rsqrtf(var + 1e-6f);
  float4 g4 = ((const float4*)gamma)[t];
  float4 b4 = ((const float4*)beta)[t];
  union { ushort h[4]; uint2 u; } o;
  o.h[0] = f2bf_bits(g4.x * (x.x - mean) * rstd + b4.x);
  o.h[1] = f2bf_bits(g4.y * (x.y - mean) * rstd + b4.y);
  o.h[2] = f2bf_bits(g4.z * (x.z - mean) * rstd + b4.z);
  o.h[3] = f2bf_bits(g4.w * (x.w - mean) * rstd + b4.w);
  ((uint2*)(out + row * 1024))[t] = o.u;
}

// -------- unified weight transpose: f32 (K x N) -> bf16 (N x K), 32x32 -------
// blocks [0,4096): Q/K/V/O (1024x1024 each); [4096,8192): W1 (1024x4096);
// [8192,12288): W2 (4096x1024).
__global__ __launch_bounds__(256) void transpose_all(
    const float* __restrict__ q, const float* __restrict__ k,
    const float* __restrict__ v, const float* __restrict__ o,
    const float* __restrict__ w1, const float* __restrict__ w2,
    bf16* __restrict__ wqkvo, bf16* __restrict__ w1t, bf16* __restrict__ w2t) {
  const int tid = blockIdx.x;
  const float* W;
  bf16* Wt;
  int K, N, n0, k0;
  if (tid < 4096) {
    const int z = tid >> 10, r = tid & 1023;
    W = (z == 0) ? q : (z == 1) ? k : (z == 2) ? v : o;
    Wt = wqkvo + (size_t)z * 1024 * 1024;
    K = 1024; N = 1024; n0 = (r & 31) << 5; k0 = (r >> 5) << 5;
  } else if (tid < 8192) {
    const int r = tid - 4096;
    W = w1; Wt = w1t; K = 1024; N = 4096;
    n0 = (r & 127) << 5; k0 = (r >> 7) << 5;
  } else {
    const int r = tid - 8192;
    W = w2; Wt = w2t; K = 4096; N = 1024;
    n0 = (r & 31) << 5; k0 = (r >> 5) << 5;
  }
  __shared__ float tile[32][33];
  const int tx = threadIdx.x & 31, ty = threadIdx.x >> 5;
#pragma unroll
  for (int i = 0; i < 32; i += 8)
    tile[ty + i][tx] = W[(long)(k0 + ty + i) * N + n0 + tx];
  __syncthreads();
#pragma unroll
  for (int i = 0; i < 32; i += 8)
    Wt[(long)(n0 + ty + i) * K + k0 + tx] = __float2bfloat16(tile[tx][ty + i]);
}

// ---------------- GEMM: C(MxN) = A(MxK,bf16) * Bt(NxK,bf16)^T ----------------
// 128x128 tile, BK=32, 4 waves, global_load_lds staging (m97 structure),
// XCD-aware bijective blockIdx swizzle. lda/ldb = row strides.
// KSPLIT=2: slice sl reads K-cols [sl*K,(sl+1)*K); sl0 -> Cout, sl1 -> pother.
// EPI: 0 = bf16; 1 = +res(f32) f32; 2 = +bias sigmoid-GELU bf16;
//      5 = split-K partial, sl0 adds bias+res.
template <int EPI, int KSPLIT>
__global__ __launch_bounds__(256) void gemm_bt(
    const bf16* __restrict__ A, const bf16* __restrict__ Bt,
    const int M, const int N, const int K, const int lda, const int ldb,
    const float* __restrict__ bias, const float* __restrict__ res,
    float* __restrict__ pother, void* __restrict__ Cout) {
  __shared__ bf16 As[128 * 32];
  __shared__ bf16 Bs[128 * 32];
  const int t = threadIdx.x;
  const int w = t >> 6, l = t & 63;
  const int nb = N >> 7;
  const int cpx = gridDim.x >> 3;
  int bidx = (blockIdx.x & 7) * cpx + (blockIdx.x >> 3);
  int sl = 0;
  if (KSPLIT == 2) {
    const int half = gridDim.x >> 1;
    sl = bidx >= half;
    bidx -= sl * half;
  }
  const int bm = bidx / nb, bn = bidx % nb;
  const long row0 = (long)bm << 7, col0 = (long)bn << 7;
  const int wr = (w >> 1) << 6, wc = (w & 1) << 6;
  const int lr = l & 15, lk = (l >> 4) << 3;

  f32x4 acc[4][4];
#pragma unroll
  for (int m = 0; m < 4; ++m)
#pragma unroll
    for (int n = 0; n < 4; ++n) acc[m][n] = (f32x4){0.f, 0.f, 0.f, 0.f};

  const bf16* gA = A + (row0 + (t >> 2)) * (long)lda + (long)sl * K + ((t & 3) << 3);
  const bf16* gB = Bt + (col0 + (t >> 2)) * (long)ldb + (long)sl * K + ((t & 3) << 3);
  char* lA = (char*)As + (w << 10);
  char* lB = (char*)Bs + (w << 10);
  const long k64a = (long)64 * lda, k64b = (long)64 * ldb;

  for (int k0 = 0; k0 < K; k0 += 32) {
    __syncthreads();
    async_copy16(gA + k0, lA);
    async_copy16(gA + k64a + k0, lA + 4096);
    async_copy16(gB + k0, lB);
    async_copy16(gB + k64b + k0, lB + 4096);
    __syncthreads();
    bf16x8 af[4], bfr[4];
#pragma unroll
    for (int m = 0; m < 4; ++m)
      af[m] = *(const bf16x8*)&As[(wr + m * 16 + lr) * 32 + lk];
#pragma unroll
    for (int n = 0; n < 4; ++n)
      bfr[n] = *(const bf16x8*)&Bs[(wc + n * 16 + lr) * 32 + lk];
#pragma unroll
    for (int m = 0; m < 4; ++m)
#pragma unroll
      for (int n = 0; n < 4; ++n)
        acc[m][n] = __builtin_amdgcn_mfma_f32_16x16x32_bf16(af[m], bfr[n], acc[m][n], 0, 0, 0);
  }

  bf16* Cb = (bf16*)Cout;
  float* Cf = (float*)Cout;
  if (EPI == 5 && sl == 1) Cf = pother;
#pragma unroll
  for (int m = 0; m < 4; ++m) {
#pragma unroll
    for (int r = 0; r < 4; ++r) {
      const long crow = row0 + wr + m * 16 + ((l >> 4) << 2) + r;
      const long rbase = crow * N;
#pragma unroll
      for (int n = 0; n < 4; ++n) {
        const long ccol = col0 + wc + n * 16 + lr;
        float v = acc[m][n][r];
        if (EPI == 2) {
          // GELU(x) ~= x * sigmoid(1.5957691216*(x + 0.044715 x^3)); max abs
          // deviation from exact erf form ~1e-3, negligible after FF2.
          const float vv = v + bias[ccol];
          const float u2 = vv * (1.5957691216f + 0.0713548162f * vv * vv);
          v = vv / (1.0f + __expf(-u2));
        }
        if (EPI == 1) v += res[rbase + ccol];
        if (EPI == 5 && sl == 0) v += bias[ccol] + res[rbase + ccol];
        if (EPI == 0 || EPI == 2)
          Cb[rbase + ccol] = __float2bfloat16(v);
        else
          Cf[rbase + ccol] = v;
      }
    }
  }
}

// ---- split-K reduce: out = p0 + p1 (p0 already holds bias+residual) ----
__global__ __launch_bounds__(256) void ff2_reduce(
    const float* __restrict__ p0, const float* __restrict__ p1,
    float* __restrict__ out) {
  const int idx = blockIdx.x * 256 + threadIdx.x;
  const float4 x = ((const float4*)p0)[idx];
  const float4 y = ((const float4*)p1)[idx];
  float4 a;
  a.x = x.x + y.x; a.y = x.y + y.y; a.z = x.z + y.z; a.w = x.w + y.w;
  ((float4*)out)[idx] = a;
}

// ---------------- flash attention: 8 waves, 256 q-rows, KVBLK=128 ------------
// Grid: x = B*H (32), y = S/256 (8). Wave w owns q rows [w*32, w*32+32).
// Double-buffered, ONE barrier per 128-kv tile (16 tiles total).
__global__ __launch_bounds__(512) void attn_kernel(
    const bf16* __restrict__ QKV, const int* __restrict__ pmask,
    bf16* __restrict__ Oout) {
  const int bh = blockIdx.x;
  const int b = bh >> 4, h = bh & 15;
  const int q0 = blockIdx.y << 8;
  const int t = threadIdx.x;
  const int w = t >> 6, l = t & 63;
  const int lq = l & 31, hi = l >> 5;

  __shared__ __align__(16) char smem[65536];

  const long base = (long)b * 2048 * 3072;
  const bf16* Qg = QKV + base + h * 64;
  const bf16* Kg = QKV + base + 1024 + h * 64;
  const bf16* Vg = QKV + base + 2048 + h * 64;

  int kSrc[2], kDst[2], vk[2], vsg[2];
#pragma unroll
  for (int p = 0; p < 2; ++p) {
    const int c = p * 512 + t;
    const int kr = c >> 3;
    kSrc[p] = kr * 3072 + (((c & 7) ^ (kr & 7)) << 3);
    kDst[p] = c * 16;
    vk[p] = c >> 3;
    vsg[p] = c & 7;
  }

  const int qw0 = q0 + w * 32;
  bf16x8 qf[4];
#pragma unroll
  for (int dc = 0; dc < 4; ++dc) {
    uint4 raw = *(const uint4*)(Qg + (long)(qw0 + lq) * 3072 + dc * 16 + hi * 8);
    union { uint4 u4; ushort us[8]; } in; in.u4 = raw;
    union { bf16x8 v; ushort us[8]; } o;
#pragma unroll
    for (int e = 0; e < 8; ++e) o.us[e] = f2bf_bits(0.125f * bfbits2f(in.us[e]));
    qf[dc] = o.v;
  }

  union { unsigned int u[4]; bf16x8 v; } bones;
  bones.u[0] = (hi == 0) ? 0x00003F80u : 0u;
  bones.u[1] = bones.u[2] = bones.u[3] = 0u;

  uint4 vreg[2];
#pragma unroll
  for (int p = 0; p < 2; ++p) {
    vreg[p] = *(const uint4*)(Vg + (long)vk[p] * 3072 + vsg[p] * 8);
    async_copy16(Kg + kSrc[p], smem + kDst[p]);
  }
#pragma unroll
  for (int p = 0; p < 2; ++p) {
    const ushort* vs = (const ushort*)&vreg[p];
#pragma unroll
    for (int e = 0; e < 8; ++e) {
      const int d = vsg[p] * 8 + e;
      *(ushort*)(smem + 32768 + d * 256 +
                 ((vk[p] * 2) ^ (((e ^ vsg[p]) & 7) << 4))) = vs[e];
    }
  }

  f32x16 oacc[2];
#pragma unroll
  for (int nt = 0; nt < 2; ++nt)
#pragma unroll
    for (int r = 0; r < 16; ++r) oacc[nt][r] = 0.f;
  float mrun = -3.0e38f, lsum = 0.f;
  int cur = 0;

  __syncthreads();

  for (int ktg = 0; ktg < 16; ++ktg) {
    if (ktg < 15) {
      const long nrow0 = (long)(ktg + 1) * 128 * 3072;
#pragma unroll
      for (int p = 0; p < 2; ++p) {
        vreg[p] = *(const uint4*)(Vg + nrow0 + (long)vk[p] * 3072 + vsg[p] * 8);
        async_copy16(Kg + nrow0 + kSrc[p], smem + (cur ^ 1) * 16384 + kDst[p]);
      }
    }
    const int k0 = ktg << 7;
    const char* Ks = smem + cur * 16384;
    const char* Vt = smem + 32768 + cur * 16384;

    f32x16 sacc[4];
#pragma unroll
    for (int kt = 0; kt < 4; ++kt) {
#pragma unroll
      for (int r = 0; r < 16; ++r) sacc[kt][r] = 0.f;
#pragma unroll
      for (int dc = 0; dc < 4; ++dc) {
        bf16x8 ka = *(const bf16x8*)(Ks +
            ((kt * 32 + lq) * 128 + ((dc * 32 + hi * 16) ^ ((lq & 7) << 4))));
        sacc[kt] = __builtin_amdgcn_mfma_f32_32x32x16_bf16(ka, qf[dc], sacc[kt], 0, 0, 0);
      }
      const int mv = pmask[b * 2048 + k0 + kt * 32 + lq];
      union { unsigned int u[4]; bf16x8 v; } aadd;
      aadd.u[0] = (hi == 0 && mv == 0) ? (unsigned int)f2bf_bits(-1.0e9f) : 0u;
      aadd.u[1] = aadd.u[2] = aadd.u[3] = 0u;
      sacc[kt] = __builtin_amdgcn_mfma_f32_32x32x16_bf16(aadd.v, bones.v, sacc[kt], 0, 0, 0);
    }

    float tmax = -3.0e38f;
#pragma unroll
    for (int kt = 0; kt < 4; ++kt)
#pragma unroll
      for (int r = 0; r < 16; ++r) tmax = fmaxf(tmax, sacc[kt][r]);
    tmax = fmaxf(tmax, __shfl_xor(tmax, 32));
    const bool need = (bool)__any(tmax > mrun);
    const float mnew = need ? fmaxf(mrun, tmax) : mrun;
    float psum = 0.f;
#pragma unroll
    for (int kt = 0; kt < 4; ++kt)
#pragma unroll
      for (int r = 0; r < 16; ++r) {
        const float p = __expf(sacc[kt][r] - mnew);
        sacc[kt][r] = p;
        psum += p;
      }
    psum += __shfl_xor(psum, 32);
    if (need) {
      const float alpha = __expf(mrun - mnew);
      mrun = mnew;
      lsum = lsum * alpha + psum;
#pragma unroll
      for (int r = 0; r < 16; ++r) {
        const float ar = __shfl(alpha, (r & 3) + 8 * (r >> 2) + 4 * hi);
        oacc[0][r] *= ar;
        oacc[1][r] *= ar;
      }
    } else {
      lsum += psum;
    }

    union { unsigned int u[4]; bf16x8 v; } paE[4], paO[4];
#pragma unroll
    for (int kt = 0; kt < 4; ++kt) {
      const unsigned int cs0 = pk2(sacc[kt][0], sacc[kt][1]);
      const unsigned int cs1 = pk2(sacc[kt][2], sacc[kt][3]);
      const unsigned int cs2 = pk2(sacc[kt][4], sacc[kt][5]);
      const unsigned int cs3 = pk2(sacc[kt][6], sacc[kt][7]);
      const unsigned int cs4 = pk2(sacc[kt][8], sacc[kt][9]);
      const unsigned int cs5 = pk2(sacc[kt][10], sacc[kt][11]);
      const unsigned int cs6 = pk2(sacc[kt][12], sacc[kt][13]);
      const unsigned int cs7 = pk2(sacc[kt][14], sacc[kt][15]);
      const unsigned int es0 = __shfl_xor(cs0, 32);
      const unsigned int es1 = __shfl_xor(cs1, 32);
      const unsigned int es2 = __shfl_xor(cs2, 32);
      const unsigned int es3 = __shfl_xor(cs3, 32);
      const unsigned int es4 = __shfl_xor(cs4, 32);
      const unsigned int es5 = __shfl_xor(cs5, 32);
      const unsigned int es6 = __shfl_xor(cs6, 32);
      const unsigned int es7 = __shfl_xor(cs7, 32);
      paE[kt].u[0] = hi ? es2 : cs0;
      paE[kt].u[1] = hi ? es3 : cs1;
      paE[kt].u[2] = hi ? cs2 : es0;
      paE[kt].u[3] = hi ? cs3 : es1;
      paO[kt].u[0] = hi ? es6 : cs4;
      paO[kt].u[1] = hi ? es7 : cs5;
      paO[kt].u[2] = hi ? cs6 : es4;
      paO[kt].u[3] = hi ? cs7 : es5;
    }

#pragma unroll
    for (int kt = 0; kt < 4; ++kt)
#pragma unroll
      for (int nt = 0; nt < 2; ++nt) {
        const int vrow = nt * 32 + lq;
        const int vsw = ((vrow & 7) ^ ((vrow >> 3) & 7)) << 4;
        bf16x8 vbE = *(const bf16x8*)(Vt + (vrow * 256 + ((kt * 64 + hi * 16) ^ vsw)));
        oacc[nt] = __builtin_amdgcn_mfma_f32_32x32x16_bf16(paE[kt].v, vbE, oacc[nt], 0, 0, 0);
        bf16x8 vbO = *(const bf16x8*)(Vt + (vrow * 256 + ((kt * 64 + 32 + hi * 16) ^ vsw)));
        oacc[nt] = __builtin_amdgcn_mfma_f32_32x32x16_bf16(paO[kt].v, vbO, oacc[nt], 0, 0, 0);
      }

    if (ktg < 15) {
      char* VtN = smem + 32768 + (cur ^ 1) * 16384;
#pragma unroll
      for (int p = 0; p < 2; ++p) {
        const ushort* vs = (const ushort*)&vreg[p];
#pragma unroll
        for (int e = 0; e < 8; ++e) {
          const int d = vsg[p] * 8 + e;
          *(ushort*)(VtN + d * 256 +
                     ((vk[p] * 2) ^ (((e ^ vsg[p]) & 7) << 4))) = vs[e];
        }
      }
    }

    __syncthreads();
    cur ^= 1;
  }

  const float inv = 1.0f / lsum;
#pragma unroll
  for (int r = 0; r < 16; ++r) {
    const int crow = (r & 3) + 8 * (r >> 2) + 4 * hi;
    const float ir = __shfl(inv, crow);
    const long orow = (long)b * 2048 + qw0 + crow;
#pragma unroll
    for (int nt = 0; nt < 2; ++nt)
      Oout[orow * 1024 + h * 64 + nt * 32 + lq] = __float2bfloat16(oacc[nt][r] * ir);
  }
}

extern "C" void kernel_launch(void* const* d_in, const int* in_sizes, int n_in,
                              void* d_out, int out_size, void* d_ws, size_t ws_size,
                              hipStream_t stream) {
  const float* X = (const float*)d_in[0];
  const int* pmask = (const int*)d_in[1];
  const float* W_Q = (const float*)d_in[2];
  const float* W_K = (const float*)d_in[3];
  const float* W_V = (const float*)d_in[4];
  const float* W_O = (const float*)d_in[5];
  const float* g1 = (const float*)d_in[6];
  const float* b1 = (const float*)d_in[7];
  const float* W1 = (const float*)d_in[8];
  const float* bias1 = (const float*)d_in[9];
  const float* W2 = (const float*)d_in[10];
  const float* bias2 = (const float*)d_in[11];
  const float* g2 = (const float*)d_in[12];
  const float* b2 = (const float*)d_in[13];
  (void)in_sizes; (void)n_in; (void)out_size; (void)ws_size;

  char* ws = (char*)d_ws;
  const size_t MB = 1ull << 20;
  bf16* W1_t   = (bf16*)(ws + 0);
  bf16* Wqkv_t = (bf16*)(ws + 8 * MB);
  bf16* Wo_t   = (bf16*)(ws + 14 * MB);
  bf16* W2_t   = (bf16*)(ws + 16 * MB);
  bf16* xn     = (bf16*)(ws + 24 * MB);
  bf16* QKV    = (bf16*)(ws + 32 * MB);
  bf16* attnb  = (bf16*)(ws + 56 * MB);
  bf16* ff1    = (bf16*)(ws + 32 * MB);
  float* p0    = (float*)(ws + 64 * MB);
  float* p1    = (float*)(ws + 0);
  float* res1  = (float*)d_out;

  transpose_all<<<12288, 256, 0, stream>>>(W_Q, W_K, W_V, W_O, W1, W2,
                                           Wqkv_t, W1_t, W2_t);
  ln_kernel<<<4096, 256, 0, stream>>>(X, g1, b1, xn);
  gemm_bt<0, 1><<<32 * 24, 256, 0, stream>>>(xn, Wqkv_t, 4096, 3072, 1024, 1024, 1024,
                                             nullptr, nullptr, nullptr, QKV);
  attn_kernel<<<dim3(32, 8), 512, 0, stream>>>(QKV, pmask, attnb);
  gemm_bt<1, 1><<<32 * 8, 256, 0, stream>>>(attnb, Wo_t, 4096, 1024, 1024, 1024, 1024,
                                            nullptr, X, nullptr, res1);
  ln_kernel<<<4096, 256, 0, stream>>>(res1, g2, b2, xn);
  gemm_bt<2, 1><<<32 * 32, 256, 0, stream>>>(xn, W1_t, 4096, 4096, 1024, 1024, 1024,
                                             bias1, nullptr, nullptr, ff1);
  gemm_bt<5, 2><<<2 * 32 * 8, 256, 0, stream>>>(ff1, W2_t, 4096, 1024, 2048, 4096, 4096,
                                                bias2, res1, p1, p0);
  ff2_reduce<<<4096, 256, 0, stream>>>(p0, p1, res1);
}

// Round 9
// 289.707 us; speedup vs baseline: 1.1175x; 1.0552x over previous
//
#include <hip/hip_runtime.h>
#include <hip/hip_bf16.h>

// EncoderLayer on MI355X (gfx950).
// B=2, S=2048, D=1024, H=16, DK=64. M = B*S = 4096.
// R9: GEMM BK 32->64 with attention-proven swizzled async staging (halves
//     barrier drains; pre-swizzled global_load_lds source, XOR'd reads ->
//     conflict-free). O-proj split-K=2. O-proj reduce fused with LN2.

using bf16 = __hip_bfloat16;
typedef __attribute__((ext_vector_type(4))) float f32x4;
typedef __attribute__((ext_vector_type(16))) float f32x16;
typedef __attribute__((ext_vector_type(8))) short bf16x8;

#define DEVI static __device__ __forceinline__

DEVI void async_copy16(const void* g, void* l) {
  __builtin_amdgcn_global_load_lds(
      (const __attribute__((address_space(1))) void*)g,
      (__attribute__((address_space(3))) void*)l, 16, 0, 0);
}

DEVI ushort f2bf_bits(float v) {
  __hip_bfloat16 h = __float2bfloat16(v);
  return *reinterpret_cast<ushort*>(&h);
}

DEVI float bfbits2f(ushort u) {
  union { float f; unsigned int i; } x;
  x.i = ((unsigned int)u) << 16;
  return x.f;
}

DEVI unsigned int pk2(float lo, float hi) {
  return (unsigned int)f2bf_bits(lo) | ((unsigned int)f2bf_bits(hi) << 16);
}

// ---------------- LayerNorm: f32 in (rows x 1024) -> bf16 out ----------------
__global__ __launch_bounds__(256) void ln_kernel(
    const float* __restrict__ in, const float* __restrict__ gamma,
    const float* __restrict__ beta, bf16* __restrict__ out) {
  const long row = blockIdx.x;
  const int t = threadIdx.x;
  float4 x = ((const float4*)(in + row * 1024))[t];
  float s = x.x + x.y + x.z + x.w;
  float s2 = x.x * x.x + x.y * x.y + x.z * x.z + x.w * x.w;
#pragma unroll
  for (int m = 1; m < 64; m <<= 1) {
    s += __shfl_xor(s, m);
    s2 += __shfl_xor(s2, m);
  }
  __shared__ float red[8];
  const int w = t >> 6, l = t & 63;
  if (l == 0) { red[w] = s; red[4 + w] = s2; }
  __syncthreads();
  s = red[0] + red[1] + red[2] + red[3];
  s2 = red[4] + red[5] + red[6] + red[7];
  const float mean = s * (1.0f / 1024.0f);
  const float var = s2 * (1.0f / 1024.0f) - mean * mean;
  const float rstd = rsqrtf(var + 1e-6f);
  float4 g4 = ((const float4*)gamma)[t];
  float4 b4 = ((const float4*)beta)[t];
  union { ushort h[4]; uint2 u; } o;
  o.h[0] = f2bf_bits(g4.x * (x.x - mean) * rstd + b4.x);
  o.h[1] = f2bf_bits(g4.y * (x.y - mean) * rstd + b4.y);
  o.h[2] = f2bf_bits(g4.z * (x.z - mean) * rstd + b4.z);
  o.h[3] = f2bf_bits(g4.w * (x.w - mean) * rstd + b4.w);
  ((uint2*)(out + row * 1024))[t] = o.u;
}

// ---- O-proj split-K reduce fused with LN2: res = p0+p1+X; xn = LN(res) ----
__global__ __launch_bounds__(256) void oproj_reduce_ln(
    const float* __restrict__ p0, const float* __restrict__ p1,
    const float* __restrict__ X, const float* __restrict__ gamma,
    const float* __restrict__ beta, float* __restrict__ res_out,
    bf16* __restrict__ xn_out) {
  const long row = blockIdx.x;
  const int t = threadIdx.x;
  const long i = row * 256 + t;
  const float4 a = ((const float4*)p0)[i];
  const float4 b = ((const float4*)p1)[i];
  const float4 c = ((const float4*)X)[i];
  float4 x;
  x.x = a.x + b.x + c.x; x.y = a.y + b.y + c.y;
  x.z = a.z + b.z + c.z; x.w = a.w + b.w + c.w;
  ((float4*)res_out)[i] = x;
  float s = x.x + x.y + x.z + x.w;
  float s2 = x.x * x.x + x.y * x.y + x.z * x.z + x.w * x.w;
#pragma unroll
  for (int m = 1; m < 64; m <<= 1) {
    s += __shfl_xor(s, m);
    s2 += __shfl_xor(s2, m);
  }
  __shared__ float red[8];
  const int w = t >> 6, l = t & 63;
  if (l == 0) { red[w] = s; red[4 + w] = s2; }
  __syncthreads();
  s = red[0] + red[1] + red[2] + red[3];
  s2 = red[4] + red[5] + red[6] + red[7];
  const float mean = s * (1.0f / 1024.0f);
  const float var = s2 * (1.0f / 1024.0f) - mean * mean;
  const float rstd = rsqrtf(var + 1e-6f);
  float4 g4 = ((const float4*)gamma)[t];
  float4 b4 = ((const float4*)beta)[t];
  union { ushort h[4]; uint2 u; } o;
  o.h[0] = f2bf_bits(g4.x * (x.x - mean) * rstd + b4.x);
  o.h[1] = f2bf_bits(g4.y * (x.y - mean) * rstd + b4.y);
  o.h[2] = f2bf_bits(g4.z * (x.z - mean) * rstd + b4.z);
  o.h[3] = f2bf_bits(g4.w * (x.w - mean) * rstd + b4.w);
  ((uint2*)(xn_out + row * 1024))[t] = o.u;
}

// -------- unified weight transpose: f32 (K x N) -> bf16 (N x K), 32x32 -------
__global__ __launch_bounds__(256) void transpose_all(
    const float* __restrict__ q, const float* __restrict__ k,
    const float* __restrict__ v, const float* __restrict__ o,
    const float* __restrict__ w1, const float* __restrict__ w2,
    bf16* __restrict__ wqkvo, bf16* __restrict__ w1t, bf16* __restrict__ w2t) {
  const int tid = blockIdx.x;
  const float* W;
  bf16* Wt;
  int K, N, n0, k0;
  if (tid < 4096) {
    const int z = tid >> 10, r = tid & 1023;
    W = (z == 0) ? q : (z == 1) ? k : (z == 2) ? v : o;
    Wt = wqkvo + (size_t)z * 1024 * 1024;
    K = 1024; N = 1024; n0 = (r & 31) << 5; k0 = (r >> 5) << 5;
  } else if (tid < 8192) {
    const int r = tid - 4096;
    W = w1; Wt = w1t; K = 1024; N = 4096;
    n0 = (r & 127) << 5; k0 = (r >> 7) << 5;
  } else {
    const int r = tid - 8192;
    W = w2; Wt = w2t; K = 4096; N = 1024;
    n0 = (r & 31) << 5; k0 = (r >> 5) << 5;
  }
  __shared__ float tile[32][33];
  const int tx = threadIdx.x & 31, ty = threadIdx.x >> 5;
#pragma unroll
  for (int i = 0; i < 32; i += 8)
    tile[ty + i][tx] = W[(long)(k0 + ty + i) * N + n0 + tx];
  __syncthreads();
#pragma unroll
  for (int i = 0; i < 32; i += 8)
    Wt[(long)(n0 + ty + i) * K + k0 + tx] = __float2bfloat16(tile[tx][ty + i]);
}

// ---------------- GEMM: C(MxN) = A(MxK,bf16) * Bt(NxK,bf16)^T ----------------
// 128x128 tile, BK=64, 4 waves. Swizzled async staging (attention-proven):
// LDS tile [128 rows][64 elems]; element (r, g*8+e) at byte
// r*128 + (g*16 ^ ((r&7)<<4)) + e*2; staged by global_load_lds with linear
// dest chunk c = cr*256+t and pre-swizzled source colgroup (t&7)^((t>>3)&7).
// XCD-aware bijective blockIdx swizzle. KSPLIT=2: slice sl reads K-cols
// [sl*K,(sl+1)*K); sl0 -> Cout, sl1 -> pother.
// EPI: 0 = bf16; 2 = +bias sigmoid-GELU bf16; 4 = raw f32 partial;
//      5 = split-K partial, sl0 adds bias+res.
template <int EPI, int KSPLIT>
__global__ __launch_bounds__(256) void gemm_bt(
    const bf16* __restrict__ A, const bf16* __restrict__ Bt,
    const int M, const int N, const int K, const int lda, const int ldb,
    const float* __restrict__ bias, const float* __restrict__ res,
    float* __restrict__ pother, void* __restrict__ Cout) {
  __shared__ bf16 As[128 * 64];
  __shared__ bf16 Bs[128 * 64];
  const int t = threadIdx.x;
  const int w = t >> 6, l = t & 63;
  const int nb = N >> 7;
  const int cpx = gridDim.x >> 3;
  int bidx = (blockIdx.x & 7) * cpx + (blockIdx.x >> 3);
  int sl = 0;
  if (KSPLIT == 2) {
    const int half = gridDim.x >> 1;
    sl = bidx >= half;
    bidx -= sl * half;
  }
  const int bm = bidx / nb, bn = bidx % nb;
  const long row0 = (long)bm << 7, col0 = (long)bn << 7;
  const int wr = (w >> 1) << 6, wc = (w & 1) << 6;
  const int lr = l & 15;
  const int lkb = (l >> 4) << 4;  // byte offset of lane's 8-elem group in 32-k

  f32x4 acc[4][4];
#pragma unroll
  for (int m = 0; m < 4; ++m)
#pragma unroll
    for (int n = 0; n < 4; ++n) acc[m][n] = (f32x4){0.f, 0.f, 0.f, 0.f};

  // staging: thread t covers rows rA = t>>3 (+32 per round), src colgroup g.
  const int rA = t >> 3;
  const int g = (t & 7) ^ ((t >> 3) & 7);
  const bf16* gA = A + (row0 + rA) * (long)lda + (long)sl * K + g * 8;
  const bf16* gB = Bt + (col0 + rA) * (long)ldb + (long)sl * K + g * 8;
  char* lA = (char*)As + t * 16;
  char* lB = (char*)Bs + t * 16;

  for (int k0 = 0; k0 < K; k0 += 64) {
    __syncthreads();
#pragma unroll
    for (int cr = 0; cr < 4; ++cr) {
      async_copy16(gA + (long)cr * 32 * lda + k0, lA + cr * 4096);
      async_copy16(gB + (long)cr * 32 * ldb + k0, lB + cr * 4096);
    }
    __syncthreads();
#pragma unroll
    for (int ks = 0; ks < 2; ++ks) {
      bf16x8 af[4], bfr[4];
#pragma unroll
      for (int m = 0; m < 4; ++m) {
        const int row = wr + m * 16 + lr;
        af[m] = *(const bf16x8*)((const char*)As +
            (row * 128 + ((ks * 64 + lkb) ^ ((row & 7) << 4))));
      }
#pragma unroll
      for (int n = 0; n < 4; ++n) {
        const int row = wc + n * 16 + lr;
        bfr[n] = *(const bf16x8*)((const char*)Bs +
            (row * 128 + ((ks * 64 + lkb) ^ ((row & 7) << 4))));
      }
#pragma unroll
      for (int m = 0; m < 4; ++m)
#pragma unroll
        for (int n = 0; n < 4; ++n)
          acc[m][n] = __builtin_amdgcn_mfma_f32_16x16x32_bf16(af[m], bfr[n], acc[m][n], 0, 0, 0);
    }
  }

  bf16* Cb = (bf16*)Cout;
  float* Cf = (float*)Cout;
  if ((EPI == 4 || EPI == 5) && sl == 1) Cf = pother;
#pragma unroll
  for (int m = 0; m < 4; ++m) {
#pragma unroll
    for (int r = 0; r < 4; ++r) {
      const long crow = row0 + wr + m * 16 + ((l >> 4) << 2) + r;
      const long rbase = crow * N;
#pragma unroll
      for (int n = 0; n < 4; ++n) {
        const long ccol = col0 + wc + n * 16 + lr;
        float v = acc[m][n][r];
        if (EPI == 2) {
          const float vv = v + bias[ccol];
          const float u2 = vv * (1.5957691216f + 0.0713548162f * vv * vv);
          v = vv / (1.0f + __expf(-u2));
        }
        if (EPI == 5 && sl == 0) v += bias[ccol] + res[rbase + ccol];
        if (EPI == 0 || EPI == 2)
          Cb[rbase + ccol] = __float2bfloat16(v);
        else
          Cf[rbase + ccol] = v;
      }
    }
  }
}

// ---- split-K reduce: out = p0 + p1 (p0 already holds bias+residual) ----
__global__ __launch_bounds__(256) void ff2_reduce(
    const float* __restrict__ p0, const float* __restrict__ p1,
    float* __restrict__ out) {
  const int idx = blockIdx.x * 256 + threadIdx.x;
  const float4 x = ((const float4*)p0)[idx];
  const float4 y = ((const float4*)p1)[idx];
  float4 a;
  a.x = x.x + y.x; a.y = x.y + y.y; a.z = x.z + y.z; a.w = x.w + y.w;
  ((float4*)out)[idx] = a;
}

// ---------------- flash attention: 8 waves, 256 q-rows, KVBLK=128 ------------
__global__ __launch_bounds__(512) void attn_kernel(
    const bf16* __restrict__ QKV, const int* __restrict__ pmask,
    bf16* __restrict__ Oout) {
  const int bh = blockIdx.x;
  const int b = bh >> 4, h = bh & 15;
  const int q0 = blockIdx.y << 8;
  const int t = threadIdx.x;
  const int w = t >> 6, l = t & 63;
  const int lq = l & 31, hi = l >> 5;

  __shared__ __align__(16) char smem[65536];

  const long base = (long)b * 2048 * 3072;
  const bf16* Qg = QKV + base + h * 64;
  const bf16* Kg = QKV + base + 1024 + h * 64;
  const bf16* Vg = QKV + base + 2048 + h * 64;

  int kSrc[2], kDst[2], vk[2], vsg[2];
#pragma unroll
  for (int p = 0; p < 2; ++p) {
    const int c = p * 512 + t;
    const int kr = c >> 3;
    kSrc[p] = kr * 3072 + (((c & 7) ^ (kr & 7)) << 3);
    kDst[p] = c * 16;
    vk[p] = c >> 3;
    vsg[p] = c & 7;
  }

  const int qw0 = q0 + w * 32;
  bf16x8 qf[4];
#pragma unroll
  for (int dc = 0; dc < 4; ++dc) {
    uint4 raw = *(const uint4*)(Qg + (long)(qw0 + lq) * 3072 + dc * 16 + hi * 8);
    union { uint4 u4; ushort us[8]; } in; in.u4 = raw;
    union { bf16x8 v; ushort us[8]; } o;
#pragma unroll
    for (int e = 0; e < 8; ++e) o.us[e] = f2bf_bits(0.125f * bfbits2f(in.us[e]));
    qf[dc] = o.v;
  }

  union { unsigned int u[4]; bf16x8 v; } bones;
  bones.u[0] = (hi == 0) ? 0x00003F80u : 0u;
  bones.u[1] = bones.u[2] = bones.u[3] = 0u;

  uint4 vreg[2];
#pragma unroll
  for (int p = 0; p < 2; ++p) {
    vreg[p] = *(const uint4*)(Vg + (long)vk[p] * 3072 + vsg[p] * 8);
    async_copy16(Kg + kSrc[p], smem + kDst[p]);
  }
#pragma unroll
  for (int p = 0; p < 2; ++p) {
    const ushort* vs = (const ushort*)&vreg[p];
#pragma unroll
    for (int e = 0; e < 8; ++e) {
      const int d = vsg[p] * 8 + e;
      *(ushort*)(smem + 32768 + d * 256 +
                 ((vk[p] * 2) ^ (((e ^ vsg[p]) & 7) << 4))) = vs[e];
    }
  }

  f32x16 oacc[2];
#pragma unroll
  for (int nt = 0; nt < 2; ++nt)
#pragma unroll
    for (int r = 0; r < 16; ++r) oacc[nt][r] = 0.f;
  float mrun = -3.0e38f, lsum = 0.f;
  int cur = 0;

  __syncthreads();

  for (int ktg = 0; ktg < 16; ++ktg) {
    if (ktg < 15) {
      const long nrow0 = (long)(ktg + 1) * 128 * 3072;
#pragma unroll
      for (int p = 0; p < 2; ++p) {
        vreg[p] = *(const uint4*)(Vg + nrow0 + (long)vk[p] * 3072 + vsg[p] * 8);
        async_copy16(Kg + nrow0 + kSrc[p], smem + (cur ^ 1) * 16384 + kDst[p]);
      }
    }
    const int k0 = ktg << 7;
    const char* Ks = smem + cur * 16384;
    const char* Vt = smem + 32768 + cur * 16384;

    f32x16 sacc[4];
#pragma unroll
    for (int kt = 0; kt < 4; ++kt) {
#pragma unroll
      for (int r = 0; r < 16; ++r) sacc[kt][r] = 0.f;
#pragma unroll
      for (int dc = 0; dc < 4; ++dc) {
        bf16x8 ka = *(const bf16x8*)(Ks +
            ((kt * 32 + lq) * 128 + ((dc * 32 + hi * 16) ^ ((lq & 7) << 4))));
        sacc[kt] = __builtin_amdgcn_mfma_f32_32x32x16_bf16(ka, qf[dc], sacc[kt], 0, 0, 0);
      }
      const int mv = pmask[b * 2048 + k0 + kt * 32 + lq];
      union { unsigned int u[4]; bf16x8 v; } aadd;
      aadd.u[0] = (hi == 0 && mv == 0) ? (unsigned int)f2bf_bits(-1.0e9f) : 0u;
      aadd.u[1] = aadd.u[2] = aadd.u[3] = 0u;
      sacc[kt] = __builtin_amdgcn_mfma_f32_32x32x16_bf16(aadd.v, bones.v, sacc[kt], 0, 0, 0);
    }

    float tmax = -3.0e38f;
#pragma unroll
    for (int kt = 0; kt < 4; ++kt)
#pragma unroll
      for (int r = 0; r < 16; ++r) tmax = fmaxf(tmax, sacc[kt][r]);
    tmax = fmaxf(tmax, __shfl_xor(tmax, 32));
    const bool need = (bool)__any(tmax > mrun);
    const float mnew = need ? fmaxf(mrun, tmax) : mrun;
    float psum = 0.f;
#pragma unroll
    for (int kt = 0; kt < 4; ++kt)
#pragma unroll
      for (int r = 0; r < 16; ++r) {
        const float p = __expf(sacc[kt][r] - mnew);
        sacc[kt][r] = p;
        psum += p;
      }
    psum += __shfl_xor(psum, 32);
    if (need) {
      const float alpha = __expf(mrun - mnew);
      mrun = mnew;
      lsum = lsum * alpha + psum;
#pragma unroll
      for (int r = 0; r < 16; ++r) {
        const float ar = __shfl(alpha, (r & 3) + 8 * (r >> 2) + 4 * hi);
        oacc[0][r] *= ar;
        oacc[1][r] *= ar;
      }
    } else {
      lsum += psum;
    }

    union { unsigned int u[4]; bf16x8 v; } paE[4], paO[4];
#pragma unroll
    for (int kt = 0; kt < 4; ++kt) {
      const unsigned int cs0 = pk2(sacc[kt][0], sacc[kt][1]);
      const unsigned int cs1 = pk2(sacc[kt][2], sacc[kt][3]);
      const unsigned int cs2 = pk2(sacc[kt][4], sacc[kt][5]);
      const unsigned int cs3 = pk2(sacc[kt][6], sacc[kt][7]);
      const unsigned int cs4 = pk2(sacc[kt][8], sacc[kt][9]);
      const unsigned int cs5 = pk2(sacc[kt][10], sacc[kt][11]);
      const unsigned int cs6 = pk2(sacc[kt][12], sacc[kt][13]);
      const unsigned int cs7 = pk2(sacc[kt][14], sacc[kt][15]);
      const unsigned int es0 = __shfl_xor(cs0, 32);
      const unsigned int es1 = __shfl_xor(cs1, 32);
      const unsigned int es2 = __shfl_xor(cs2, 32);
      const unsigned int es3 = __shfl_xor(cs3, 32);
      const unsigned int es4 = __shfl_xor(cs4, 32);
      const unsigned int es5 = __shfl_xor(cs5, 32);
      const unsigned int es6 = __shfl_xor(cs6, 32);
      const unsigned int es7 = __shfl_xor(cs7, 32);
      paE[kt].u[0] = hi ? es2 : cs0;
      paE[kt].u[1] = hi ? es3 : cs1;
      paE[kt].u[2] = hi ? cs2 : es0;
      paE[kt].u[3] = hi ? cs3 : es1;
      paO[kt].u[0] = hi ? es6 : cs4;
      paO[kt].u[1] = hi ? es7 : cs5;
      paO[kt].u[2] = hi ? cs6 : es4;
      paO[kt].u[3] = hi ? cs7 : es5;
    }

#pragma unroll
    for (int kt = 0; kt < 4; ++kt)
#pragma unroll
      for (int nt = 0; nt < 2; ++nt) {
        const int vrow = nt * 32 + lq;
        const int vsw = ((vrow & 7) ^ ((vrow >> 3) & 7)) << 4;
        bf16x8 vbE = *(const bf16x8*)(Vt + (vrow * 256 + ((kt * 64 + hi * 16) ^ vsw)));
        oacc[nt] = __builtin_amdgcn_mfma_f32_32x32x16_bf16(paE[kt].v, vbE, oacc[nt], 0, 0, 0);
        bf16x8 vbO = *(const bf16x8*)(Vt + (vrow * 256 + ((kt * 64 + 32 + hi * 16) ^ vsw)));
        oacc[nt] = __builtin_amdgcn_mfma_f32_32x32x16_bf16(paO[kt].v, vbO, oacc[nt], 0, 0, 0);
      }

    if (ktg < 15) {
      char* VtN = smem + 32768 + (cur ^ 1) * 16384;
#pragma unroll
      for (int p = 0; p < 2; ++p) {
        const ushort* vs = (const ushort*)&vreg[p];
#pragma unroll
        for (int e = 0; e < 8; ++e) {
          const int d = vsg[p] * 8 + e;
          *(ushort*)(VtN + d * 256 +
                     ((vk[p] * 2) ^ (((e ^ vsg[p]) & 7) << 4))) = vs[e];
        }
      }
    }

    __syncthreads();
    cur ^= 1;
  }

  const float inv = 1.0f / lsum;
#pragma unroll
  for (int r = 0; r < 16; ++r) {
    const int crow = (r & 3) + 8 * (r >> 2) + 4 * hi;
    const float ir = __shfl(inv, crow);
    const long orow = (long)b * 2048 + qw0 + crow;
#pragma unroll
    for (int nt = 0; nt < 2; ++nt)
      Oout[orow * 1024 + h * 64 + nt * 32 + lq] = __float2bfloat16(oacc[nt][r] * ir);
  }
}

extern "C" void kernel_launch(void* const* d_in, const int* in_sizes, int n_in,
                              void* d_out, int out_size, void* d_ws, size_t ws_size,
                              hipStream_t stream) {
  const float* X = (const float*)d_in[0];
  const int* pmask = (const int*)d_in[1];
  const float* W_Q = (const float*)d_in[2];
  const float* W_K = (const float*)d_in[3];
  const float* W_V = (const float*)d_in[4];
  const float* W_O = (const float*)d_in[5];
  const float* g1 = (const float*)d_in[6];
  const float* b1 = (const float*)d_in[7];
  const float* W1 = (const float*)d_in[8];
  const float* bias1 = (const float*)d_in[9];
  const float* W2 = (const float*)d_in[10];
  const float* bias2 = (const float*)d_in[11];
  const float* g2 = (const float*)d_in[12];
  const float* b2 = (const float*)d_in[13];
  (void)in_sizes; (void)n_in; (void)out_size; (void)ws_size;

  char* ws = (char*)d_ws;
  const size_t MB = 1ull << 20;
  // layout (80 MB):
  //   [0,8): W1_t (dead after FF1; FF2 p1 overlays [0,16))
  //   [8,14): Wqkv_t  [14,16): Wo_t
  //   [16,24): W2_t
  //   [24,32): xn (LN1 out; later LN2 out from fused reduce)
  //   [32,56): QKV (dead after attn; O-proj p1 overlays [32,48);
  //            ff1 (32MB) overlays [32,64) after oproj_reduce_ln)
  //   [56,64): attnb
  //   [64,80): O-proj p0, later FF2 p0
  // post-attention residual lives in d_out (f32 4096x1024).
  bf16* W1_t   = (bf16*)(ws + 0);
  bf16* Wqkv_t = (bf16*)(ws + 8 * MB);
  bf16* Wo_t   = (bf16*)(ws + 14 * MB);
  bf16* W2_t   = (bf16*)(ws + 16 * MB);
  bf16* xn     = (bf16*)(ws + 24 * MB);
  bf16* QKV    = (bf16*)(ws + 32 * MB);
  bf16* attnb  = (bf16*)(ws + 56 * MB);
  bf16* ff1    = (bf16*)(ws + 32 * MB);
  float* p0o   = (float*)(ws + 64 * MB);  // O-proj partial 0
  float* p1o   = (float*)(ws + 32 * MB);  // O-proj partial 1 (over dead QKV)
  float* p0    = (float*)(ws + 64 * MB);  // FF2 partial 0
  float* p1    = (float*)(ws + 0);        // FF2 partial 1 (over dead W1_t)
  float* res1  = (float*)d_out;

  transpose_all<<<12288, 256, 0, stream>>>(W_Q, W_K, W_V, W_O, W1, W2,
                                           Wqkv_t, W1_t, W2_t);
  ln_kernel<<<4096, 256, 0, stream>>>(X, g1, b1, xn);
  gemm_bt<0, 1><<<32 * 24, 256, 0, stream>>>(xn, Wqkv_t, 4096, 3072, 1024, 1024, 1024,
                                             nullptr, nullptr, nullptr, QKV);
  attn_kernel<<<dim3(32, 8), 512, 0, stream>>>(QKV, pmask, attnb);
  // O projection split-K=2 (slices of 512), raw partials
  gemm_bt<4, 2><<<2 * 32 * 8, 256, 0, stream>>>(attnb, Wo_t, 4096, 1024, 512, 1024, 1024,
                                                nullptr, nullptr, p1o, p0o);
  // fused: res1 = p0o+p1o+X ; xn = LN2(res1)
  oproj_reduce_ln<<<4096, 256, 0, stream>>>(p0o, p1o, X, g2, b2, res1, xn);
  gemm_bt<2, 1><<<32 * 32, 256, 0, stream>>>(xn, W1_t, 4096, 4096, 1024, 1024, 1024,
                                             bias1, nullptr, nullptr, ff1);
  gemm_bt<5, 2><<<2 * 32 * 8, 256, 0, stream>>>(ff1, W2_t, 4096, 1024, 2048, 4096, 4096,
                                                bias2, res1, p1, p0);
  ff2_reduce<<<4096, 256, 0, stream>>>(p0, p1, res1);
}

// Round 10
// 286.982 us; speedup vs baseline: 1.1282x; 1.0095x over previous
//
#include <hip/hip_runtime.h>
#include <hip/hip_bf16.h>

// EncoderLayer on MI355X (gfx950).
// B=2, S=2048, D=1024, H=16, DK=64. M = B*S = 4096.
// R10: attention + T5 (s_setprio(1) around QK^T and PV MFMA clusters; m191
//      attn-proven +4-7%) and T13 defer-rescale THR=8 (isolated this time;
//      m214v23 +5%). All other kernels identical to R9.

using bf16 = __hip_bfloat16;
typedef __attribute__((ext_vector_type(4))) float f32x4;
typedef __attribute__((ext_vector_type(16))) float f32x16;
typedef __attribute__((ext_vector_type(8))) short bf16x8;

#define DEVI static __device__ __forceinline__

DEVI void async_copy16(const void* g, void* l) {
  __builtin_amdgcn_global_load_lds(
      (const __attribute__((address_space(1))) void*)g,
      (__attribute__((address_space(3))) void*)l, 16, 0, 0);
}

DEVI ushort f2bf_bits(float v) {
  __hip_bfloat16 h = __float2bfloat16(v);
  return *reinterpret_cast<ushort*>(&h);
}

DEVI float bfbits2f(ushort u) {
  union { float f; unsigned int i; } x;
  x.i = ((unsigned int)u) << 16;
  return x.f;
}

DEVI unsigned int pk2(float lo, float hi) {
  return (unsigned int)f2bf_bits(lo) | ((unsigned int)f2bf_bits(hi) << 16);
}

// ---------------- LayerNorm: f32 in (rows x 1024) -> bf16 out ----------------
__global__ __launch_bounds__(256) void ln_kernel(
    const float* __restrict__ in, const float* __restrict__ gamma,
    const float* __restrict__ beta, bf16* __restrict__ out) {
  const long row = blockIdx.x;
  const int t = threadIdx.x;
  float4 x = ((const float4*)(in + row * 1024))[t];
  float s = x.x + x.y + x.z + x.w;
  float s2 = x.x * x.x + x.y * x.y + x.z * x.z + x.w * x.w;
#pragma unroll
  for (int m = 1; m < 64; m <<= 1) {
    s += __shfl_xor(s, m);
    s2 += __shfl_xor(s2, m);
  }
  __shared__ float red[8];
  const int w = t >> 6, l = t & 63;
  if (l == 0) { red[w] = s; red[4 + w] = s2; }
  __syncthreads();
  s = red[0] + red[1] + red[2] + red[3];
  s2 = red[4] + red[5] + red[6] + red[7];
  const float mean = s * (1.0f / 1024.0f);
  const float var = s2 * (1.0f / 1024.0f) - mean * mean;
  const float rstd = rsqrtf(var + 1e-6f);
  float4 g4 = ((const float4*)gamma)[t];
  float4 b4 = ((const float4*)beta)[t];
  union { ushort h[4]; uint2 u; } o;
  o.h[0] = f2bf_bits(g4.x * (x.x - mean) * rstd + b4.x);
  o.h[1] = f2bf_bits(g4.y * (x.y - mean) * rstd + b4.y);
  o.h[2] = f2bf_bits(g4.z * (x.z - mean) * rstd + b4.z);
  o.h[3] = f2bf_bits(g4.w * (x.w - mean) * rstd + b4.w);
  ((uint2*)(out + row * 1024))[t] = o.u;
}

// ---- O-proj split-K reduce fused with LN2: res = p0+p1+X; xn = LN(res) ----
__global__ __launch_bounds__(256) void oproj_reduce_ln(
    const float* __restrict__ p0, const float* __restrict__ p1,
    const float* __restrict__ X, const float* __restrict__ gamma,
    const float* __restrict__ beta, float* __restrict__ res_out,
    bf16* __restrict__ xn_out) {
  const long row = blockIdx.x;
  const int t = threadIdx.x;
  const long i = row * 256 + t;
  const float4 a = ((const float4*)p0)[i];
  const float4 b = ((const float4*)p1)[i];
  const float4 c = ((const float4*)X)[i];
  float4 x;
  x.x = a.x + b.x + c.x; x.y = a.y + b.y + c.y;
  x.z = a.z + b.z + c.z; x.w = a.w + b.w + c.w;
  ((float4*)res_out)[i] = x;
  float s = x.x + x.y + x.z + x.w;
  float s2 = x.x * x.x + x.y * x.y + x.z * x.z + x.w * x.w;
#pragma unroll
  for (int m = 1; m < 64; m <<= 1) {
    s += __shfl_xor(s, m);
    s2 += __shfl_xor(s2, m);
  }
  __shared__ float red[8];
  const int w = t >> 6, l = t & 63;
  if (l == 0) { red[w] = s; red[4 + w] = s2; }
  __syncthreads();
  s = red[0] + red[1] + red[2] + red[3];
  s2 = red[4] + red[5] + red[6] + red[7];
  const float mean = s * (1.0f / 1024.0f);
  const float var = s2 * (1.0f / 1024.0f) - mean * mean;
  const float rstd = rsqrtf(var + 1e-6f);
  float4 g4 = ((const float4*)gamma)[t];
  float4 b4 = ((const float4*)beta)[t];
  union { ushort h[4]; uint2 u; } o;
  o.h[0] = f2bf_bits(g4.x * (x.x - mean) * rstd + b4.x);
  o.h[1] = f2bf_bits(g4.y * (x.y - mean) * rstd + b4.y);
  o.h[2] = f2bf_bits(g4.z * (x.z - mean) * rstd + b4.z);
  o.h[3] = f2bf_bits(g4.w * (x.w - mean) * rstd + b4.w);
  ((uint2*)(xn_out + row * 1024))[t] = o.u;
}

// -------- unified weight transpose: f32 (K x N) -> bf16 (N x K), 32x32 -------
__global__ __launch_bounds__(256) void transpose_all(
    const float* __restrict__ q, const float* __restrict__ k,
    const float* __restrict__ v, const float* __restrict__ o,
    const float* __restrict__ w1, const float* __restrict__ w2,
    bf16* __restrict__ wqkvo, bf16* __restrict__ w1t, bf16* __restrict__ w2t) {
  const int tid = blockIdx.x;
  const float* W;
  bf16* Wt;
  int K, N, n0, k0;
  if (tid < 4096) {
    const int z = tid >> 10, r = tid & 1023;
    W = (z == 0) ? q : (z == 1) ? k : (z == 2) ? v : o;
    Wt = wqkvo + (size_t)z * 1024 * 1024;
    K = 1024; N = 1024; n0 = (r & 31) << 5; k0 = (r >> 5) << 5;
  } else if (tid < 8192) {
    const int r = tid - 4096;
    W = w1; Wt = w1t; K = 1024; N = 4096;
    n0 = (r & 127) << 5; k0 = (r >> 7) << 5;
  } else {
    const int r = tid - 8192;
    W = w2; Wt = w2t; K = 4096; N = 1024;
    n0 = (r & 31) << 5; k0 = (r >> 5) << 5;
  }
  __shared__ float tile[32][33];
  const int tx = threadIdx.x & 31, ty = threadIdx.x >> 5;
#pragma unroll
  for (int i = 0; i < 32; i += 8)
    tile[ty + i][tx] = W[(long)(k0 + ty + i) * N + n0 + tx];
  __syncthreads();
#pragma unroll
  for (int i = 0; i < 32; i += 8)
    Wt[(long)(n0 + ty + i) * K + k0 + tx] = __float2bfloat16(tile[tx][ty + i]);
}

// ---------------- GEMM: C(MxN) = A(MxK,bf16) * Bt(NxK,bf16)^T ----------------
// 128x128 tile, BK=64, 4 waves. Swizzled async staging (attention-proven):
// LDS tile [128 rows][64 elems]; element (r, g*8+e) at byte
// r*128 + (g*16 ^ ((r&7)<<4)) + e*2; staged by global_load_lds with linear
// dest chunk c = cr*256+t and pre-swizzled source colgroup (t&7)^((t>>3)&7).
// XCD-aware bijective blockIdx swizzle. KSPLIT=2: slice sl reads K-cols
// [sl*K,(sl+1)*K); sl0 -> Cout, sl1 -> pother.
// EPI: 0 = bf16; 2 = +bias sigmoid-GELU bf16; 4 = raw f32 partial;
//      5 = split-K partial, sl0 adds bias+res.
template <int EPI, int KSPLIT>
__global__ __launch_bounds__(256) void gemm_bt(
    const bf16* __restrict__ A, const bf16* __restrict__ Bt,
    const int M, const int N, const int K, const int lda, const int ldb,
    const float* __restrict__ bias, const float* __restrict__ res,
    float* __restrict__ pother, void* __restrict__ Cout) {
  __shared__ bf16 As[128 * 64];
  __shared__ bf16 Bs[128 * 64];
  const int t = threadIdx.x;
  const int w = t >> 6, l = t & 63;
  const int nb = N >> 7;
  const int cpx = gridDim.x >> 3;
  int bidx = (blockIdx.x & 7) * cpx + (blockIdx.x >> 3);
  int sl = 0;
  if (KSPLIT == 2) {
    const int half = gridDim.x >> 1;
    sl = bidx >= half;
    bidx -= sl * half;
  }
  const int bm = bidx / nb, bn = bidx % nb;
  const long row0 = (long)bm << 7, col0 = (long)bn << 7;
  const int wr = (w >> 1) << 6, wc = (w & 1) << 6;
  const int lr = l & 15;
  const int lkb = (l >> 4) << 4;

  f32x4 acc[4][4];
#pragma unroll
  for (int m = 0; m < 4; ++m)
#pragma unroll
    for (int n = 0; n < 4; ++n) acc[m][n] = (f32x4){0.f, 0.f, 0.f, 0.f};

  const int rA = t >> 3;
  const int g = (t & 7) ^ ((t >> 3) & 7);
  const bf16* gA = A + (row0 + rA) * (long)lda + (long)sl * K + g * 8;
  const bf16* gB = Bt + (col0 + rA) * (long)ldb + (long)sl * K + g * 8;
  char* lA = (char*)As + t * 16;
  char* lB = (char*)Bs + t * 16;

  for (int k0 = 0; k0 < K; k0 += 64) {
    __syncthreads();
#pragma unroll
    for (int cr = 0; cr < 4; ++cr) {
      async_copy16(gA + (long)cr * 32 * lda + k0, lA + cr * 4096);
      async_copy16(gB + (long)cr * 32 * ldb + k0, lB + cr * 4096);
    }
    __syncthreads();
#pragma unroll
    for (int ks = 0; ks < 2; ++ks) {
      bf16x8 af[4], bfr[4];
#pragma unroll
      for (int m = 0; m < 4; ++m) {
        const int row = wr + m * 16 + lr;
        af[m] = *(const bf16x8*)((const char*)As +
            (row * 128 + ((ks * 64 + lkb) ^ ((row & 7) << 4))));
      }
#pragma unroll
      for (int n = 0; n < 4; ++n) {
        const int row = wc + n * 16 + lr;
        bfr[n] = *(const bf16x8*)((const char*)Bs +
            (row * 128 + ((ks * 64 + lkb) ^ ((row & 7) << 4))));
      }
#pragma unroll
      for (int m = 0; m < 4; ++m)
#pragma unroll
        for (int n = 0; n < 4; ++n)
          acc[m][n] = __builtin_amdgcn_mfma_f32_16x16x32_bf16(af[m], bfr[n], acc[m][n], 0, 0, 0);
    }
  }

  bf16* Cb = (bf16*)Cout;
  float* Cf = (float*)Cout;
  if ((EPI == 4 || EPI == 5) && sl == 1) Cf = pother;
#pragma unroll
  for (int m = 0; m < 4; ++m) {
#pragma unroll
    for (int r = 0; r < 4; ++r) {
      const long crow = row0 + wr + m * 16 + ((l >> 4) << 2) + r;
      const long rbase = crow * N;
#pragma unroll
      for (int n = 0; n < 4; ++n) {
        const long ccol = col0 + wc + n * 16 + lr;
        float v = acc[m][n][r];
        if (EPI == 2) {
          const float vv = v + bias[ccol];
          const float u2 = vv * (1.5957691216f + 0.0713548162f * vv * vv);
          v = vv / (1.0f + __expf(-u2));
        }
        if (EPI == 5 && sl == 0) v += bias[ccol] + res[rbase + ccol];
        if (EPI == 0 || EPI == 2)
          Cb[rbase + ccol] = __float2bfloat16(v);
        else
          Cf[rbase + ccol] = v;
      }
    }
  }
}

// ---- split-K reduce: out = p0 + p1 (p0 already holds bias+residual) ----
__global__ __launch_bounds__(256) void ff2_reduce(
    const float* __restrict__ p0, const float* __restrict__ p1,
    float* __restrict__ out) {
  const int idx = blockIdx.x * 256 + threadIdx.x;
  const float4 x = ((const float4*)p0)[idx];
  const float4 y = ((const float4*)p1)[idx];
  float4 a;
  a.x = x.x + y.x; a.y = x.y + y.y; a.z = x.z + y.z; a.w = x.w + y.w;
  ((float4*)out)[idx] = a;
}

// ---------------- flash attention: 8 waves, 256 q-rows, KVBLK=128 ------------
// R10: + setprio(1) around MFMA clusters (T5), defer-rescale THR=8 (T13).
__global__ __launch_bounds__(512) void attn_kernel(
    const bf16* __restrict__ QKV, const int* __restrict__ pmask,
    bf16* __restrict__ Oout) {
  const int bh = blockIdx.x;
  const int b = bh >> 4, h = bh & 15;
  const int q0 = blockIdx.y << 8;
  const int t = threadIdx.x;
  const int w = t >> 6, l = t & 63;
  const int lq = l & 31, hi = l >> 5;

  __shared__ __align__(16) char smem[65536];

  const long base = (long)b * 2048 * 3072;
  const bf16* Qg = QKV + base + h * 64;
  const bf16* Kg = QKV + base + 1024 + h * 64;
  const bf16* Vg = QKV + base + 2048 + h * 64;

  int kSrc[2], kDst[2], vk[2], vsg[2];
#pragma unroll
  for (int p = 0; p < 2; ++p) {
    const int c = p * 512 + t;
    const int kr = c >> 3;
    kSrc[p] = kr * 3072 + (((c & 7) ^ (kr & 7)) << 3);
    kDst[p] = c * 16;
    vk[p] = c >> 3;
    vsg[p] = c & 7;
  }

  const int qw0 = q0 + w * 32;
  bf16x8 qf[4];
#pragma unroll
  for (int dc = 0; dc < 4; ++dc) {
    uint4 raw = *(const uint4*)(Qg + (long)(qw0 + lq) * 3072 + dc * 16 + hi * 8);
    union { uint4 u4; ushort us[8]; } in; in.u4 = raw;
    union { bf16x8 v; ushort us[8]; } o;
#pragma unroll
    for (int e = 0; e < 8; ++e) o.us[e] = f2bf_bits(0.125f * bfbits2f(in.us[e]));
    qf[dc] = o.v;
  }

  union { unsigned int u[4]; bf16x8 v; } bones;
  bones.u[0] = (hi == 0) ? 0x00003F80u : 0u;
  bones.u[1] = bones.u[2] = bones.u[3] = 0u;

  uint4 vreg[2];
#pragma unroll
  for (int p = 0; p < 2; ++p) {
    vreg[p] = *(const uint4*)(Vg + (long)vk[p] * 3072 + vsg[p] * 8);
    async_copy16(Kg + kSrc[p], smem + kDst[p]);
  }
#pragma unroll
  for (int p = 0; p < 2; ++p) {
    const ushort* vs = (const ushort*)&vreg[p];
#pragma unroll
    for (int e = 0; e < 8; ++e) {
      const int d = vsg[p] * 8 + e;
      *(ushort*)(smem + 32768 + d * 256 +
                 ((vk[p] * 2) ^ (((e ^ vsg[p]) & 7) << 4))) = vs[e];
    }
  }

  f32x16 oacc[2];
#pragma unroll
  for (int nt = 0; nt < 2; ++nt)
#pragma unroll
    for (int r = 0; r < 16; ++r) oacc[nt][r] = 0.f;
  float mrun = -3.0e38f, lsum = 0.f;
  int cur = 0;

  __syncthreads();

  for (int ktg = 0; ktg < 16; ++ktg) {
    if (ktg < 15) {
      const long nrow0 = (long)(ktg + 1) * 128 * 3072;
#pragma unroll
      for (int p = 0; p < 2; ++p) {
        vreg[p] = *(const uint4*)(Vg + nrow0 + (long)vk[p] * 3072 + vsg[p] * 8);
        async_copy16(Kg + nrow0 + kSrc[p], smem + (cur ^ 1) * 16384 + kDst[p]);
      }
    }
    const int k0 = ktg << 7;
    const char* Ks = smem + cur * 16384;
    const char* Vt = smem + 32768 + cur * 16384;

    // ---- S^T = K Q^T (T5: boost priority through the MFMA cluster) ----
    f32x16 sacc[4];
    __builtin_amdgcn_s_setprio(1);
#pragma unroll
    for (int kt = 0; kt < 4; ++kt) {
#pragma unroll
      for (int r = 0; r < 16; ++r) sacc[kt][r] = 0.f;
#pragma unroll
      for (int dc = 0; dc < 4; ++dc) {
        bf16x8 ka = *(const bf16x8*)(Ks +
            ((kt * 32 + lq) * 128 + ((dc * 32 + hi * 16) ^ ((lq & 7) << 4))));
        sacc[kt] = __builtin_amdgcn_mfma_f32_32x32x16_bf16(ka, qf[dc], sacc[kt], 0, 0, 0);
      }
      const int mv = pmask[b * 2048 + k0 + kt * 32 + lq];
      union { unsigned int u[4]; bf16x8 v; } aadd;
      aadd.u[0] = (hi == 0 && mv == 0) ? (unsigned int)f2bf_bits(-1.0e9f) : 0u;
      aadd.u[1] = aadd.u[2] = aadd.u[3] = 0u;
      sacc[kt] = __builtin_amdgcn_mfma_f32_32x32x16_bf16(aadd.v, bones.v, sacc[kt], 0, 0, 0);
    }
    __builtin_amdgcn_s_setprio(0);

    // ---- online softmax; defer-rescale threshold 8 (T13) ----
    float tmax = -3.0e38f;
#pragma unroll
    for (int kt = 0; kt < 4; ++kt)
#pragma unroll
      for (int r = 0; r < 16; ++r) tmax = fmaxf(tmax, sacc[kt][r]);
    tmax = fmaxf(tmax, __shfl_xor(tmax, 32));
    const bool need = (bool)__any(tmax > mrun + 8.0f);
    const float mnew = need ? fmaxf(mrun, tmax) : mrun;
    float psum = 0.f;
#pragma unroll
    for (int kt = 0; kt < 4; ++kt)
#pragma unroll
      for (int r = 0; r < 16; ++r) {
        const float p = __expf(sacc[kt][r] - mnew);
        sacc[kt][r] = p;
        psum += p;
      }
    psum += __shfl_xor(psum, 32);
    if (need) {
      const float alpha = __expf(mrun - mnew);
      mrun = mnew;
      lsum = lsum * alpha + psum;
#pragma unroll
      for (int r = 0; r < 16; ++r) {
        const float ar = __shfl(alpha, (r & 3) + 8 * (r >> 2) + 4 * hi);
        oacc[0][r] *= ar;
        oacc[1][r] *= ar;
      }
    } else {
      lsum += psum;
    }

    union { unsigned int u[4]; bf16x8 v; } paE[4], paO[4];
#pragma unroll
    for (int kt = 0; kt < 4; ++kt) {
      const unsigned int cs0 = pk2(sacc[kt][0], sacc[kt][1]);
      const unsigned int cs1 = pk2(sacc[kt][2], sacc[kt][3]);
      const unsigned int cs2 = pk2(sacc[kt][4], sacc[kt][5]);
      const unsigned int cs3 = pk2(sacc[kt][6], sacc[kt][7]);
      const unsigned int cs4 = pk2(sacc[kt][8], sacc[kt][9]);
      const unsigned int cs5 = pk2(sacc[kt][10], sacc[kt][11]);
      const unsigned int cs6 = pk2(sacc[kt][12], sacc[kt][13]);
      const unsigned int cs7 = pk2(sacc[kt][14], sacc[kt][15]);
      const unsigned int es0 = __shfl_xor(cs0, 32);
      const unsigned int es1 = __shfl_xor(cs1, 32);
      const unsigned int es2 = __shfl_xor(cs2, 32);
      const unsigned int es3 = __shfl_xor(cs3, 32);
      const unsigned int es4 = __shfl_xor(cs4, 32);
      const unsigned int es5 = __shfl_xor(cs5, 32);
      const unsigned int es6 = __shfl_xor(cs6, 32);
      const unsigned int es7 = __shfl_xor(cs7, 32);
      paE[kt].u[0] = hi ? es2 : cs0;
      paE[kt].u[1] = hi ? es3 : cs1;
      paE[kt].u[2] = hi ? cs2 : es0;
      paE[kt].u[3] = hi ? cs3 : es1;
      paO[kt].u[0] = hi ? es6 : cs4;
      paO[kt].u[1] = hi ? es7 : cs5;
      paO[kt].u[2] = hi ? cs6 : es4;
      paO[kt].u[3] = hi ? cs7 : es5;
    }

    // ---- O += P V (T5 again) ----
    __builtin_amdgcn_s_setprio(1);
#pragma unroll
    for (int kt = 0; kt < 4; ++kt)
#pragma unroll
      for (int nt = 0; nt < 2; ++nt) {
        const int vrow = nt * 32 + lq;
        const int vsw = ((vrow & 7) ^ ((vrow >> 3) & 7)) << 4;
        bf16x8 vbE = *(const bf16x8*)(Vt + (vrow * 256 + ((kt * 64 + hi * 16) ^ vsw)));
        oacc[nt] = __builtin_amdgcn_mfma_f32_32x32x16_bf16(paE[kt].v, vbE, oacc[nt], 0, 0, 0);
        bf16x8 vbO = *(const bf16x8*)(Vt + (vrow * 256 + ((kt * 64 + 32 + hi * 16) ^ vsw)));
        oacc[nt] = __builtin_amdgcn_mfma_f32_32x32x16_bf16(paO[kt].v, vbO, oacc[nt], 0, 0, 0);
      }
    __builtin_amdgcn_s_setprio(0);

    if (ktg < 15) {
      char* VtN = smem + 32768 + (cur ^ 1) * 16384;
#pragma unroll
      for (int p = 0; p < 2; ++p) {
        const ushort* vs = (const ushort*)&vreg[p];
#pragma unroll
        for (int e = 0; e < 8; ++e) {
          const int d = vsg[p] * 8 + e;
          *(ushort*)(VtN + d * 256 +
                     ((vk[p] * 2) ^ (((e ^ vsg[p]) & 7) << 4))) = vs[e];
        }
      }
    }

    __syncthreads();
    cur ^= 1;
  }

  const float inv = 1.0f / lsum;
#pragma unroll
  for (int r = 0; r < 16; ++r) {
    const int crow = (r & 3) + 8 * (r >> 2) + 4 * hi;
    const float ir = __shfl(inv, crow);
    const long orow = (long)b * 2048 + qw0 + crow;
#pragma unroll
    for (int nt = 0; nt < 2; ++nt)
      Oout[orow * 1024 + h * 64 + nt * 32 + lq] = __float2bfloat16(oacc[nt][r] * ir);
  }
}

extern "C" void kernel_launch(void* const* d_in, const int* in_sizes, int n_in,
                              void* d_out, int out_size, void* d_ws, size_t ws_size,
                              hipStream_t stream) {
  const float* X = (const float*)d_in[0];
  const int* pmask = (const int*)d_in[1];
  const float* W_Q = (const float*)d_in[2];
  const float* W_K = (const float*)d_in[3];
  const float* W_V = (const float*)d_in[4];
  const float* W_O = (const float*)d_in[5];
  const float* g1 = (const float*)d_in[6];
  const float* b1 = (const float*)d_in[7];
  const float* W1 = (const float*)d_in[8];
  const float* bias1 = (const float*)d_in[9];
  const float* W2 = (const float*)d_in[10];
  const float* bias2 = (const float*)d_in[11];
  const float* g2 = (const float*)d_in[12];
  const float* b2 = (const float*)d_in[13];
  (void)in_sizes; (void)n_in; (void)out_size; (void)ws_size;

  char* ws = (char*)d_ws;
  const size_t MB = 1ull << 20;
  bf16* W1_t   = (bf16*)(ws + 0);
  bf16* Wqkv_t = (bf16*)(ws + 8 * MB);
  bf16* Wo_t   = (bf16*)(ws + 14 * MB);
  bf16* W2_t   = (bf16*)(ws + 16 * MB);
  bf16* xn     = (bf16*)(ws + 24 * MB);
  bf16* QKV    = (bf16*)(ws + 32 * MB);
  bf16* attnb  = (bf16*)(ws + 56 * MB);
  bf16* ff1    = (bf16*)(ws + 32 * MB);
  float* p0o   = (float*)(ws + 64 * MB);
  float* p1o   = (float*)(ws + 32 * MB);
  float* p0    = (float*)(ws + 64 * MB);
  float* p1    = (float*)(ws + 0);
  float* res1  = (float*)d_out;

  transpose_all<<<12288, 256, 0, stream>>>(W_Q, W_K, W_V, W_O, W1, W2,
                                           Wqkv_t, W1_t, W2_t);
  ln_kernel<<<4096, 256, 0, stream>>>(X, g1, b1, xn);
  gemm_bt<0, 1><<<32 * 24, 256, 0, stream>>>(xn, Wqkv_t, 4096, 3072, 1024, 1024, 1024,
                                             nullptr, nullptr, nullptr, QKV);
  attn_kernel<<<dim3(32, 8), 512, 0, stream>>>(QKV, pmask, attnb);
  gemm_bt<4, 2><<<2 * 32 * 8, 256, 0, stream>>>(attnb, Wo_t, 4096, 1024, 512, 1024, 1024,
                                                nullptr, nullptr, p1o, p0o);
  oproj_reduce_ln<<<4096, 256, 0, stream>>>(p0o, p1o, X, g2, b2, res1, xn);
  gemm_bt<2, 1><<<32 * 32, 256, 0, stream>>>(xn, W1_t, 4096, 4096, 1024, 1024, 1024,
                                             bias1, nullptr, nullptr, ff1);
  gemm_bt<5, 2><<<2 * 32 * 8, 256, 0, stream>>>(ff1, W2_t, 4096, 1024, 2048, 4096, 4096,
                                                bias2, res1, p1, p0);
  ff2_reduce<<<4096, 256, 0, stream>>>(p0, p1, res1);
}

// Round 11
// 267.591 us; speedup vs baseline: 1.2099x; 1.0725x over previous
//
#include <hip/hip_runtime.h>
#include <hip/hip_bf16.h>

// EncoderLayer on MI355X (gfx950).
// B=2, S=2048, D=1024, H=16, DK=64. M = B*S = 4096.
// R11: GEMM -> counted-vmcnt double-buffered staging (T3/T4 minimal 2-phase):
//      STAGE(next) issued before compute, s_waitcnt vmcnt(8) (never 0 in-loop),
//      raw s_barrier pair per K-step. Loads land under previous iter's compute.
//      LDS 2x32KB dbuf (2 blocks/CU). Compute/swizzle/epilogue identical to R9.
//      Attention unchanged from R10 (T5 setprio + T13 defer-rescale).

using bf16 = __hip_bfloat16;
typedef __attribute__((ext_vector_type(4))) float f32x4;
typedef __attribute__((ext_vector_type(16))) float f32x16;
typedef __attribute__((ext_vector_type(8))) short bf16x8;

#define DEVI static __device__ __forceinline__

DEVI void async_copy16(const void* g, void* l) {
  __builtin_amdgcn_global_load_lds(
      (const __attribute__((address_space(1))) void*)g,
      (__attribute__((address_space(3))) void*)l, 16, 0, 0);
}

DEVI ushort f2bf_bits(float v) {
  __hip_bfloat16 h = __float2bfloat16(v);
  return *reinterpret_cast<ushort*>(&h);
}

DEVI float bfbits2f(ushort u) {
  union { float f; unsigned int i; } x;
  x.i = ((unsigned int)u) << 16;
  return x.f;
}

DEVI unsigned int pk2(float lo, float hi) {
  return (unsigned int)f2bf_bits(lo) | ((unsigned int)f2bf_bits(hi) << 16);
}

// ---------------- LayerNorm: f32 in (rows x 1024) -> bf16 out ----------------
__global__ __launch_bounds__(256) void ln_kernel(
    const float* __restrict__ in, const float* __restrict__ gamma,
    const float* __restrict__ beta, bf16* __restrict__ out) {
  const long row = blockIdx.x;
  const int t = threadIdx.x;
  float4 x = ((const float4*)(in + row * 1024))[t];
  float s = x.x + x.y + x.z + x.w;
  float s2 = x.x * x.x + x.y * x.y + x.z * x.z + x.w * x.w;
#pragma unroll
  for (int m = 1; m < 64; m <<= 1) {
    s += __shfl_xor(s, m);
    s2 += __shfl_xor(s2, m);
  }
  __shared__ float red[8];
  const int w = t >> 6, l = t & 63;
  if (l == 0) { red[w] = s; red[4 + w] = s2; }
  __syncthreads();
  s = red[0] + red[1] + red[2] + red[3];
  s2 = red[4] + red[5] + red[6] + red[7];
  const float mean = s * (1.0f / 1024.0f);
  const float var = s2 * (1.0f / 1024.0f) - mean * mean;
  const float rstd = rsqrtf(var + 1e-6f);
  float4 g4 = ((const float4*)gamma)[t];
  float4 b4 = ((const float4*)beta)[t];
  union { ushort h[4]; uint2 u; } o;
  o.h[0] = f2bf_bits(g4.x * (x.x - mean) * rstd + b4.x);
  o.h[1] = f2bf_bits(g4.y * (x.y - mean) * rstd + b4.y);
  o.h[2] = f2bf_bits(g4.z * (x.z - mean) * rstd + b4.z);
  o.h[3] = f2bf_bits(g4.w * (x.w - mean) * rstd + b4.w);
  ((uint2*)(out + row * 1024))[t] = o.u;
}

// ---- O-proj split-K reduce fused with LN2: res = p0+p1+X; xn = LN(res) ----
__global__ __launch_bounds__(256) void oproj_reduce_ln(
    const float* __restrict__ p0, const float* __restrict__ p1,
    const float* __restrict__ X, const float* __restrict__ gamma,
    const float* __restrict__ beta, float* __restrict__ res_out,
    bf16* __restrict__ xn_out) {
  const long row = blockIdx.x;
  const int t = threadIdx.x;
  const long i = row * 256 + t;
  const float4 a = ((const float4*)p0)[i];
  const float4 b = ((const float4*)p1)[i];
  const float4 c = ((const float4*)X)[i];
  float4 x;
  x.x = a.x + b.x + c.x; x.y = a.y + b.y + c.y;
  x.z = a.z + b.z + c.z; x.w = a.w + b.w + c.w;
  ((float4*)res_out)[i] = x;
  float s = x.x + x.y + x.z + x.w;
  float s2 = x.x * x.x + x.y * x.y + x.z * x.z + x.w * x.w;
#pragma unroll
  for (int m = 1; m < 64; m <<= 1) {
    s += __shfl_xor(s, m);
    s2 += __shfl_xor(s2, m);
  }
  __shared__ float red[8];
  const int w = t >> 6, l = t & 63;
  if (l == 0) { red[w] = s; red[4 + w] = s2; }
  __syncthreads();
  s = red[0] + red[1] + red[2] + red[3];
  s2 = red[4] + red[5] + red[6] + red[7];
  const float mean = s * (1.0f / 1024.0f);
  const float var = s2 * (1.0f / 1024.0f) - mean * mean;
  const float rstd = rsqrtf(var + 1e-6f);
  float4 g4 = ((const float4*)gamma)[t];
  float4 b4 = ((const float4*)beta)[t];
  union { ushort h[4]; uint2 u; } o;
  o.h[0] = f2bf_bits(g4.x * (x.x - mean) * rstd + b4.x);
  o.h[1] = f2bf_bits(g4.y * (x.y - mean) * rstd + b4.y);
  o.h[2] = f2bf_bits(g4.z * (x.z - mean) * rstd + b4.z);
  o.h[3] = f2bf_bits(g4.w * (x.w - mean) * rstd + b4.w);
  ((uint2*)(xn_out + row * 1024))[t] = o.u;
}

// -------- unified weight transpose: f32 (K x N) -> bf16 (N x K), 32x32 -------
__global__ __launch_bounds__(256) void transpose_all(
    const float* __restrict__ q, const float* __restrict__ k,
    const float* __restrict__ v, const float* __restrict__ o,
    const float* __restrict__ w1, const float* __restrict__ w2,
    bf16* __restrict__ wqkvo, bf16* __restrict__ w1t, bf16* __restrict__ w2t) {
  const int tid = blockIdx.x;
  const float* W;
  bf16* Wt;
  int K, N, n0, k0;
  if (tid < 4096) {
    const int z = tid >> 10, r = tid & 1023;
    W = (z == 0) ? q : (z == 1) ? k : (z == 2) ? v : o;
    Wt = wqkvo + (size_t)z * 1024 * 1024;
    K = 1024; N = 1024; n0 = (r & 31) << 5; k0 = (r >> 5) << 5;
  } else if (tid < 8192) {
    const int r = tid - 4096;
    W = w1; Wt = w1t; K = 1024; N = 4096;
    n0 = (r & 127) << 5; k0 = (r >> 7) << 5;
  } else {
    const int r = tid - 8192;
    W = w2; Wt = w2t; K = 4096; N = 1024;
    n0 = (r & 31) << 5; k0 = (r >> 5) << 5;
  }
  __shared__ float tile[32][33];
  const int tx = threadIdx.x & 31, ty = threadIdx.x >> 5;
#pragma unroll
  for (int i = 0; i < 32; i += 8)
    tile[ty + i][tx] = W[(long)(k0 + ty + i) * N + n0 + tx];
  __syncthreads();
#pragma unroll
  for (int i = 0; i < 32; i += 8)
    Wt[(long)(n0 + ty + i) * K + k0 + tx] = __float2bfloat16(tile[tx][ty + i]);
}

// ---------------- GEMM: C(MxN) = A(MxK,bf16) * Bt(NxK,bf16)^T ----------------
// 128x128 tile, BK=64, 4 waves. R11: counted-vmcnt DOUBLE-BUFFERED staging:
// per K-step: STAGE(next tile -> other buf, 8 global_load_lds), then
// s_waitcnt vmcnt(8) (current tile landed, next still in flight), raw
// s_barrier, compute, raw s_barrier (frees buffer for overwrite next iter).
// LDS [128][64] per operand, swizzled: elem (r, g*8+e) at byte
// r*128 + (g*16 ^ ((r&7)<<4)) + e*2 (pre-swizzled global source, linear dest).
// EPI: 0 = bf16; 2 = +bias sigmoid-GELU bf16; 4 = raw f32 partial;
//      5 = split-K partial, sl0 adds bias+res.
template <int EPI, int KSPLIT>
__global__ __launch_bounds__(256) void gemm_bt(
    const bf16* __restrict__ A, const bf16* __restrict__ Bt,
    const int M, const int N, const int K, const int lda, const int ldb,
    const float* __restrict__ bias, const float* __restrict__ res,
    float* __restrict__ pother, void* __restrict__ Cout) {
  __shared__ __align__(16) char gsmem[65536];  // 2 bufs x (A 16K | B 16K)
  const int t = threadIdx.x;
  const int w = t >> 6, l = t & 63;
  const int nb = N >> 7;
  const int cpx = gridDim.x >> 3;
  int bidx = (blockIdx.x & 7) * cpx + (blockIdx.x >> 3);
  int sl = 0;
  if (KSPLIT == 2) {
    const int half = gridDim.x >> 1;
    sl = bidx >= half;
    bidx -= sl * half;
  }
  const int bm = bidx / nb, bn = bidx % nb;
  const long row0 = (long)bm << 7, col0 = (long)bn << 7;
  const int wr = (w >> 1) << 6, wc = (w & 1) << 6;
  const int lr = l & 15;
  const int lkb = (l >> 4) << 4;

  f32x4 acc[4][4];
#pragma unroll
  for (int m = 0; m < 4; ++m)
#pragma unroll
    for (int n = 0; n < 4; ++n) acc[m][n] = (f32x4){0.f, 0.f, 0.f, 0.f};

  const int rA = t >> 3;
  const int g = (t & 7) ^ ((t >> 3) & 7);
  const bf16* gA = A + (row0 + rA) * (long)lda + (long)sl * K + g * 8;
  const bf16* gB = Bt + (col0 + rA) * (long)ldb + (long)sl * K + g * 8;

  const int nt = K >> 6;
  // prologue: stage tile 0 into buf 0 (8 loads/thread)
#pragma unroll
  for (int cr = 0; cr < 4; ++cr) {
    async_copy16(gA + (long)cr * 32 * lda, gsmem + t * 16 + cr * 4096);
    async_copy16(gB + (long)cr * 32 * ldb, gsmem + 16384 + t * 16 + cr * 4096);
  }
  int cur = 0;

  for (int kt = 0; kt < nt; ++kt) {
    if (kt < nt - 1) {
      // stage next tile into the other buffer (its readers finished at the
      // previous iteration's trailing barrier)
      const int k1 = (kt + 1) << 6;
      char* dst = gsmem + (cur ^ 1) * 32768;
#pragma unroll
      for (int cr = 0; cr < 4; ++cr) {
        async_copy16(gA + (long)cr * 32 * lda + k1, dst + t * 16 + cr * 4096);
        async_copy16(gB + (long)cr * 32 * ldb + k1, dst + 16384 + t * 16 + cr * 4096);
      }
      asm volatile("s_waitcnt vmcnt(8)" ::: "memory");  // current tile landed
    } else {
      asm volatile("s_waitcnt vmcnt(0)" ::: "memory");
    }
    __builtin_amdgcn_s_barrier();          // all waves' loads landed
    __builtin_amdgcn_sched_barrier(0);
    const char* As = gsmem + cur * 32768;
    const char* Bs = As + 16384;
#pragma unroll
    for (int ks = 0; ks < 2; ++ks) {
      bf16x8 af[4], bfr[4];
#pragma unroll
      for (int m = 0; m < 4; ++m) {
        const int row = wr + m * 16 + lr;
        af[m] = *(const bf16x8*)(As +
            (row * 128 + ((ks * 64 + lkb) ^ ((row & 7) << 4))));
      }
#pragma unroll
      for (int n = 0; n < 4; ++n) {
        const int row = wc + n * 16 + lr;
        bfr[n] = *(const bf16x8*)(Bs +
            (row * 128 + ((ks * 64 + lkb) ^ ((row & 7) << 4))));
      }
#pragma unroll
      for (int m = 0; m < 4; ++m)
#pragma unroll
        for (int n = 0; n < 4; ++n)
          acc[m][n] = __builtin_amdgcn_mfma_f32_16x16x32_bf16(af[m], bfr[n], acc[m][n], 0, 0, 0);
    }
    __builtin_amdgcn_sched_barrier(0);
    __builtin_amdgcn_s_barrier();          // reads done; buffer may be reused
    cur ^= 1;
  }

  bf16* Cb = (bf16*)Cout;
  float* Cf = (float*)Cout;
  if ((EPI == 4 || EPI == 5) && sl == 1) Cf = pother;
#pragma unroll
  for (int m = 0; m < 4; ++m) {
#pragma unroll
    for (int r = 0; r < 4; ++r) {
      const long crow = row0 + wr + m * 16 + ((l >> 4) << 2) + r;
      const long rbase = crow * N;
#pragma unroll
      for (int n = 0; n < 4; ++n) {
        const long ccol = col0 + wc + n * 16 + lr;
        float v = acc[m][n][r];
        if (EPI == 2) {
          const float vv = v + bias[ccol];
          const float u2 = vv * (1.5957691216f + 0.0713548162f * vv * vv);
          v = vv / (1.0f + __expf(-u2));
        }
        if (EPI == 5 && sl == 0) v += bias[ccol] + res[rbase + ccol];
        if (EPI == 0 || EPI == 2)
          Cb[rbase + ccol] = __float2bfloat16(v);
        else
          Cf[rbase + ccol] = v;
      }
    }
  }
}

// ---- split-K reduce: out = p0 + p1 (p0 already holds bias+residual) ----
__global__ __launch_bounds__(256) void ff2_reduce(
    const float* __restrict__ p0, const float* __restrict__ p1,
    float* __restrict__ out) {
  const int idx = blockIdx.x * 256 + threadIdx.x;
  const float4 x = ((const float4*)p0)[idx];
  const float4 y = ((const float4*)p1)[idx];
  float4 a;
  a.x = x.x + y.x; a.y = x.y + y.y; a.z = x.z + y.z; a.w = x.w + y.w;
  ((float4*)out)[idx] = a;
}

// ---------------- flash attention: 8 waves, 256 q-rows, KVBLK=128 ------------
// T5 setprio around MFMA clusters; T13 defer-rescale THR=8. (R10-proven.)
__global__ __launch_bounds__(512) void attn_kernel(
    const bf16* __restrict__ QKV, const int* __restrict__ pmask,
    bf16* __restrict__ Oout) {
  const int bh = blockIdx.x;
  const int b = bh >> 4, h = bh & 15;
  const int q0 = blockIdx.y << 8;
  const int t = threadIdx.x;
  const int w = t >> 6, l = t & 63;
  const int lq = l & 31, hi = l >> 5;

  __shared__ __align__(16) char smem[65536];

  const long base = (long)b * 2048 * 3072;
  const bf16* Qg = QKV + base + h * 64;
  const bf16* Kg = QKV + base + 1024 + h * 64;
  const bf16* Vg = QKV + base + 2048 + h * 64;

  int kSrc[2], kDst[2], vk[2], vsg[2];
#pragma unroll
  for (int p = 0; p < 2; ++p) {
    const int c = p * 512 + t;
    const int kr = c >> 3;
    kSrc[p] = kr * 3072 + (((c & 7) ^ (kr & 7)) << 3);
    kDst[p] = c * 16;
    vk[p] = c >> 3;
    vsg[p] = c & 7;
  }

  const int qw0 = q0 + w * 32;
  bf16x8 qf[4];
#pragma unroll
  for (int dc = 0; dc < 4; ++dc) {
    uint4 raw = *(const uint4*)(Qg + (long)(qw0 + lq) * 3072 + dc * 16 + hi * 8);
    union { uint4 u4; ushort us[8]; } in; in.u4 = raw;
    union { bf16x8 v; ushort us[8]; } o;
#pragma unroll
    for (int e = 0; e < 8; ++e) o.us[e] = f2bf_bits(0.125f * bfbits2f(in.us[e]));
    qf[dc] = o.v;
  }

  union { unsigned int u[4]; bf16x8 v; } bones;
  bones.u[0] = (hi == 0) ? 0x00003F80u : 0u;
  bones.u[1] = bones.u[2] = bones.u[3] = 0u;

  uint4 vreg[2];
#pragma unroll
  for (int p = 0; p < 2; ++p) {
    vreg[p] = *(const uint4*)(Vg + (long)vk[p] * 3072 + vsg[p] * 8);
    async_copy16(Kg + kSrc[p], smem + kDst[p]);
  }
#pragma unroll
  for (int p = 0; p < 2; ++p) {
    const ushort* vs = (const ushort*)&vreg[p];
#pragma unroll
    for (int e = 0; e < 8; ++e) {
      const int d = vsg[p] * 8 + e;
      *(ushort*)(smem + 32768 + d * 256 +
                 ((vk[p] * 2) ^ (((e ^ vsg[p]) & 7) << 4))) = vs[e];
    }
  }

  f32x16 oacc[2];
#pragma unroll
  for (int nt = 0; nt < 2; ++nt)
#pragma unroll
    for (int r = 0; r < 16; ++r) oacc[nt][r] = 0.f;
  float mrun = -3.0e38f, lsum = 0.f;
  int cur = 0;

  __syncthreads();

  for (int ktg = 0; ktg < 16; ++ktg) {
    if (ktg < 15) {
      const long nrow0 = (long)(ktg + 1) * 128 * 3072;
#pragma unroll
      for (int p = 0; p < 2; ++p) {
        vreg[p] = *(const uint4*)(Vg + nrow0 + (long)vk[p] * 3072 + vsg[p] * 8);
        async_copy16(Kg + nrow0 + kSrc[p], smem + (cur ^ 1) * 16384 + kDst[p]);
      }
    }
    const int k0 = ktg << 7;
    const char* Ks = smem + cur * 16384;
    const char* Vt = smem + 32768 + cur * 16384;

    f32x16 sacc[4];
    __builtin_amdgcn_s_setprio(1);
#pragma unroll
    for (int kt = 0; kt < 4; ++kt) {
#pragma unroll
      for (int r = 0; r < 16; ++r) sacc[kt][r] = 0.f;
#pragma unroll
      for (int dc = 0; dc < 4; ++dc) {
        bf16x8 ka = *(const bf16x8*)(Ks +
            ((kt * 32 + lq) * 128 + ((dc * 32 + hi * 16) ^ ((lq & 7) << 4))));
        sacc[kt] = __builtin_amdgcn_mfma_f32_32x32x16_bf16(ka, qf[dc], sacc[kt], 0, 0, 0);
      }
      const int mv = pmask[b * 2048 + k0 + kt * 32 + lq];
      union { unsigned int u[4]; bf16x8 v; } aadd;
      aadd.u[0] = (hi == 0 && mv == 0) ? (unsigned int)f2bf_bits(-1.0e9f) : 0u;
      aadd.u[1] = aadd.u[2] = aadd.u[3] = 0u;
      sacc[kt] = __builtin_amdgcn_mfma_f32_32x32x16_bf16(aadd.v, bones.v, sacc[kt], 0, 0, 0);
    }
    __builtin_amdgcn_s_setprio(0);

    float tmax = -3.0e38f;
#pragma unroll
    for (int kt = 0; kt < 4; ++kt)
#pragma unroll
      for (int r = 0; r < 16; ++r) tmax = fmaxf(tmax, sacc[kt][r]);
    tmax = fmaxf(tmax, __shfl_xor(tmax, 32));
    const bool need = (bool)__any(tmax > mrun + 8.0f);
    const float mnew = need ? fmaxf(mrun, tmax) : mrun;
    float psum = 0.f;
#pragma unroll
    for (int kt = 0; kt < 4; ++kt)
#pragma unroll
      for (int r = 0; r < 16; ++r) {
        const float p = __expf(sacc[kt][r] - mnew);
        sacc[kt][r] = p;
        psum += p;
      }
    psum += __shfl_xor(psum, 32);
    if (need) {
      const float alpha = __expf(mrun - mnew);
      mrun = mnew;
      lsum = lsum * alpha + psum;
#pragma unroll
      for (int r = 0; r < 16; ++r) {
        const float ar = __shfl(alpha, (r & 3) + 8 * (r >> 2) + 4 * hi);
        oacc[0][r] *= ar;
        oacc[1][r] *= ar;
      }
    } else {
      lsum += psum;
    }

    union { unsigned int u[4]; bf16x8 v; } paE[4], paO[4];
#pragma unroll
    for (int kt = 0; kt < 4; ++kt) {
      const unsigned int cs0 = pk2(sacc[kt][0], sacc[kt][1]);
      const unsigned int cs1 = pk2(sacc[kt][2], sacc[kt][3]);
      const unsigned int cs2 = pk2(sacc[kt][4], sacc[kt][5]);
      const unsigned int cs3 = pk2(sacc[kt][6], sacc[kt][7]);
      const unsigned int cs4 = pk2(sacc[kt][8], sacc[kt][9]);
      const unsigned int cs5 = pk2(sacc[kt][10], sacc[kt][11]);
      const unsigned int cs6 = pk2(sacc[kt][12], sacc[kt][13]);
      const unsigned int cs7 = pk2(sacc[kt][14], sacc[kt][15]);
      const unsigned int es0 = __shfl_xor(cs0, 32);
      const unsigned int es1 = __shfl_xor(cs1, 32);
      const unsigned int es2 = __shfl_xor(cs2, 32);
      const unsigned int es3 = __shfl_xor(cs3, 32);
      const unsigned int es4 = __shfl_xor(cs4, 32);
      const unsigned int es5 = __shfl_xor(cs5, 32);
      const unsigned int es6 = __shfl_xor(cs6, 32);
      const unsigned int es7 = __shfl_xor(cs7, 32);
      paE[kt].u[0] = hi ? es2 : cs0;
      paE[kt].u[1] = hi ? es3 : cs1;
      paE[kt].u[2] = hi ? cs2 : es0;
      paE[kt].u[3] = hi ? cs3 : es1;
      paO[kt].u[0] = hi ? es6 : cs4;
      paO[kt].u[1] = hi ? es7 : cs5;
      paO[kt].u[2] = hi ? cs6 : es4;
      paO[kt].u[3] = hi ? cs7 : es5;
    }

    __builtin_amdgcn_s_setprio(1);
#pragma unroll
    for (int kt = 0; kt < 4; ++kt)
#pragma unroll
      for (int nt = 0; nt < 2; ++nt) {
        const int vrow = nt * 32 + lq;
        const int vsw = ((vrow & 7) ^ ((vrow >> 3) & 7)) << 4;
        bf16x8 vbE = *(const bf16x8*)(Vt + (vrow * 256 + ((kt * 64 + hi * 16) ^ vsw)));
        oacc[nt] = __builtin_amdgcn_mfma_f32_32x32x16_bf16(paE[kt].v, vbE, oacc[nt], 0, 0, 0);
        bf16x8 vbO = *(const bf16x8*)(Vt + (vrow * 256 + ((kt * 64 + 32 + hi * 16) ^ vsw)));
        oacc[nt] = __builtin_amdgcn_mfma_f32_32x32x16_bf16(paO[kt].v, vbO, oacc[nt], 0, 0, 0);
      }
    __builtin_amdgcn_s_setprio(0);

    if (ktg < 15) {
      char* VtN = smem + 32768 + (cur ^ 1) * 16384;
#pragma unroll
      for (int p = 0; p < 2; ++p) {
        const ushort* vs = (const ushort*)&vreg[p];
#pragma unroll
        for (int e = 0; e < 8; ++e) {
          const int d = vsg[p] * 8 + e;
          *(ushort*)(VtN + d * 256 +
                     ((vk[p] * 2) ^ (((e ^ vsg[p]) & 7) << 4))) = vs[e];
        }
      }
    }

    __syncthreads();
    cur ^= 1;
  }

  const float inv = 1.0f / lsum;
#pragma unroll
  for (int r = 0; r < 16; ++r) {
    const int crow = (r & 3) + 8 * (r >> 2) + 4 * hi;
    const float ir = __shfl(inv, crow);
    const long orow = (long)b * 2048 + qw0 + crow;
#pragma unroll
    for (int nt = 0; nt < 2; ++nt)
      Oout[orow * 1024 + h * 64 + nt * 32 + lq] = __float2bfloat16(oacc[nt][r] * ir);
  }
}

extern "C" void kernel_launch(void* const* d_in, const int* in_sizes, int n_in,
                              void* d_out, int out_size, void* d_ws, size_t ws_size,
                              hipStream_t stream) {
  const float* X = (const float*)d_in[0];
  const int* pmask = (const int*)d_in[1];
  const float* W_Q = (const float*)d_in[2];
  const float* W_K = (const float*)d_in[3];
  const float* W_V = (const float*)d_in[4];
  const float* W_O = (const float*)d_in[5];
  const float* g1 = (const float*)d_in[6];
  const float* b1 = (const float*)d_in[7];
  const float* W1 = (const float*)d_in[8];
  const float* bias1 = (const float*)d_in[9];
  const float* W2 = (const float*)d_in[10];
  const float* bias2 = (const float*)d_in[11];
  const float* g2 = (const float*)d_in[12];
  const float* b2 = (const float*)d_in[13];
  (void)in_sizes; (void)n_in; (void)out_size; (void)ws_size;

  char* ws = (char*)d_ws;
  const size_t MB = 1ull << 20;
  bf16* W1_t   = (bf16*)(ws + 0);
  bf16* Wqkv_t = (bf16*)(ws + 8 * MB);
  bf16* Wo_t   = (bf16*)(ws + 14 * MB);
  bf16* W2_t   = (bf16*)(ws + 16 * MB);
  bf16* xn     = (bf16*)(ws + 24 * MB);
  bf16* QKV    = (bf16*)(ws + 32 * MB);
  bf16* attnb  = (bf16*)(ws + 56 * MB);
  bf16* ff1    = (bf16*)(ws + 32 * MB);
  float* p0o   = (float*)(ws + 64 * MB);
  float* p1o   = (float*)(ws + 32 * MB);
  float* p0    = (float*)(ws + 64 * MB);
  float* p1    = (float*)(ws + 0);
  float* res1  = (float*)d_out;

  transpose_all<<<12288, 256, 0, stream>>>(W_Q, W_K, W_V, W_O, W1, W2,
                                           Wqkv_t, W1_t, W2_t);
  ln_kernel<<<4096, 256, 0, stream>>>(X, g1, b1, xn);
  gemm_bt<0, 1><<<32 * 24, 256, 0, stream>>>(xn, Wqkv_t, 4096, 3072, 1024, 1024, 1024,
                                             nullptr, nullptr, nullptr, QKV);
  attn_kernel<<<dim3(32, 8), 512, 0, stream>>>(QKV, pmask, attnb);
  gemm_bt<4, 2><<<2 * 32 * 8, 256, 0, stream>>>(attnb, Wo_t, 4096, 1024, 512, 1024, 1024,
                                                nullptr, nullptr, p1o, p0o);
  oproj_reduce_ln<<<4096, 256, 0, stream>>>(p0o, p1o, X, g2, b2, res1, xn);
  gemm_bt<2, 1><<<32 * 32, 256, 0, stream>>>(xn, W1_t, 4096, 4096, 1024, 1024, 1024,
                                             bias1, nullptr, nullptr, ff1);
  gemm_bt<5, 2><<<2 * 32 * 8, 256, 0, stream>>>(ff1, W2_t, 4096, 1024, 2048, 4096, 4096,
                                                bias2, res1, p1, p0);
  ff2_reduce<<<4096, 256, 0, stream>>>(p0, p1, res1);
}

// Round 12
// 267.507 us; speedup vs baseline: 1.2103x; 1.0003x over previous
//
#include <hip/hip_runtime.h>
#include <hip/hip_bf16.h>

// EncoderLayer on MI355X (gfx950).
// B=2, S=2048, D=1024, H=16, DK=64. M = B*S = 4096.
// R12: FF1 -> 256x256 tile GEMM (8 waves, per-wave 128x64 => LDS bytes/MAC
//      -25%), counted-vmcnt dbuf sync copied verbatim from R11; 128KB LDS.
//      LN1 merged into the weight-transpose dispatch (blocks 12288+).
//      Everything else identical to R11.

using bf16 = __hip_bfloat16;
typedef __attribute__((ext_vector_type(4))) float f32x4;
typedef __attribute__((ext_vector_type(16))) float f32x16;
typedef __attribute__((ext_vector_type(8))) short bf16x8;

#define DEVI static __device__ __forceinline__

DEVI void async_copy16(const void* g, void* l) {
  __builtin_amdgcn_global_load_lds(
      (const __attribute__((address_space(1))) void*)g,
      (__attribute__((address_space(3))) void*)l, 16, 0, 0);
}

DEVI ushort f2bf_bits(float v) {
  __hip_bfloat16 h = __float2bfloat16(v);
  return *reinterpret_cast<ushort*>(&h);
}

DEVI float bfbits2f(ushort u) {
  union { float f; unsigned int i; } x;
  x.i = ((unsigned int)u) << 16;
  return x.f;
}

DEVI unsigned int pk2(float lo, float hi) {
  return (unsigned int)f2bf_bits(lo) | ((unsigned int)f2bf_bits(hi) << 16);
}

// ---- merged: weight transposes (blocks 0..12287) + LN1 (blocks 12288+) ----
__global__ __launch_bounds__(256) void transpose_all_ln(
    const float* __restrict__ q, const float* __restrict__ k,
    const float* __restrict__ v, const float* __restrict__ o,
    const float* __restrict__ w1, const float* __restrict__ w2,
    bf16* __restrict__ wqkvo, bf16* __restrict__ w1t, bf16* __restrict__ w2t,
    const float* __restrict__ X, const float* __restrict__ g1,
    const float* __restrict__ b1, bf16* __restrict__ xn) {
  const int tid = blockIdx.x;
  if (tid >= 12288) {
    // ---- LN1 on row (tid - 12288) ----
    const long row = tid - 12288;
    const int t = threadIdx.x;
    float4 x = ((const float4*)(X + row * 1024))[t];
    float s = x.x + x.y + x.z + x.w;
    float s2 = x.x * x.x + x.y * x.y + x.z * x.z + x.w * x.w;
#pragma unroll
    for (int m = 1; m < 64; m <<= 1) {
      s += __shfl_xor(s, m);
      s2 += __shfl_xor(s2, m);
    }
    __shared__ float red[8];
    const int w = t >> 6, l = t & 63;
    if (l == 0) { red[w] = s; red[4 + w] = s2; }
    __syncthreads();
    s = red[0] + red[1] + red[2] + red[3];
    s2 = red[4] + red[5] + red[6] + red[7];
    const float mean = s * (1.0f / 1024.0f);
    const float var = s2 * (1.0f / 1024.0f) - mean * mean;
    const float rstd = rsqrtf(var + 1e-6f);
    float4 g4 = ((const float4*)g1)[t];
    float4 b4 = ((const float4*)b1)[t];
    union { ushort h[4]; uint2 u; } oo;
    oo.h[0] = f2bf_bits(g4.x * (x.x - mean) * rstd + b4.x);
    oo.h[1] = f2bf_bits(g4.y * (x.y - mean) * rstd + b4.y);
    oo.h[2] = f2bf_bits(g4.z * (x.z - mean) * rstd + b4.z);
    oo.h[3] = f2bf_bits(g4.w * (x.w - mean) * rstd + b4.w);
    ((uint2*)(xn + row * 1024))[t] = oo.u;
    return;
  }
  const float* W;
  bf16* Wt;
  int K, N, n0, k0;
  if (tid < 4096) {
    const int z = tid >> 10, r = tid & 1023;
    W = (z == 0) ? q : (z == 1) ? k : (z == 2) ? v : o;
    Wt = wqkvo + (size_t)z * 1024 * 1024;
    K = 1024; N = 1024; n0 = (r & 31) << 5; k0 = (r >> 5) << 5;
  } else if (tid < 8192) {
    const int r = tid - 4096;
    W = w1; Wt = w1t; K = 1024; N = 4096;
    n0 = (r & 127) << 5; k0 = (r >> 7) << 5;
  } else {
    const int r = tid - 8192;
    W = w2; Wt = w2t; K = 4096; N = 1024;
    n0 = (r & 31) << 5; k0 = (r >> 5) << 5;
  }
  __shared__ float tile[32][33];
  const int tx = threadIdx.x & 31, ty = threadIdx.x >> 5;
#pragma unroll
  for (int i = 0; i < 32; i += 8)
    tile[ty + i][tx] = W[(long)(k0 + ty + i) * N + n0 + tx];
  __syncthreads();
#pragma unroll
  for (int i = 0; i < 32; i += 8)
    Wt[(long)(n0 + ty + i) * K + k0 + tx] = __float2bfloat16(tile[tx][ty + i]);
}

// ---- O-proj split-K reduce fused with LN2: res = p0+p1+X; xn = LN(res) ----
__global__ __launch_bounds__(256) void oproj_reduce_ln(
    const float* __restrict__ p0, const float* __restrict__ p1,
    const float* __restrict__ X, const float* __restrict__ gamma,
    const float* __restrict__ beta, float* __restrict__ res_out,
    bf16* __restrict__ xn_out) {
  const long row = blockIdx.x;
  const int t = threadIdx.x;
  const long i = row * 256 + t;
  const float4 a = ((const float4*)p0)[i];
  const float4 b = ((const float4*)p1)[i];
  const float4 c = ((const float4*)X)[i];
  float4 x;
  x.x = a.x + b.x + c.x; x.y = a.y + b.y + c.y;
  x.z = a.z + b.z + c.z; x.w = a.w + b.w + c.w;
  ((float4*)res_out)[i] = x;
  float s = x.x + x.y + x.z + x.w;
  float s2 = x.x * x.x + x.y * x.y + x.z * x.z + x.w * x.w;
#pragma unroll
  for (int m = 1; m < 64; m <<= 1) {
    s += __shfl_xor(s, m);
    s2 += __shfl_xor(s2, m);
  }
  __shared__ float red[8];
  const int w = t >> 6, l = t & 63;
  if (l == 0) { red[w] = s; red[4 + w] = s2; }
  __syncthreads();
  s = red[0] + red[1] + red[2] + red[3];
  s2 = red[4] + red[5] + red[6] + red[7];
  const float mean = s * (1.0f / 1024.0f);
  const float var = s2 * (1.0f / 1024.0f) - mean * mean;
  const float rstd = rsqrtf(var + 1e-6f);
  float4 g4 = ((const float4*)gamma)[t];
  float4 b4 = ((const float4*)beta)[t];
  union { ushort h[4]; uint2 u; } o;
  o.h[0] = f2bf_bits(g4.x * (x.x - mean) * rstd + b4.x);
  o.h[1] = f2bf_bits(g4.y * (x.y - mean) * rstd + b4.y);
  o.h[2] = f2bf_bits(g4.z * (x.z - mean) * rstd + b4.z);
  o.h[3] = f2bf_bits(g4.w * (x.w - mean) * rstd + b4.w);
  ((uint2*)(xn_out + row * 1024))[t] = o.u;
}

// ------------- 128x128 GEMM (R11 counted-vmcnt dbuf), unchanged -------------
template <int EPI, int KSPLIT>
__global__ __launch_bounds__(256) void gemm_bt(
    const bf16* __restrict__ A, const bf16* __restrict__ Bt,
    const int M, const int N, const int K, const int lda, const int ldb,
    const float* __restrict__ bias, const float* __restrict__ res,
    float* __restrict__ pother, void* __restrict__ Cout) {
  __shared__ __align__(16) char gsmem[65536];
  const int t = threadIdx.x;
  const int w = t >> 6, l = t & 63;
  const int nb = N >> 7;
  const int cpx = gridDim.x >> 3;
  int bidx = (blockIdx.x & 7) * cpx + (blockIdx.x >> 3);
  int sl = 0;
  if (KSPLIT == 2) {
    const int half = gridDim.x >> 1;
    sl = bidx >= half;
    bidx -= sl * half;
  }
  const int bm = bidx / nb, bn = bidx % nb;
  const long row0 = (long)bm << 7, col0 = (long)bn << 7;
  const int wr = (w >> 1) << 6, wc = (w & 1) << 6;
  const int lr = l & 15;
  const int lkb = (l >> 4) << 4;

  f32x4 acc[4][4];
#pragma unroll
  for (int m = 0; m < 4; ++m)
#pragma unroll
    for (int n = 0; n < 4; ++n) acc[m][n] = (f32x4){0.f, 0.f, 0.f, 0.f};

  const int rA = t >> 3;
  const int g = (t & 7) ^ ((t >> 3) & 7);
  const bf16* gA = A + (row0 + rA) * (long)lda + (long)sl * K + g * 8;
  const bf16* gB = Bt + (col0 + rA) * (long)ldb + (long)sl * K + g * 8;

  const int nt = K >> 6;
#pragma unroll
  for (int cr = 0; cr < 4; ++cr) {
    async_copy16(gA + (long)cr * 32 * lda, gsmem + t * 16 + cr * 4096);
    async_copy16(gB + (long)cr * 32 * ldb, gsmem + 16384 + t * 16 + cr * 4096);
  }
  int cur = 0;

  for (int kt = 0; kt < nt; ++kt) {
    if (kt < nt - 1) {
      const int k1 = (kt + 1) << 6;
      char* dst = gsmem + (cur ^ 1) * 32768;
#pragma unroll
      for (int cr = 0; cr < 4; ++cr) {
        async_copy16(gA + (long)cr * 32 * lda + k1, dst + t * 16 + cr * 4096);
        async_copy16(gB + (long)cr * 32 * ldb + k1, dst + 16384 + t * 16 + cr * 4096);
      }
      asm volatile("s_waitcnt vmcnt(8)" ::: "memory");
    } else {
      asm volatile("s_waitcnt vmcnt(0)" ::: "memory");
    }
    __builtin_amdgcn_s_barrier();
    __builtin_amdgcn_sched_barrier(0);
    const char* As = gsmem + cur * 32768;
    const char* Bs = As + 16384;
#pragma unroll
    for (int ks = 0; ks < 2; ++ks) {
      bf16x8 af[4], bfr[4];
#pragma unroll
      for (int m = 0; m < 4; ++m) {
        const int row = wr + m * 16 + lr;
        af[m] = *(const bf16x8*)(As +
            (row * 128 + ((ks * 64 + lkb) ^ ((row & 7) << 4))));
      }
#pragma unroll
      for (int n = 0; n < 4; ++n) {
        const int row = wc + n * 16 + lr;
        bfr[n] = *(const bf16x8*)(Bs +
            (row * 128 + ((ks * 64 + lkb) ^ ((row & 7) << 4))));
      }
#pragma unroll
      for (int m = 0; m < 4; ++m)
#pragma unroll
        for (int n = 0; n < 4; ++n)
          acc[m][n] = __builtin_amdgcn_mfma_f32_16x16x32_bf16(af[m], bfr[n], acc[m][n], 0, 0, 0);
    }
    __builtin_amdgcn_sched_barrier(0);
    __builtin_amdgcn_s_barrier();
    cur ^= 1;
  }

  bf16* Cb = (bf16*)Cout;
  float* Cf = (float*)Cout;
  if ((EPI == 4 || EPI == 5) && sl == 1) Cf = pother;
#pragma unroll
  for (int m = 0; m < 4; ++m) {
#pragma unroll
    for (int r = 0; r < 4; ++r) {
      const long crow = row0 + wr + m * 16 + ((l >> 4) << 2) + r;
      const long rbase = crow * N;
#pragma unroll
      for (int n = 0; n < 4; ++n) {
        const long ccol = col0 + wc + n * 16 + lr;
        float v = acc[m][n][r];
        if (EPI == 2) {
          const float vv = v + bias[ccol];
          const float u2 = vv * (1.5957691216f + 0.0713548162f * vv * vv);
          v = vv / (1.0f + __expf(-u2));
        }
        if (EPI == 5 && sl == 0) v += bias[ccol] + res[rbase + ccol];
        if (EPI == 0 || EPI == 2)
          Cb[rbase + ccol] = __float2bfloat16(v);
        else
          Cf[rbase + ccol] = v;
      }
    }
  }
}

// ---- 256x256 GEMM: 8 waves (2Mx4N), per-wave 128x64, BK=64, 128KB LDS dbuf,
// counted-vmcnt sync identical to gemm_bt (8 loads/thread/step -> vmcnt(8)).
// EPI: 0 = bf16 store; 2 = +bias sigmoid-GELU bf16. lda=ldb=K.
template <int EPI>
__global__ __launch_bounds__(512) void gemm_bt256(
    const bf16* __restrict__ A, const bf16* __restrict__ Bt,
    const int M, const int N, const int K,
    const float* __restrict__ bias, void* __restrict__ Cout) {
  __shared__ __align__(16) char gsmem[131072];  // 2 bufs x (A 32K | B 32K)
  const int t = threadIdx.x;
  const int w = t >> 6, l = t & 63;
  const int nb = N >> 8;
  const int cpx = gridDim.x >> 3;
  const int bidx = (blockIdx.x & 7) * cpx + (blockIdx.x >> 3);
  const int bm = bidx / nb, bn = bidx % nb;
  const long row0 = (long)bm << 8, col0 = (long)bn << 8;
  const int wr = (w >> 2) << 7, wc = (w & 3) << 6;
  const int lr = l & 15;
  const int lkb = (l >> 4) << 4;

  f32x4 acc[8][4];
#pragma unroll
  for (int m = 0; m < 8; ++m)
#pragma unroll
    for (int n = 0; n < 4; ++n) acc[m][n] = (f32x4){0.f, 0.f, 0.f, 0.f};

  // staging: chunk c = p*512 + t (p 0..3 per operand); row r = c>>3 = p*64+(t>>3),
  // stored group g' = t&7, source group g = g' ^ (r&7) ((c>>3)&7 == (t>>3)&7).
  const int g = (t & 7) ^ ((t >> 3) & 7);
  const bf16* gA = A + (row0 + (t >> 3)) * (long)K + g * 8;
  const bf16* gB = Bt + (col0 + (t >> 3)) * (long)K + g * 8;

  const int nt = K >> 6;
#pragma unroll
  for (int p = 0; p < 4; ++p) {
    async_copy16(gA + (long)p * 64 * K, gsmem + (p * 512 + t) * 16);
    async_copy16(gB + (long)p * 64 * K, gsmem + 32768 + (p * 512 + t) * 16);
  }
  int cur = 0;

  for (int kt = 0; kt < nt; ++kt) {
    if (kt < nt - 1) {
      const int k1 = (kt + 1) << 6;
      char* dst = gsmem + (cur ^ 1) * 65536;
#pragma unroll
      for (int p = 0; p < 4; ++p) {
        async_copy16(gA + (long)p * 64 * K + k1, dst + (p * 512 + t) * 16);
        async_copy16(gB + (long)p * 64 * K + k1, dst + 32768 + (p * 512 + t) * 16);
      }
      asm volatile("s_waitcnt vmcnt(8)" ::: "memory");
    } else {
      asm volatile("s_waitcnt vmcnt(0)" ::: "memory");
    }
    __builtin_amdgcn_s_barrier();
    __builtin_amdgcn_sched_barrier(0);
    const char* As = gsmem + cur * 65536;
    const char* Bs = As + 32768;
#pragma unroll
    for (int ks = 0; ks < 2; ++ks) {
      bf16x8 af[8], bfr[4];
#pragma unroll
      for (int m = 0; m < 8; ++m) {
        const int row = wr + m * 16 + lr;
        af[m] = *(const bf16x8*)(As +
            (row * 128 + ((ks * 64 + lkb) ^ ((row & 7) << 4))));
      }
#pragma unroll
      for (int n = 0; n < 4; ++n) {
        const int row = wc + n * 16 + lr;
        bfr[n] = *(const bf16x8*)(Bs +
            (row * 128 + ((ks * 64 + lkb) ^ ((row & 7) << 4))));
      }
#pragma unroll
      for (int m = 0; m < 8; ++m)
#pragma unroll
        for (int n = 0; n < 4; ++n)
          acc[m][n] = __builtin_amdgcn_mfma_f32_16x16x32_bf16(af[m], bfr[n], acc[m][n], 0, 0, 0);
    }
    __builtin_amdgcn_sched_barrier(0);
    __builtin_amdgcn_s_barrier();
    cur ^= 1;
  }

  bf16* Cb = (bf16*)Cout;
#pragma unroll
  for (int m = 0; m < 8; ++m) {
#pragma unroll
    for (int r = 0; r < 4; ++r) {
      const long crow = row0 + wr + m * 16 + ((l >> 4) << 2) + r;
      const long rbase = crow * N;
#pragma unroll
      for (int n = 0; n < 4; ++n) {
        const long ccol = col0 + wc + n * 16 + lr;
        float v = acc[m][n][r];
        if (EPI == 2) {
          const float vv = v + bias[ccol];
          const float u2 = vv * (1.5957691216f + 0.0713548162f * vv * vv);
          v = vv / (1.0f + __expf(-u2));
        }
        Cb[rbase + ccol] = __float2bfloat16(v);
      }
    }
  }
}

// ---- split-K reduce: out = p0 + p1 (p0 already holds bias+residual) ----
__global__ __launch_bounds__(256) void ff2_reduce(
    const float* __restrict__ p0, const float* __restrict__ p1,
    float* __restrict__ out) {
  const int idx = blockIdx.x * 256 + threadIdx.x;
  const float4 x = ((const float4*)p0)[idx];
  const float4 y = ((const float4*)p1)[idx];
  float4 a;
  a.x = x.x + y.x; a.y = x.y + y.y; a.z = x.z + y.z; a.w = x.w + y.w;
  ((float4*)out)[idx] = a;
}

// ---------------- flash attention: 8 waves, 256 q-rows, KVBLK=128 ------------
// T5 setprio around MFMA clusters; T13 defer-rescale THR=8. (R10-proven.)
__global__ __launch_bounds__(512) void attn_kernel(
    const bf16* __restrict__ QKV, const int* __restrict__ pmask,
    bf16* __restrict__ Oout) {
  const int bh = blockIdx.x;
  const int b = bh >> 4, h = bh & 15;
  const int q0 = blockIdx.y << 8;
  const int t = threadIdx.x;
  const int w = t >> 6, l = t & 63;
  const int lq = l & 31, hi = l >> 5;

  __shared__ __align__(16) char smem[65536];

  const long base = (long)b * 2048 * 3072;
  const bf16* Qg = QKV + base + h * 64;
  const bf16* Kg = QKV + base + 1024 + h * 64;
  const bf16* Vg = QKV + base + 2048 + h * 64;

  int kSrc[2], kDst[2], vk[2], vsg[2];
#pragma unroll
  for (int p = 0; p < 2; ++p) {
    const int c = p * 512 + t;
    const int kr = c >> 3;
    kSrc[p] = kr * 3072 + (((c & 7) ^ (kr & 7)) << 3);
    kDst[p] = c * 16;
    vk[p] = c >> 3;
    vsg[p] = c & 7;
  }

  const int qw0 = q0 + w * 32;
  bf16x8 qf[4];
#pragma unroll
  for (int dc = 0; dc < 4; ++dc) {
    uint4 raw = *(const uint4*)(Qg + (long)(qw0 + lq) * 3072 + dc * 16 + hi * 8);
    union { uint4 u4; ushort us[8]; } in; in.u4 = raw;
    union { bf16x8 v; ushort us[8]; } o;
#pragma unroll
    for (int e = 0; e < 8; ++e) o.us[e] = f2bf_bits(0.125f * bfbits2f(in.us[e]));
    qf[dc] = o.v;
  }

  union { unsigned int u[4]; bf16x8 v; } bones;
  bones.u[0] = (hi == 0) ? 0x00003F80u : 0u;
  bones.u[1] = bones.u[2] = bones.u[3] = 0u;

  uint4 vreg[2];
#pragma unroll
  for (int p = 0; p < 2; ++p) {
    vreg[p] = *(const uint4*)(Vg + (long)vk[p] * 3072 + vsg[p] * 8);
    async_copy16(Kg + kSrc[p], smem + kDst[p]);
  }
#pragma unroll
  for (int p = 0; p < 2; ++p) {
    const ushort* vs = (const ushort*)&vreg[p];
#pragma unroll
    for (int e = 0; e < 8; ++e) {
      const int d = vsg[p] * 8 + e;
      *(ushort*)(smem + 32768 + d * 256 +
                 ((vk[p] * 2) ^ (((e ^ vsg[p]) & 7) << 4))) = vs[e];
    }
  }

  f32x16 oacc[2];
#pragma unroll
  for (int nt = 0; nt < 2; ++nt)
#pragma unroll
    for (int r = 0; r < 16; ++r) oacc[nt][r] = 0.f;
  float mrun = -3.0e38f, lsum = 0.f;
  int cur = 0;

  __syncthreads();

  for (int ktg = 0; ktg < 16; ++ktg) {
    if (ktg < 15) {
      const long nrow0 = (long)(ktg + 1) * 128 * 3072;
#pragma unroll
      for (int p = 0; p < 2; ++p) {
        vreg[p] = *(const uint4*)(Vg + nrow0 + (long)vk[p] * 3072 + vsg[p] * 8);
        async_copy16(Kg + nrow0 + kSrc[p], smem + (cur ^ 1) * 16384 + kDst[p]);
      }
    }
    const int k0 = ktg << 7;
    const char* Ks = smem + cur * 16384;
    const char* Vt = smem + 32768 + cur * 16384;

    f32x16 sacc[4];
    __builtin_amdgcn_s_setprio(1);
#pragma unroll
    for (int kt = 0; kt < 4; ++kt) {
#pragma unroll
      for (int r = 0; r < 16; ++r) sacc[kt][r] = 0.f;
#pragma unroll
      for (int dc = 0; dc < 4; ++dc) {
        bf16x8 ka = *(const bf16x8*)(Ks +
            ((kt * 32 + lq) * 128 + ((dc * 32 + hi * 16) ^ ((lq & 7) << 4))));
        sacc[kt] = __builtin_amdgcn_mfma_f32_32x32x16_bf16(ka, qf[dc], sacc[kt], 0, 0, 0);
      }
      const int mv = pmask[b * 2048 + k0 + kt * 32 + lq];
      union { unsigned int u[4]; bf16x8 v; } aadd;
      aadd.u[0] = (hi == 0 && mv == 0) ? (unsigned int)f2bf_bits(-1.0e9f) : 0u;
      aadd.u[1] = aadd.u[2] = aadd.u[3] = 0u;
      sacc[kt] = __builtin_amdgcn_mfma_f32_32x32x16_bf16(aadd.v, bones.v, sacc[kt], 0, 0, 0);
    }
    __builtin_amdgcn_s_setprio(0);

    float tmax = -3.0e38f;
#pragma unroll
    for (int kt = 0; kt < 4; ++kt)
#pragma unroll
      for (int r = 0; r < 16; ++r) tmax = fmaxf(tmax, sacc[kt][r]);
    tmax = fmaxf(tmax, __shfl_xor(tmax, 32));
    const bool need = (bool)__any(tmax > mrun + 8.0f);
    const float mnew = need ? fmaxf(mrun, tmax) : mrun;
    float psum = 0.f;
#pragma unroll
    for (int kt = 0; kt < 4; ++kt)
#pragma unroll
      for (int r = 0; r < 16; ++r) {
        const float p = __expf(sacc[kt][r] - mnew);
        sacc[kt][r] = p;
        psum += p;
      }
    psum += __shfl_xor(psum, 32);
    if (need) {
      const float alpha = __expf(mrun - mnew);
      mrun = mnew;
      lsum = lsum * alpha + psum;
#pragma unroll
      for (int r = 0; r < 16; ++r) {
        const float ar = __shfl(alpha, (r & 3) + 8 * (r >> 2) + 4 * hi);
        oacc[0][r] *= ar;
        oacc[1][r] *= ar;
      }
    } else {
      lsum += psum;
    }

    union { unsigned int u[4]; bf16x8 v; } paE[4], paO[4];
#pragma unroll
    for (int kt = 0; kt < 4; ++kt) {
      const unsigned int cs0 = pk2(sacc[kt][0], sacc[kt][1]);
      const unsigned int cs1 = pk2(sacc[kt][2], sacc[kt][3]);
      const unsigned int cs2 = pk2(sacc[kt][4], sacc[kt][5]);
      const unsigned int cs3 = pk2(sacc[kt][6], sacc[kt][7]);
      const unsigned int cs4 = pk2(sacc[kt][8], sacc[kt][9]);
      const unsigned int cs5 = pk2(sacc[kt][10], sacc[kt][11]);
      const unsigned int cs6 = pk2(sacc[kt][12], sacc[kt][13]);
      const unsigned int cs7 = pk2(sacc[kt][14], sacc[kt][15]);
      const unsigned int es0 = __shfl_xor(cs0, 32);
      const unsigned int es1 = __shfl_xor(cs1, 32);
      const unsigned int es2 = __shfl_xor(cs2, 32);
      const unsigned int es3 = __shfl_xor(cs3, 32);
      const unsigned int es4 = __shfl_xor(cs4, 32);
      const unsigned int es5 = __shfl_xor(cs5, 32);
      const unsigned int es6 = __shfl_xor(cs6, 32);
      const unsigned int es7 = __shfl_xor(cs7, 32);
      paE[kt].u[0] = hi ? es2 : cs0;
      paE[kt].u[1] = hi ? es3 : cs1;
      paE[kt].u[2] = hi ? cs2 : es0;
      paE[kt].u[3] = hi ? cs3 : es1;
      paO[kt].u[0] = hi ? es6 : cs4;
      paO[kt].u[1] = hi ? es7 : cs5;
      paO[kt].u[2] = hi ? cs6 : es4;
      paO[kt].u[3] = hi ? cs7 : es5;
    }

    __builtin_amdgcn_s_setprio(1);
#pragma unroll
    for (int kt = 0; kt < 4; ++kt)
#pragma unroll
      for (int nt = 0; nt < 2; ++nt) {
        const int vrow = nt * 32 + lq;
        const int vsw = ((vrow & 7) ^ ((vrow >> 3) & 7)) << 4;
        bf16x8 vbE = *(const bf16x8*)(Vt + (vrow * 256 + ((kt * 64 + hi * 16) ^ vsw)));
        oacc[nt] = __builtin_amdgcn_mfma_f32_32x32x16_bf16(paE[kt].v, vbE, oacc[nt], 0, 0, 0);
        bf16x8 vbO = *(const bf16x8*)(Vt + (vrow * 256 + ((kt * 64 + 32 + hi * 16) ^ vsw)));
        oacc[nt] = __builtin_amdgcn_mfma_f32_32x32x16_bf16(paO[kt].v, vbO, oacc[nt], 0, 0, 0);
      }
    __builtin_amdgcn_s_setprio(0);

    if (ktg < 15) {
      char* VtN = smem + 32768 + (cur ^ 1) * 16384;
#pragma unroll
      for (int p = 0; p < 2; ++p) {
        const ushort* vs = (const ushort*)&vreg[p];
#pragma unroll
        for (int e = 0; e < 8; ++e) {
          const int d = vsg[p] * 8 + e;
          *(ushort*)(VtN + d * 256 +
                     ((vk[p] * 2) ^ (((e ^ vsg[p]) & 7) << 4))) = vs[e];
        }
      }
    }

    __syncthreads();
    cur ^= 1;
  }

  const float inv = 1.0f / lsum;
#pragma unroll
  for (int r = 0; r < 16; ++r) {
    const int crow = (r & 3) + 8 * (r >> 2) + 4 * hi;
    const float ir = __shfl(inv, crow);
    const long orow = (long)b * 2048 + qw0 + crow;
#pragma unroll
    for (int nt = 0; nt < 2; ++nt)
      Oout[orow * 1024 + h * 64 + nt * 32 + lq] = __float2bfloat16(oacc[nt][r] * ir);
  }
}

extern "C" void kernel_launch(void* const* d_in, const int* in_sizes, int n_in,
                              void* d_out, int out_size, void* d_ws, size_t ws_size,
                              hipStream_t stream) {
  const float* X = (const float*)d_in[0];
  const int* pmask = (const int*)d_in[1];
  const float* W_Q = (const float*)d_in[2];
  const float* W_K = (const float*)d_in[3];
  const float* W_V = (const float*)d_in[4];
  const float* W_O = (const float*)d_in[5];
  const float* g1 = (const float*)d_in[6];
  const float* b1 = (const float*)d_in[7];
  const float* W1 = (const float*)d_in[8];
  const float* bias1 = (const float*)d_in[9];
  const float* W2 = (const float*)d_in[10];
  const float* bias2 = (const float*)d_in[11];
  const float* g2 = (const float*)d_in[12];
  const float* b2 = (const float*)d_in[13];
  (void)in_sizes; (void)n_in; (void)out_size; (void)ws_size;

  char* ws = (char*)d_ws;
  const size_t MB = 1ull << 20;
  bf16* W1_t   = (bf16*)(ws + 0);
  bf16* Wqkv_t = (bf16*)(ws + 8 * MB);
  bf16* Wo_t   = (bf16*)(ws + 14 * MB);
  bf16* W2_t   = (bf16*)(ws + 16 * MB);
  bf16* xn     = (bf16*)(ws + 24 * MB);
  bf16* QKV    = (bf16*)(ws + 32 * MB);
  bf16* attnb  = (bf16*)(ws + 56 * MB);
  bf16* ff1    = (bf16*)(ws + 32 * MB);
  float* p0o   = (float*)(ws + 64 * MB);
  float* p1o   = (float*)(ws + 32 * MB);
  float* p0    = (float*)(ws + 64 * MB);
  float* p1    = (float*)(ws + 0);
  float* res1  = (float*)d_out;

  // merged weight transposes + LN1 (blocks 12288..16383 do LN rows)
  transpose_all_ln<<<16384, 256, 0, stream>>>(W_Q, W_K, W_V, W_O, W1, W2,
                                              Wqkv_t, W1_t, W2_t,
                                              X, g1, b1, xn);
  gemm_bt<0, 1><<<32 * 24, 256, 0, stream>>>(xn, Wqkv_t, 4096, 3072, 1024, 1024, 1024,
                                             nullptr, nullptr, nullptr, QKV);
  attn_kernel<<<dim3(32, 8), 512, 0, stream>>>(QKV, pmask, attnb);
  gemm_bt<4, 2><<<2 * 32 * 8, 256, 0, stream>>>(attnb, Wo_t, 4096, 1024, 512, 1024, 1024,
                                                nullptr, nullptr, p1o, p0o);
  oproj_reduce_ln<<<4096, 256, 0, stream>>>(p0o, p1o, X, g2, b2, res1, xn);
  // FF1: 256x256 tile, grid exactly 256 blocks (1/CU)
  gemm_bt256<2><<<16 * 16, 512, 0, stream>>>(xn, W1_t, 4096, 4096, 1024, bias1, ff1);
  gemm_bt<5, 2><<<2 * 32 * 8, 256, 0, stream>>>(ff1, W2_t, 4096, 1024, 2048, 4096, 4096,
                                                bias2, res1, p1, p0);
  ff2_reduce<<<4096, 256, 0, stream>>>(p0, p1, res1);
}

// Round 13
// 264.110 us; speedup vs baseline: 1.2258x; 1.0129x over previous
//
#include <hip/hip_runtime.h>
#include <hip/hip_bf16.h>

// EncoderLayer on MI355X (gfx950).
// B=2, S=2048, D=1024, H=16, DK=64. M = B*S = 4096.
// R13: FF1 reverted to proven 128^2 gemm_bt (R12's 256^2+2phase was null, as
//      the guide's m230 predicted). gemm_bt upgraded to DEPTH-2 A-prefetch:
//      A ring-3 (48KB) + B dbuf (32KB) = 80KB (2 blocks/CU preserved),
//      counted vmcnt(12)/(8)/(0) by FIFO trace; barriers/compute identical
//      to R11. Attention unchanged (T5+T13, R10-proven).

using bf16 = __hip_bfloat16;
typedef __attribute__((ext_vector_type(4))) float f32x4;
typedef __attribute__((ext_vector_type(16))) float f32x16;
typedef __attribute__((ext_vector_type(8))) short bf16x8;

#define DEVI static __device__ __forceinline__

DEVI void async_copy16(const void* g, void* l) {
  __builtin_amdgcn_global_load_lds(
      (const __attribute__((address_space(1))) void*)g,
      (__attribute__((address_space(3))) void*)l, 16, 0, 0);
}

DEVI ushort f2bf_bits(float v) {
  __hip_bfloat16 h = __float2bfloat16(v);
  return *reinterpret_cast<ushort*>(&h);
}

DEVI float bfbits2f(ushort u) {
  union { float f; unsigned int i; } x;
  x.i = ((unsigned int)u) << 16;
  return x.f;
}

DEVI unsigned int pk2(float lo, float hi) {
  return (unsigned int)f2bf_bits(lo) | ((unsigned int)f2bf_bits(hi) << 16);
}

// ---- merged: weight transposes (blocks 0..12287) + LN1 (blocks 12288+) ----
__global__ __launch_bounds__(256) void transpose_all_ln(
    const float* __restrict__ q, const float* __restrict__ k,
    const float* __restrict__ v, const float* __restrict__ o,
    const float* __restrict__ w1, const float* __restrict__ w2,
    bf16* __restrict__ wqkvo, bf16* __restrict__ w1t, bf16* __restrict__ w2t,
    const float* __restrict__ X, const float* __restrict__ g1,
    const float* __restrict__ b1, bf16* __restrict__ xn) {
  const int tid = blockIdx.x;
  if (tid >= 12288) {
    const long row = tid - 12288;
    const int t = threadIdx.x;
    float4 x = ((const float4*)(X + row * 1024))[t];
    float s = x.x + x.y + x.z + x.w;
    float s2 = x.x * x.x + x.y * x.y + x.z * x.z + x.w * x.w;
#pragma unroll
    for (int m = 1; m < 64; m <<= 1) {
      s += __shfl_xor(s, m);
      s2 += __shfl_xor(s2, m);
    }
    __shared__ float red[8];
    const int w = t >> 6, l = t & 63;
    if (l == 0) { red[w] = s; red[4 + w] = s2; }
    __syncthreads();
    s = red[0] + red[1] + red[2] + red[3];
    s2 = red[4] + red[5] + red[6] + red[7];
    const float mean = s * (1.0f / 1024.0f);
    const float var = s2 * (1.0f / 1024.0f) - mean * mean;
    const float rstd = rsqrtf(var + 1e-6f);
    float4 g4 = ((const float4*)g1)[t];
    float4 b4 = ((const float4*)b1)[t];
    union { ushort h[4]; uint2 u; } oo;
    oo.h[0] = f2bf_bits(g4.x * (x.x - mean) * rstd + b4.x);
    oo.h[1] = f2bf_bits(g4.y * (x.y - mean) * rstd + b4.y);
    oo.h[2] = f2bf_bits(g4.z * (x.z - mean) * rstd + b4.z);
    oo.h[3] = f2bf_bits(g4.w * (x.w - mean) * rstd + b4.w);
    ((uint2*)(xn + row * 1024))[t] = oo.u;
    return;
  }
  const float* W;
  bf16* Wt;
  int K, N, n0, k0;
  if (tid < 4096) {
    const int z = tid >> 10, r = tid & 1023;
    W = (z == 0) ? q : (z == 1) ? k : (z == 2) ? v : o;
    Wt = wqkvo + (size_t)z * 1024 * 1024;
    K = 1024; N = 1024; n0 = (r & 31) << 5; k0 = (r >> 5) << 5;
  } else if (tid < 8192) {
    const int r = tid - 4096;
    W = w1; Wt = w1t; K = 1024; N = 4096;
    n0 = (r & 127) << 5; k0 = (r >> 7) << 5;
  } else {
    const int r = tid - 8192;
    W = w2; Wt = w2t; K = 4096; N = 1024;
    n0 = (r & 31) << 5; k0 = (r >> 5) << 5;
  }
  __shared__ float tile[32][33];
  const int tx = threadIdx.x & 31, ty = threadIdx.x >> 5;
#pragma unroll
  for (int i = 0; i < 32; i += 8)
    tile[ty + i][tx] = W[(long)(k0 + ty + i) * N + n0 + tx];
  __syncthreads();
#pragma unroll
  for (int i = 0; i < 32; i += 8)
    Wt[(long)(n0 + ty + i) * K + k0 + tx] = __float2bfloat16(tile[tx][ty + i]);
}

// ---- O-proj split-K reduce fused with LN2: res = p0+p1+X; xn = LN(res) ----
__global__ __launch_bounds__(256) void oproj_reduce_ln(
    const float* __restrict__ p0, const float* __restrict__ p1,
    const float* __restrict__ X, const float* __restrict__ gamma,
    const float* __restrict__ beta, float* __restrict__ res_out,
    bf16* __restrict__ xn_out) {
  const long row = blockIdx.x;
  const int t = threadIdx.x;
  const long i = row * 256 + t;
  const float4 a = ((const float4*)p0)[i];
  const float4 b = ((const float4*)p1)[i];
  const float4 c = ((const float4*)X)[i];
  float4 x;
  x.x = a.x + b.x + c.x; x.y = a.y + b.y + c.y;
  x.z = a.z + b.z + c.z; x.w = a.w + b.w + c.w;
  ((float4*)res_out)[i] = x;
  float s = x.x + x.y + x.z + x.w;
  float s2 = x.x * x.x + x.y * x.y + x.z * x.z + x.w * x.w;
#pragma unroll
  for (int m = 1; m < 64; m <<= 1) {
    s += __shfl_xor(s, m);
    s2 += __shfl_xor(s2, m);
  }
  __shared__ float red[8];
  const int w = t >> 6, l = t & 63;
  if (l == 0) { red[w] = s; red[4 + w] = s2; }
  __syncthreads();
  s = red[0] + red[1] + red[2] + red[3];
  s2 = red[4] + red[5] + red[6] + red[7];
  const float mean = s * (1.0f / 1024.0f);
  const float var = s2 * (1.0f / 1024.0f) - mean * mean;
  const float rstd = rsqrtf(var + 1e-6f);
  float4 g4 = ((const float4*)gamma)[t];
  float4 b4 = ((const float4*)beta)[t];
  union { ushort h[4]; uint2 u; } o;
  o.h[0] = f2bf_bits(g4.x * (x.x - mean) * rstd + b4.x);
  o.h[1] = f2bf_bits(g4.y * (x.y - mean) * rstd + b4.y);
  o.h[2] = f2bf_bits(g4.z * (x.z - mean) * rstd + b4.z);
  o.h[3] = f2bf_bits(g4.w * (x.w - mean) * rstd + b4.w);
  ((uint2*)(xn_out + row * 1024))[t] = o.u;
}

// ---------------- GEMM: C(MxN) = A(MxK,bf16) * Bt(NxK,bf16)^T ----------------
// 128x128 tile, BK=64, 4 waves. R13: A ring-3 (depth-2 prefetch) + B dbuf,
// counted vmcnt by FIFO trace: per iter issue B(k+1) then A(k+2);
//   k < nt-2: vmcnt(12)  (allow A(k+1),B(k+1),A(k+2) in flight)
//   k = nt-2: vmcnt(8)   (allow A(k+1),B(k+1))
//   k = nt-1: vmcnt(0)
// Barrier pair per iter identical to R11. LDS 80KB -> 2 blocks/CU.
// Swizzled layout: elem (r, g*8+e) at byte r*128 + (g*16 ^ ((r&7)<<4)) + e*2,
// staged linearly via pre-swizzled global source colgroup (t&7)^((t>>3)&7).
// EPI: 0 = bf16; 2 = +bias sigmoid-GELU bf16; 4 = raw f32 partial;
//      5 = split-K partial, sl0 adds bias+res.
template <int EPI, int KSPLIT>
__global__ __launch_bounds__(256) void gemm_bt(
    const bf16* __restrict__ A, const bf16* __restrict__ Bt,
    const int M, const int N, const int K, const int lda, const int ldb,
    const float* __restrict__ bias, const float* __restrict__ res,
    float* __restrict__ pother, void* __restrict__ Cout) {
  __shared__ __align__(16) char gsmem[81920];  // A ring: 3x16K; B dbuf: 2x16K at +49152
  const int t = threadIdx.x;
  const int w = t >> 6, l = t & 63;
  const int nb = N >> 7;
  const int cpx = gridDim.x >> 3;
  int bidx = (blockIdx.x & 7) * cpx + (blockIdx.x >> 3);
  int sl = 0;
  if (KSPLIT == 2) {
    const int half = gridDim.x >> 1;
    sl = bidx >= half;
    bidx -= sl * half;
  }
  const int bm = bidx / nb, bn = bidx % nb;
  const long row0 = (long)bm << 7, col0 = (long)bn << 7;
  const int wr = (w >> 1) << 6, wc = (w & 1) << 6;
  const int lr = l & 15;
  const int lkb = (l >> 4) << 4;

  f32x4 acc[4][4];
#pragma unroll
  for (int m = 0; m < 4; ++m)
#pragma unroll
    for (int n = 0; n < 4; ++n) acc[m][n] = (f32x4){0.f, 0.f, 0.f, 0.f};

  const int rA = t >> 3;
  const int g = (t & 7) ^ ((t >> 3) & 7);
  const bf16* gA = A + (row0 + rA) * (long)lda + (long)sl * K + g * 8;
  const bf16* gB = Bt + (col0 + rA) * (long)ldb + (long)sl * K + g * 8;
  char* const Bbase = gsmem + 49152;

  const int nt = K >> 6;
  // prologue (FIFO order: A0, B0, A1)
#pragma unroll
  for (int cr = 0; cr < 4; ++cr)
    async_copy16(gA + (long)cr * 32 * lda, gsmem + t * 16 + cr * 4096);
#pragma unroll
  for (int cr = 0; cr < 4; ++cr)
    async_copy16(gB + (long)cr * 32 * ldb, Bbase + t * 16 + cr * 4096);
#pragma unroll
  for (int cr = 0; cr < 4; ++cr)
    async_copy16(gA + (long)cr * 32 * lda + 64, gsmem + 16384 + t * 16 + cr * 4096);
  int curB = 0;

  for (int kt = 0; kt < nt; ++kt) {
    // issue next B (depth-1) then next-next A (depth-2)
    if (kt + 1 < nt) {
      const int k1 = (kt + 1) << 6;
      char* dstB = Bbase + (curB ^ 1) * 16384;
#pragma unroll
      for (int cr = 0; cr < 4; ++cr)
        async_copy16(gB + (long)cr * 32 * ldb + k1, dstB + t * 16 + cr * 4096);
    }
    if (kt + 2 < nt) {
      const int k2 = (kt + 2) << 6;
      char* dstA = gsmem + ((kt + 2) % 3) * 16384;
#pragma unroll
      for (int cr = 0; cr < 4; ++cr)
        async_copy16(gA + (long)cr * 32 * lda + k2, dstA + t * 16 + cr * 4096);
    }
    if (kt < nt - 2) {
      asm volatile("s_waitcnt vmcnt(12)" ::: "memory");
    } else if (kt == nt - 2) {
      asm volatile("s_waitcnt vmcnt(8)" ::: "memory");
    } else {
      asm volatile("s_waitcnt vmcnt(0)" ::: "memory");
    }
    __builtin_amdgcn_s_barrier();
    __builtin_amdgcn_sched_barrier(0);
    const char* As = gsmem + (kt % 3) * 16384;
    const char* Bs = Bbase + curB * 16384;
#pragma unroll
    for (int ks = 0; ks < 2; ++ks) {
      bf16x8 af[4], bfr[4];
#pragma unroll
      for (int m = 0; m < 4; ++m) {
        const int row = wr + m * 16 + lr;
        af[m] = *(const bf16x8*)(As +
            (row * 128 + ((ks * 64 + lkb) ^ ((row & 7) << 4))));
      }
#pragma unroll
      for (int n = 0; n < 4; ++n) {
        const int row = wc + n * 16 + lr;
        bfr[n] = *(const bf16x8*)(Bs +
            (row * 128 + ((ks * 64 + lkb) ^ ((row & 7) << 4))));
      }
#pragma unroll
      for (int m = 0; m < 4; ++m)
#pragma unroll
        for (int n = 0; n < 4; ++n)
          acc[m][n] = __builtin_amdgcn_mfma_f32_16x16x32_bf16(af[m], bfr[n], acc[m][n], 0, 0, 0);
    }
    __builtin_amdgcn_sched_barrier(0);
    __builtin_amdgcn_s_barrier();
    curB ^= 1;
  }

  bf16* Cb = (bf16*)Cout;
  float* Cf = (float*)Cout;
  if ((EPI == 4 || EPI == 5) && sl == 1) Cf = pother;
#pragma unroll
  for (int m = 0; m < 4; ++m) {
#pragma unroll
    for (int r = 0; r < 4; ++r) {
      const long crow = row0 + wr + m * 16 + ((l >> 4) << 2) + r;
      const long rbase = crow * N;
#pragma unroll
      for (int n = 0; n < 4; ++n) {
        const long ccol = col0 + wc + n * 16 + lr;
        float v = acc[m][n][r];
        if (EPI == 2) {
          const float vv = v + bias[ccol];
          const float u2 = vv * (1.5957691216f + 0.0713548162f * vv * vv);
          v = vv / (1.0f + __expf(-u2));
        }
        if (EPI == 5 && sl == 0) v += bias[ccol] + res[rbase + ccol];
        if (EPI == 0 || EPI == 2)
          Cb[rbase + ccol] = __float2bfloat16(v);
        else
          Cf[rbase + ccol] = v;
      }
    }
  }
}

// ---- split-K reduce: out = p0 + p1 (p0 already holds bias+residual) ----
__global__ __launch_bounds__(256) void ff2_reduce(
    const float* __restrict__ p0, const float* __restrict__ p1,
    float* __restrict__ out) {
  const int idx = blockIdx.x * 256 + threadIdx.x;
  const float4 x = ((const float4*)p0)[idx];
  const float4 y = ((const float4*)p1)[idx];
  float4 a;
  a.x = x.x + y.x; a.y = x.y + y.y; a.z = x.z + y.z; a.w = x.w + y.w;
  ((float4*)out)[idx] = a;
}

// ---------------- flash attention: 8 waves, 256 q-rows, KVBLK=128 ------------
// T5 setprio around MFMA clusters; T13 defer-rescale THR=8. (R10-proven.)
__global__ __launch_bounds__(512) void attn_kernel(
    const bf16* __restrict__ QKV, const int* __restrict__ pmask,
    bf16* __restrict__ Oout) {
  const int bh = blockIdx.x;
  const int b = bh >> 4, h = bh & 15;
  const int q0 = blockIdx.y << 8;
  const int t = threadIdx.x;
  const int w = t >> 6, l = t & 63;
  const int lq = l & 31, hi = l >> 5;

  __shared__ __align__(16) char smem[65536];

  const long base = (long)b * 2048 * 3072;
  const bf16* Qg = QKV + base + h * 64;
  const bf16* Kg = QKV + base + 1024 + h * 64;
  const bf16* Vg = QKV + base + 2048 + h * 64;

  int kSrc[2], kDst[2], vk[2], vsg[2];
#pragma unroll
  for (int p = 0; p < 2; ++p) {
    const int c = p * 512 + t;
    const int kr = c >> 3;
    kSrc[p] = kr * 3072 + (((c & 7) ^ (kr & 7)) << 3);
    kDst[p] = c * 16;
    vk[p] = c >> 3;
    vsg[p] = c & 7;
  }

  const int qw0 = q0 + w * 32;
  bf16x8 qf[4];
#pragma unroll
  for (int dc = 0; dc < 4; ++dc) {
    uint4 raw = *(const uint4*)(Qg + (long)(qw0 + lq) * 3072 + dc * 16 + hi * 8);
    union { uint4 u4; ushort us[8]; } in; in.u4 = raw;
    union { bf16x8 v; ushort us[8]; } o;
#pragma unroll
    for (int e = 0; e < 8; ++e) o.us[e] = f2bf_bits(0.125f * bfbits2f(in.us[e]));
    qf[dc] = o.v;
  }

  union { unsigned int u[4]; bf16x8 v; } bones;
  bones.u[0] = (hi == 0) ? 0x00003F80u : 0u;
  bones.u[1] = bones.u[2] = bones.u[3] = 0u;

  uint4 vreg[2];
#pragma unroll
  for (int p = 0; p < 2; ++p) {
    vreg[p] = *(const uint4*)(Vg + (long)vk[p] * 3072 + vsg[p] * 8);
    async_copy16(Kg + kSrc[p], smem + kDst[p]);
  }
#pragma unroll
  for (int p = 0; p < 2; ++p) {
    const ushort* vs = (const ushort*)&vreg[p];
#pragma unroll
    for (int e = 0; e < 8; ++e) {
      const int d = vsg[p] * 8 + e;
      *(ushort*)(smem + 32768 + d * 256 +
                 ((vk[p] * 2) ^ (((e ^ vsg[p]) & 7) << 4))) = vs[e];
    }
  }

  f32x16 oacc[2];
#pragma unroll
  for (int nt = 0; nt < 2; ++nt)
#pragma unroll
    for (int r = 0; r < 16; ++r) oacc[nt][r] = 0.f;
  float mrun = -3.0e38f, lsum = 0.f;
  int cur = 0;

  __syncthreads();

  for (int ktg = 0; ktg < 16; ++ktg) {
    if (ktg < 15) {
      const long nrow0 = (long)(ktg + 1) * 128 * 3072;
#pragma unroll
      for (int p = 0; p < 2; ++p) {
        vreg[p] = *(const uint4*)(Vg + nrow0 + (long)vk[p] * 3072 + vsg[p] * 8);
        async_copy16(Kg + nrow0 + kSrc[p], smem + (cur ^ 1) * 16384 + kDst[p]);
      }
    }
    const int k0 = ktg << 7;
    const char* Ks = smem + cur * 16384;
    const char* Vt = smem + 32768 + cur * 16384;

    f32x16 sacc[4];
    __builtin_amdgcn_s_setprio(1);
#pragma unroll
    for (int kt = 0; kt < 4; ++kt) {
#pragma unroll
      for (int r = 0; r < 16; ++r) sacc[kt][r] = 0.f;
#pragma unroll
      for (int dc = 0; dc < 4; ++dc) {
        bf16x8 ka = *(const bf16x8*)(Ks +
            ((kt * 32 + lq) * 128 + ((dc * 32 + hi * 16) ^ ((lq & 7) << 4))));
        sacc[kt] = __builtin_amdgcn_mfma_f32_32x32x16_bf16(ka, qf[dc], sacc[kt], 0, 0, 0);
      }
      const int mv = pmask[b * 2048 + k0 + kt * 32 + lq];
      union { unsigned int u[4]; bf16x8 v; } aadd;
      aadd.u[0] = (hi == 0 && mv == 0) ? (unsigned int)f2bf_bits(-1.0e9f) : 0u;
      aadd.u[1] = aadd.u[2] = aadd.u[3] = 0u;
      sacc[kt] = __builtin_amdgcn_mfma_f32_32x32x16_bf16(aadd.v, bones.v, sacc[kt], 0, 0, 0);
    }
    __builtin_amdgcn_s_setprio(0);

    float tmax = -3.0e38f;
#pragma unroll
    for (int kt = 0; kt < 4; ++kt)
#pragma unroll
      for (int r = 0; r < 16; ++r) tmax = fmaxf(tmax, sacc[kt][r]);
    tmax = fmaxf(tmax, __shfl_xor(tmax, 32));
    const bool need = (bool)__any(tmax > mrun + 8.0f);
    const float mnew = need ? fmaxf(mrun, tmax) : mrun;
    float psum = 0.f;
#pragma unroll
    for (int kt = 0; kt < 4; ++kt)
#pragma unroll
      for (int r = 0; r < 16; ++r) {
        const float p = __expf(sacc[kt][r] - mnew);
        sacc[kt][r] = p;
        psum += p;
      }
    psum += __shfl_xor(psum, 32);
    if (need) {
      const float alpha = __expf(mrun - mnew);
      mrun = mnew;
      lsum = lsum * alpha + psum;
#pragma unroll
      for (int r = 0; r < 16; ++r) {
        const float ar = __shfl(alpha, (r & 3) + 8 * (r >> 2) + 4 * hi);
        oacc[0][r] *= ar;
        oacc[1][r] *= ar;
      }
    } else {
      lsum += psum;
    }

    union { unsigned int u[4]; bf16x8 v; } paE[4], paO[4];
#pragma unroll
    for (int kt = 0; kt < 4; ++kt) {
      const unsigned int cs0 = pk2(sacc[kt][0], sacc[kt][1]);
      const unsigned int cs1 = pk2(sacc[kt][2], sacc[kt][3]);
      const unsigned int cs2 = pk2(sacc[kt][4], sacc[kt][5]);
      const unsigned int cs3 = pk2(sacc[kt][6], sacc[kt][7]);
      const unsigned int cs4 = pk2(sacc[kt][8], sacc[kt][9]);
      const unsigned int cs5 = pk2(sacc[kt][10], sacc[kt][11]);
      const unsigned int cs6 = pk2(sacc[kt][12], sacc[kt][13]);
      const unsigned int cs7 = pk2(sacc[kt][14], sacc[kt][15]);
      const unsigned int es0 = __shfl_xor(cs0, 32);
      const unsigned int es1 = __shfl_xor(cs1, 32);
      const unsigned int es2 = __shfl_xor(cs2, 32);
      const unsigned int es3 = __shfl_xor(cs3, 32);
      const unsigned int es4 = __shfl_xor(cs4, 32);
      const unsigned int es5 = __shfl_xor(cs5, 32);
      const unsigned int es6 = __shfl_xor(cs6, 32);
      const unsigned int es7 = __shfl_xor(cs7, 32);
      paE[kt].u[0] = hi ? es2 : cs0;
      paE[kt].u[1] = hi ? es3 : cs1;
      paE[kt].u[2] = hi ? cs2 : es0;
      paE[kt].u[3] = hi ? cs3 : es1;
      paO[kt].u[0] = hi ? es6 : cs4;
      paO[kt].u[1] = hi ? es7 : cs5;
      paO[kt].u[2] = hi ? cs6 : es4;
      paO[kt].u[3] = hi ? cs7 : es5;
    }

    __builtin_amdgcn_s_setprio(1);
#pragma unroll
    for (int kt = 0; kt < 4; ++kt)
#pragma unroll
      for (int nt = 0; nt < 2; ++nt) {
        const int vrow = nt * 32 + lq;
        const int vsw = ((vrow & 7) ^ ((vrow >> 3) & 7)) << 4;
        bf16x8 vbE = *(const bf16x8*)(Vt + (vrow * 256 + ((kt * 64 + hi * 16) ^ vsw)));
        oacc[nt] = __builtin_amdgcn_mfma_f32_32x32x16_bf16(paE[kt].v, vbE, oacc[nt], 0, 0, 0);
        bf16x8 vbO = *(const bf16x8*)(Vt + (vrow * 256 + ((kt * 64 + 32 + hi * 16) ^ vsw)));
        oacc[nt] = __builtin_amdgcn_mfma_f32_32x32x16_bf16(paO[kt].v, vbO, oacc[nt], 0, 0, 0);
      }
    __builtin_amdgcn_s_setprio(0);

    if (ktg < 15) {
      char* VtN = smem + 32768 + (cur ^ 1) * 16384;
#pragma unroll
      for (int p = 0; p < 2; ++p) {
        const ushort* vs = (const ushort*)&vreg[p];
#pragma unroll
        for (int e = 0; e < 8; ++e) {
          const int d = vsg[p] * 8 + e;
          *(ushort*)(VtN + d * 256 +
                     ((vk[p] * 2) ^ (((e ^ vsg[p]) & 7) << 4))) = vs[e];
        }
      }
    }

    __syncthreads();
    cur ^= 1;
  }

  const float inv = 1.0f / lsum;
#pragma unroll
  for (int r = 0; r < 16; ++r) {
    const int crow = (r & 3) + 8 * (r >> 2) + 4 * hi;
    const float ir = __shfl(inv, crow);
    const long orow = (long)b * 2048 + qw0 + crow;
#pragma unroll
    for (int nt = 0; nt < 2; ++nt)
      Oout[orow * 1024 + h * 64 + nt * 32 + lq] = __float2bfloat16(oacc[nt][r] * ir);
  }
}

extern "C" void kernel_launch(void* const* d_in, const int* in_sizes, int n_in,
                              void* d_out, int out_size, void* d_ws, size_t ws_size,
                              hipStream_t stream) {
  const float* X = (const float*)d_in[0];
  const int* pmask = (const int*)d_in[1];
  const float* W_Q = (const float*)d_in[2];
  const float* W_K = (const float*)d_in[3];
  const float* W_V = (const float*)d_in[4];
  const float* W_O = (const float*)d_in[5];
  const float* g1 = (const float*)d_in[6];
  const float* b1 = (const float*)d_in[7];
  const float* W1 = (const float*)d_in[8];
  const float* bias1 = (const float*)d_in[9];
  const float* W2 = (const float*)d_in[10];
  const float* bias2 = (const float*)d_in[11];
  const float* g2 = (const float*)d_in[12];
  const float* b2 = (const float*)d_in[13];
  (void)in_sizes; (void)n_in; (void)out_size; (void)ws_size;

  char* ws = (char*)d_ws;
  const size_t MB = 1ull << 20;
  bf16* W1_t   = (bf16*)(ws + 0);
  bf16* Wqkv_t = (bf16*)(ws + 8 * MB);
  bf16* Wo_t   = (bf16*)(ws + 14 * MB);
  bf16* W2_t   = (bf16*)(ws + 16 * MB);
  bf16* xn     = (bf16*)(ws + 24 * MB);
  bf16* QKV    = (bf16*)(ws + 32 * MB);
  bf16* attnb  = (bf16*)(ws + 56 * MB);
  bf16* ff1    = (bf16*)(ws + 32 * MB);
  float* p0o   = (float*)(ws + 64 * MB);
  float* p1o   = (float*)(ws + 32 * MB);
  float* p0    = (float*)(ws + 64 * MB);
  float* p1    = (float*)(ws + 0);
  float* res1  = (float*)d_out;

  transpose_all_ln<<<16384, 256, 0, stream>>>(W_Q, W_K, W_V, W_O, W1, W2,
                                              Wqkv_t, W1_t, W2_t,
                                              X, g1, b1, xn);
  gemm_bt<0, 1><<<32 * 24, 256, 0, stream>>>(xn, Wqkv_t, 4096, 3072, 1024, 1024, 1024,
                                             nullptr, nullptr, nullptr, QKV);
  attn_kernel<<<dim3(32, 8), 512, 0, stream>>>(QKV, pmask, attnb);
  gemm_bt<4, 2><<<2 * 32 * 8, 256, 0, stream>>>(attnb, Wo_t, 4096, 1024, 512, 1024, 1024,
                                                nullptr, nullptr, p1o, p0o);
  oproj_reduce_ln<<<4096, 256, 0, stream>>>(p0o, p1o, X, g2, b2, res1, xn);
  gemm_bt<2, 1><<<32 * 32, 256, 0, stream>>>(xn, W1_t, 4096, 4096, 1024, 1024, 1024,
                                             bias1, nullptr, nullptr, ff1);
  gemm_bt<5, 2><<<2 * 32 * 8, 256, 0, stream>>>(ff1, W2_t, 4096, 1024, 2048, 4096, 4096,
                                                bias2, res1, p1, p0);
  ff2_reduce<<<4096, 256, 0, stream>>>(p0, p1, res1);
}

// Round 14
// 259.499 us; speedup vs baseline: 1.2476x; 1.0178x over previous
//
#include <hip/hip_runtime.h>
#include <hip/hip_bf16.h>

// EncoderLayer on MI355X (gfx950).
// B=2, S=2048, D=1024, H=16, DK=64. M = B*S = 4096.
// R14: attention P-exchange via v_permlane32_swap_b32 (T12, m255: 1.20x vs
//      ds_bpermute): one swap yields BOTH A-frag words (paE.u[0]&u[2]) ->
//      per tile -32 ds_bpermute -32 cndmask, +16 permlane. Everything else
//      identical to R13 (depth-2 A-ring GEMM, T5+T13 attn, fused reduces).

using bf16 = __hip_bfloat16;
typedef __attribute__((ext_vector_type(4))) float f32x4;
typedef __attribute__((ext_vector_type(16))) float f32x16;
typedef __attribute__((ext_vector_type(8))) short bf16x8;

#define DEVI static __device__ __forceinline__

DEVI void async_copy16(const void* g, void* l) {
  __builtin_amdgcn_global_load_lds(
      (const __attribute__((address_space(1))) void*)g,
      (__attribute__((address_space(3))) void*)l, 16, 0, 0);
}

DEVI ushort f2bf_bits(float v) {
  __hip_bfloat16 h = __float2bfloat16(v);
  return *reinterpret_cast<ushort*>(&h);
}

DEVI float bfbits2f(ushort u) {
  union { float f; unsigned int i; } x;
  x.i = ((unsigned int)u) << 16;
  return x.f;
}

DEVI unsigned int pk2(float lo, float hi) {
  return (unsigned int)f2bf_bits(lo) | ((unsigned int)f2bf_bits(hi) << 16);
}

// ---- merged: weight transposes (blocks 0..12287) + LN1 (blocks 12288+) ----
__global__ __launch_bounds__(256) void transpose_all_ln(
    const float* __restrict__ q, const float* __restrict__ k,
    const float* __restrict__ v, const float* __restrict__ o,
    const float* __restrict__ w1, const float* __restrict__ w2,
    bf16* __restrict__ wqkvo, bf16* __restrict__ w1t, bf16* __restrict__ w2t,
    const float* __restrict__ X, const float* __restrict__ g1,
    const float* __restrict__ b1, bf16* __restrict__ xn) {
  const int tid = blockIdx.x;
  if (tid >= 12288) {
    const long row = tid - 12288;
    const int t = threadIdx.x;
    float4 x = ((const float4*)(X + row * 1024))[t];
    float s = x.x + x.y + x.z + x.w;
    float s2 = x.x * x.x + x.y * x.y + x.z * x.z + x.w * x.w;
#pragma unroll
    for (int m = 1; m < 64; m <<= 1) {
      s += __shfl_xor(s, m);
      s2 += __shfl_xor(s2, m);
    }
    __shared__ float red[8];
    const int w = t >> 6, l = t & 63;
    if (l == 0) { red[w] = s; red[4 + w] = s2; }
    __syncthreads();
    s = red[0] + red[1] + red[2] + red[3];
    s2 = red[4] + red[5] + red[6] + red[7];
    const float mean = s * (1.0f / 1024.0f);
    const float var = s2 * (1.0f / 1024.0f) - mean * mean;
    const float rstd = rsqrtf(var + 1e-6f);
    float4 g4 = ((const float4*)g1)[t];
    float4 b4 = ((const float4*)b1)[t];
    union { ushort h[4]; uint2 u; } oo;
    oo.h[0] = f2bf_bits(g4.x * (x.x - mean) * rstd + b4.x);
    oo.h[1] = f2bf_bits(g4.y * (x.y - mean) * rstd + b4.y);
    oo.h[2] = f2bf_bits(g4.z * (x.z - mean) * rstd + b4.z);
    oo.h[3] = f2bf_bits(g4.w * (x.w - mean) * rstd + b4.w);
    ((uint2*)(xn + row * 1024))[t] = oo.u;
    return;
  }
  const float* W;
  bf16* Wt;
  int K, N, n0, k0;
  if (tid < 4096) {
    const int z = tid >> 10, r = tid & 1023;
    W = (z == 0) ? q : (z == 1) ? k : (z == 2) ? v : o;
    Wt = wqkvo + (size_t)z * 1024 * 1024;
    K = 1024; N = 1024; n0 = (r & 31) << 5; k0 = (r >> 5) << 5;
  } else if (tid < 8192) {
    const int r = tid - 4096;
    W = w1; Wt = w1t; K = 1024; N = 4096;
    n0 = (r & 127) << 5; k0 = (r >> 7) << 5;
  } else {
    const int r = tid - 8192;
    W = w2; Wt = w2t; K = 4096; N = 1024;
    n0 = (r & 31) << 5; k0 = (r >> 5) << 5;
  }
  __shared__ float tile[32][33];
  const int tx = threadIdx.x & 31, ty = threadIdx.x >> 5;
#pragma unroll
  for (int i = 0; i < 32; i += 8)
    tile[ty + i][tx] = W[(long)(k0 + ty + i) * N + n0 + tx];
  __syncthreads();
#pragma unroll
  for (int i = 0; i < 32; i += 8)
    Wt[(long)(n0 + ty + i) * K + k0 + tx] = __float2bfloat16(tile[tx][ty + i]);
}

// ---- O-proj split-K reduce fused with LN2: res = p0+p1+X; xn = LN(res) ----
__global__ __launch_bounds__(256) void oproj_reduce_ln(
    const float* __restrict__ p0, const float* __restrict__ p1,
    const float* __restrict__ X, const float* __restrict__ gamma,
    const float* __restrict__ beta, float* __restrict__ res_out,
    bf16* __restrict__ xn_out) {
  const long row = blockIdx.x;
  const int t = threadIdx.x;
  const long i = row * 256 + t;
  const float4 a = ((const float4*)p0)[i];
  const float4 b = ((const float4*)p1)[i];
  const float4 c = ((const float4*)X)[i];
  float4 x;
  x.x = a.x + b.x + c.x; x.y = a.y + b.y + c.y;
  x.z = a.z + b.z + c.z; x.w = a.w + b.w + c.w;
  ((float4*)res_out)[i] = x;
  float s = x.x + x.y + x.z + x.w;
  float s2 = x.x * x.x + x.y * x.y + x.z * x.z + x.w * x.w;
#pragma unroll
  for (int m = 1; m < 64; m <<= 1) {
    s += __shfl_xor(s, m);
    s2 += __shfl_xor(s2, m);
  }
  __shared__ float red[8];
  const int w = t >> 6, l = t & 63;
  if (l == 0) { red[w] = s; red[4 + w] = s2; }
  __syncthreads();
  s = red[0] + red[1] + red[2] + red[3];
  s2 = red[4] + red[5] + red[6] + red[7];
  const float mean = s * (1.0f / 1024.0f);
  const float var = s2 * (1.0f / 1024.0f) - mean * mean;
  const float rstd = rsqrtf(var + 1e-6f);
  float4 g4 = ((const float4*)gamma)[t];
  float4 b4 = ((const float4*)beta)[t];
  union { ushort h[4]; uint2 u; } o;
  o.h[0] = f2bf_bits(g4.x * (x.x - mean) * rstd + b4.x);
  o.h[1] = f2bf_bits(g4.y * (x.y - mean) * rstd + b4.y);
  o.h[2] = f2bf_bits(g4.z * (x.z - mean) * rstd + b4.z);
  o.h[3] = f2bf_bits(g4.w * (x.w - mean) * rstd + b4.w);
  ((uint2*)(xn_out + row * 1024))[t] = o.u;
}

// ---------------- GEMM: C(MxN) = A(MxK,bf16) * Bt(NxK,bf16)^T ----------------
// 128x128 tile, BK=64, 4 waves. A ring-3 (depth-2 prefetch) + B dbuf, counted
// vmcnt(12)/(8)/(0); barrier pair per iter. 80KB LDS (2 blocks/CU).
template <int EPI, int KSPLIT>
__global__ __launch_bounds__(256) void gemm_bt(
    const bf16* __restrict__ A, const bf16* __restrict__ Bt,
    const int M, const int N, const int K, const int lda, const int ldb,
    const float* __restrict__ bias, const float* __restrict__ res,
    float* __restrict__ pother, void* __restrict__ Cout) {
  __shared__ __align__(16) char gsmem[81920];
  const int t = threadIdx.x;
  const int w = t >> 6, l = t & 63;
  const int nb = N >> 7;
  const int cpx = gridDim.x >> 3;
  int bidx = (blockIdx.x & 7) * cpx + (blockIdx.x >> 3);
  int sl = 0;
  if (KSPLIT == 2) {
    const int half = gridDim.x >> 1;
    sl = bidx >= half;
    bidx -= sl * half;
  }
  const int bm = bidx / nb, bn = bidx % nb;
  const long row0 = (long)bm << 7, col0 = (long)bn << 7;
  const int wr = (w >> 1) << 6, wc = (w & 1) << 6;
  const int lr = l & 15;
  const int lkb = (l >> 4) << 4;

  f32x4 acc[4][4];
#pragma unroll
  for (int m = 0; m < 4; ++m)
#pragma unroll
    for (int n = 0; n < 4; ++n) acc[m][n] = (f32x4){0.f, 0.f, 0.f, 0.f};

  const int rA = t >> 3;
  const int g = (t & 7) ^ ((t >> 3) & 7);
  const bf16* gA = A + (row0 + rA) * (long)lda + (long)sl * K + g * 8;
  const bf16* gB = Bt + (col0 + rA) * (long)ldb + (long)sl * K + g * 8;
  char* const Bbase = gsmem + 49152;

  const int nt = K >> 6;
#pragma unroll
  for (int cr = 0; cr < 4; ++cr)
    async_copy16(gA + (long)cr * 32 * lda, gsmem + t * 16 + cr * 4096);
#pragma unroll
  for (int cr = 0; cr < 4; ++cr)
    async_copy16(gB + (long)cr * 32 * ldb, Bbase + t * 16 + cr * 4096);
#pragma unroll
  for (int cr = 0; cr < 4; ++cr)
    async_copy16(gA + (long)cr * 32 * lda + 64, gsmem + 16384 + t * 16 + cr * 4096);
  int curB = 0;

  for (int kt = 0; kt < nt; ++kt) {
    if (kt + 1 < nt) {
      const int k1 = (kt + 1) << 6;
      char* dstB = Bbase + (curB ^ 1) * 16384;
#pragma unroll
      for (int cr = 0; cr < 4; ++cr)
        async_copy16(gB + (long)cr * 32 * ldb + k1, dstB + t * 16 + cr * 4096);
    }
    if (kt + 2 < nt) {
      const int k2 = (kt + 2) << 6;
      char* dstA = gsmem + ((kt + 2) % 3) * 16384;
#pragma unroll
      for (int cr = 0; cr < 4; ++cr)
        async_copy16(gA + (long)cr * 32 * lda + k2, dstA + t * 16 + cr * 4096);
    }
    if (kt < nt - 2) {
      asm volatile("s_waitcnt vmcnt(12)" ::: "memory");
    } else if (kt == nt - 2) {
      asm volatile("s_waitcnt vmcnt(8)" ::: "memory");
    } else {
      asm volatile("s_waitcnt vmcnt(0)" ::: "memory");
    }
    __builtin_amdgcn_s_barrier();
    __builtin_amdgcn_sched_barrier(0);
    const char* As = gsmem + (kt % 3) * 16384;
    const char* Bs = Bbase + curB * 16384;
#pragma unroll
    for (int ks = 0; ks < 2; ++ks) {
      bf16x8 af[4], bfr[4];
#pragma unroll
      for (int m = 0; m < 4; ++m) {
        const int row = wr + m * 16 + lr;
        af[m] = *(const bf16x8*)(As +
            (row * 128 + ((ks * 64 + lkb) ^ ((row & 7) << 4))));
      }
#pragma unroll
      for (int n = 0; n < 4; ++n) {
        const int row = wc + n * 16 + lr;
        bfr[n] = *(const bf16x8*)(Bs +
            (row * 128 + ((ks * 64 + lkb) ^ ((row & 7) << 4))));
      }
#pragma unroll
      for (int m = 0; m < 4; ++m)
#pragma unroll
        for (int n = 0; n < 4; ++n)
          acc[m][n] = __builtin_amdgcn_mfma_f32_16x16x32_bf16(af[m], bfr[n], acc[m][n], 0, 0, 0);
    }
    __builtin_amdgcn_sched_barrier(0);
    __builtin_amdgcn_s_barrier();
    curB ^= 1;
  }

  bf16* Cb = (bf16*)Cout;
  float* Cf = (float*)Cout;
  if ((EPI == 4 || EPI == 5) && sl == 1) Cf = pother;
#pragma unroll
  for (int m = 0; m < 4; ++m) {
#pragma unroll
    for (int r = 0; r < 4; ++r) {
      const long crow = row0 + wr + m * 16 + ((l >> 4) << 2) + r;
      const long rbase = crow * N;
#pragma unroll
      for (int n = 0; n < 4; ++n) {
        const long ccol = col0 + wc + n * 16 + lr;
        float v = acc[m][n][r];
        if (EPI == 2) {
          const float vv = v + bias[ccol];
          const float u2 = vv * (1.5957691216f + 0.0713548162f * vv * vv);
          v = vv / (1.0f + __expf(-u2));
        }
        if (EPI == 5 && sl == 0) v += bias[ccol] + res[rbase + ccol];
        if (EPI == 0 || EPI == 2)
          Cb[rbase + ccol] = __float2bfloat16(v);
        else
          Cf[rbase + ccol] = v;
      }
    }
  }
}

// ---- split-K reduce: out = p0 + p1 (p0 already holds bias+residual) ----
__global__ __launch_bounds__(256) void ff2_reduce(
    const float* __restrict__ p0, const float* __restrict__ p1,
    float* __restrict__ out) {
  const int idx = blockIdx.x * 256 + threadIdx.x;
  const float4 x = ((const float4*)p0)[idx];
  const float4 y = ((const float4*)p1)[idx];
  float4 a;
  a.x = x.x + y.x; a.y = x.y + y.y; a.z = x.z + y.z; a.w = x.w + y.w;
  ((float4*)out)[idx] = a;
}

// ---------------- flash attention: 8 waves, 256 q-rows, KVBLK=128 ------------
// T5 setprio; T13 defer-rescale; R14: permlane32_swap P-exchange (T12).
__global__ __launch_bounds__(512) void attn_kernel(
    const bf16* __restrict__ QKV, const int* __restrict__ pmask,
    bf16* __restrict__ Oout) {
  const int bh = blockIdx.x;
  const int b = bh >> 4, h = bh & 15;
  const int q0 = blockIdx.y << 8;
  const int t = threadIdx.x;
  const int w = t >> 6, l = t & 63;
  const int lq = l & 31, hi = l >> 5;

  __shared__ __align__(16) char smem[65536];

  const long base = (long)b * 2048 * 3072;
  const bf16* Qg = QKV + base + h * 64;
  const bf16* Kg = QKV + base + 1024 + h * 64;
  const bf16* Vg = QKV + base + 2048 + h * 64;

  int kSrc[2], kDst[2], vk[2], vsg[2];
#pragma unroll
  for (int p = 0; p < 2; ++p) {
    const int c = p * 512 + t;
    const int kr = c >> 3;
    kSrc[p] = kr * 3072 + (((c & 7) ^ (kr & 7)) << 3);
    kDst[p] = c * 16;
    vk[p] = c >> 3;
    vsg[p] = c & 7;
  }

  const int qw0 = q0 + w * 32;
  bf16x8 qf[4];
#pragma unroll
  for (int dc = 0; dc < 4; ++dc) {
    uint4 raw = *(const uint4*)(Qg + (long)(qw0 + lq) * 3072 + dc * 16 + hi * 8);
    union { uint4 u4; ushort us[8]; } in; in.u4 = raw;
    union { bf16x8 v; ushort us[8]; } o;
#pragma unroll
    for (int e = 0; e < 8; ++e) o.us[e] = f2bf_bits(0.125f * bfbits2f(in.us[e]));
    qf[dc] = o.v;
  }

  union { unsigned int u[4]; bf16x8 v; } bones;
  bones.u[0] = (hi == 0) ? 0x00003F80u : 0u;
  bones.u[1] = bones.u[2] = bones.u[3] = 0u;

  uint4 vreg[2];
#pragma unroll
  for (int p = 0; p < 2; ++p) {
    vreg[p] = *(const uint4*)(Vg + (long)vk[p] * 3072 + vsg[p] * 8);
    async_copy16(Kg + kSrc[p], smem + kDst[p]);
  }
#pragma unroll
  for (int p = 0; p < 2; ++p) {
    const ushort* vs = (const ushort*)&vreg[p];
#pragma unroll
    for (int e = 0; e < 8; ++e) {
      const int d = vsg[p] * 8 + e;
      *(ushort*)(smem + 32768 + d * 256 +
                 ((vk[p] * 2) ^ (((e ^ vsg[p]) & 7) << 4))) = vs[e];
    }
  }

  f32x16 oacc[2];
#pragma unroll
  for (int nt = 0; nt < 2; ++nt)
#pragma unroll
    for (int r = 0; r < 16; ++r) oacc[nt][r] = 0.f;
  float mrun = -3.0e38f, lsum = 0.f;
  int cur = 0;

  __syncthreads();

  for (int ktg = 0; ktg < 16; ++ktg) {
    if (ktg < 15) {
      const long nrow0 = (long)(ktg + 1) * 128 * 3072;
#pragma unroll
      for (int p = 0; p < 2; ++p) {
        vreg[p] = *(const uint4*)(Vg + nrow0 + (long)vk[p] * 3072 + vsg[p] * 8);
        async_copy16(Kg + nrow0 + kSrc[p], smem + (cur ^ 1) * 16384 + kDst[p]);
      }
    }
    const int k0 = ktg << 7;
    const char* Ks = smem + cur * 16384;
    const char* Vt = smem + 32768 + cur * 16384;

    f32x16 sacc[4];
    __builtin_amdgcn_s_setprio(1);
#pragma unroll
    for (int kt = 0; kt < 4; ++kt) {
#pragma unroll
      for (int r = 0; r < 16; ++r) sacc[kt][r] = 0.f;
#pragma unroll
      for (int dc = 0; dc < 4; ++dc) {
        bf16x8 ka = *(const bf16x8*)(Ks +
            ((kt * 32 + lq) * 128 + ((dc * 32 + hi * 16) ^ ((lq & 7) << 4))));
        sacc[kt] = __builtin_amdgcn_mfma_f32_32x32x16_bf16(ka, qf[dc], sacc[kt], 0, 0, 0);
      }
      const int mv = pmask[b * 2048 + k0 + kt * 32 + lq];
      union { unsigned int u[4]; bf16x8 v; } aadd;
      aadd.u[0] = (hi == 0 && mv == 0) ? (unsigned int)f2bf_bits(-1.0e9f) : 0u;
      aadd.u[1] = aadd.u[2] = aadd.u[3] = 0u;
      sacc[kt] = __builtin_amdgcn_mfma_f32_32x32x16_bf16(aadd.v, bones.v, sacc[kt], 0, 0, 0);
    }
    __builtin_amdgcn_s_setprio(0);

    float tmax = -3.0e38f;
#pragma unroll
    for (int kt = 0; kt < 4; ++kt)
#pragma unroll
      for (int r = 0; r < 16; ++r) tmax = fmaxf(tmax, sacc[kt][r]);
    tmax = fmaxf(tmax, __shfl_xor(tmax, 32));
    const bool need = (bool)__any(tmax > mrun + 8.0f);
    const float mnew = need ? fmaxf(mrun, tmax) : mrun;
    float psum = 0.f;
#pragma unroll
    for (int kt = 0; kt < 4; ++kt)
#pragma unroll
      for (int r = 0; r < 16; ++r) {
        const float p = __expf(sacc[kt][r] - mnew);
        sacc[kt][r] = p;
        psum += p;
      }
    psum += __shfl_xor(psum, 32);
    if (need) {
      const float alpha = __expf(mrun - mnew);
      mrun = mnew;
      lsum = lsum * alpha + psum;
#pragma unroll
      for (int r = 0; r < 16; ++r) {
        const float ar = __shfl(alpha, (r & 3) + 8 * (r >> 2) + 4 * hi);
        oacc[0][r] *= ar;
        oacc[1][r] *= ar;
      }
    } else {
      lsum += psum;
    }

    // ---- P -> bf16 A-fragments via pack + permlane32_swap (T12) ----
    // swap(c0,c2): c0' = [cs0.lo, cs2.lo] = paE.u[0];
    //              c2' = [cs0.hi, cs2.hi] = paE.u[2]  (one swap, two words)
    union { unsigned int u[4]; bf16x8 v; } paE[4], paO[4];
#pragma unroll
    for (int kt = 0; kt < 4; ++kt) {
      unsigned int c0 = pk2(sacc[kt][0], sacc[kt][1]);
      unsigned int c1 = pk2(sacc[kt][2], sacc[kt][3]);
      unsigned int c2 = pk2(sacc[kt][4], sacc[kt][5]);
      unsigned int c3 = pk2(sacc[kt][6], sacc[kt][7]);
      unsigned int c4 = pk2(sacc[kt][8], sacc[kt][9]);
      unsigned int c5 = pk2(sacc[kt][10], sacc[kt][11]);
      unsigned int c6 = pk2(sacc[kt][12], sacc[kt][13]);
      unsigned int c7 = pk2(sacc[kt][14], sacc[kt][15]);
      asm volatile("v_permlane32_swap_b32 %0, %1" : "+v"(c0), "+v"(c2));
      asm volatile("v_permlane32_swap_b32 %0, %1" : "+v"(c1), "+v"(c3));
      asm volatile("v_permlane32_swap_b32 %0, %1" : "+v"(c4), "+v"(c6));
      asm volatile("v_permlane32_swap_b32 %0, %1" : "+v"(c5), "+v"(c7));
      paE[kt].u[0] = c0; paE[kt].u[1] = c1; paE[kt].u[2] = c2; paE[kt].u[3] = c3;
      paO[kt].u[0] = c4; paO[kt].u[1] = c5; paO[kt].u[2] = c6; paO[kt].u[3] = c7;
    }

    __builtin_amdgcn_s_setprio(1);
#pragma unroll
    for (int kt = 0; kt < 4; ++kt)
#pragma unroll
      for (int nt = 0; nt < 2; ++nt) {
        const int vrow = nt * 32 + lq;
        const int vsw = ((vrow & 7) ^ ((vrow >> 3) & 7)) << 4;
        bf16x8 vbE = *(const bf16x8*)(Vt + (vrow * 256 + ((kt * 64 + hi * 16) ^ vsw)));
        oacc[nt] = __builtin_amdgcn_mfma_f32_32x32x16_bf16(paE[kt].v, vbE, oacc[nt], 0, 0, 0);
        bf16x8 vbO = *(const bf16x8*)(Vt + (vrow * 256 + ((kt * 64 + 32 + hi * 16) ^ vsw)));
        oacc[nt] = __builtin_amdgcn_mfma_f32_32x32x16_bf16(paO[kt].v, vbO, oacc[nt], 0, 0, 0);
      }
    __builtin_amdgcn_s_setprio(0);

    if (ktg < 15) {
      char* VtN = smem + 32768 + (cur ^ 1) * 16384;
#pragma unroll
      for (int p = 0; p < 2; ++p) {
        const ushort* vs = (const ushort*)&vreg[p];
#pragma unroll
        for (int e = 0; e < 8; ++e) {
          const int d = vsg[p] * 8 + e;
          *(ushort*)(VtN + d * 256 +
                     ((vk[p] * 2) ^ (((e ^ vsg[p]) & 7) << 4))) = vs[e];
        }
      }
    }

    __syncthreads();
    cur ^= 1;
  }

  const float inv = 1.0f / lsum;
#pragma unroll
  for (int r = 0; r < 16; ++r) {
    const int crow = (r & 3) + 8 * (r >> 2) + 4 * hi;
    const float ir = __shfl(inv, crow);
    const long orow = (long)b * 2048 + qw0 + crow;
#pragma unroll
    for (int nt = 0; nt < 2; ++nt)
      Oout[orow * 1024 + h * 64 + nt * 32 + lq] = __float2bfloat16(oacc[nt][r] * ir);
  }
}

extern "C" void kernel_launch(void* const* d_in, const int* in_sizes, int n_in,
                              void* d_out, int out_size, void* d_ws, size_t ws_size,
                              hipStream_t stream) {
  const float* X = (const float*)d_in[0];
  const int* pmask = (const int*)d_in[1];
  const float* W_Q = (const float*)d_in[2];
  const float* W_K = (const float*)d_in[3];
  const float* W_V = (const float*)d_in[4];
  const float* W_O = (const float*)d_in[5];
  const float* g1 = (const float*)d_in[6];
  const float* b1 = (const float*)d_in[7];
  const float* W1 = (const float*)d_in[8];
  const float* bias1 = (const float*)d_in[9];
  const float* W2 = (const float*)d_in[10];
  const float* bias2 = (const float*)d_in[11];
  const float* g2 = (const float*)d_in[12];
  const float* b2 = (const float*)d_in[13];
  (void)in_sizes; (void)n_in; (void)out_size; (void)ws_size;

  char* ws = (char*)d_ws;
  const size_t MB = 1ull << 20;
  bf16* W1_t   = (bf16*)(ws + 0);
  bf16* Wqkv_t = (bf16*)(ws + 8 * MB);
  bf16* Wo_t   = (bf16*)(ws + 14 * MB);
  bf16* W2_t   = (bf16*)(ws + 16 * MB);
  bf16* xn     = (bf16*)(ws + 24 * MB);
  bf16* QKV    = (bf16*)(ws + 32 * MB);
  bf16* attnb  = (bf16*)(ws + 56 * MB);
  bf16* ff1    = (bf16*)(ws + 32 * MB);
  float* p0o   = (float*)(ws + 64 * MB);
  float* p1o   = (float*)(ws + 32 * MB);
  float* p0    = (float*)(ws + 64 * MB);
  float* p1    = (float*)(ws + 0);
  float* res1  = (float*)d_out;

  transpose_all_ln<<<16384, 256, 0, stream>>>(W_Q, W_K, W_V, W_O, W1, W2,
                                              Wqkv_t, W1_t, W2_t,
                                              X, g1, b1, xn);
  gemm_bt<0, 1><<<32 * 24, 256, 0, stream>>>(xn, Wqkv_t, 4096, 3072, 1024, 1024, 1024,
                                             nullptr, nullptr, nullptr, QKV);
  attn_kernel<<<dim3(32, 8), 512, 0, stream>>>(QKV, pmask, attnb);
  gemm_bt<4, 2><<<2 * 32 * 8, 256, 0, stream>>>(attnb, Wo_t, 4096, 1024, 512, 1024, 1024,
                                                nullptr, nullptr, p1o, p0o);
  oproj_reduce_ln<<<4096, 256, 0, stream>>>(p0o, p1o, X, g2, b2, res1, xn);
  gemm_bt<2, 1><<<32 * 32, 256, 0, stream>>>(xn, W1_t, 4096, 4096, 1024, 1024, 1024,
                                             bias1, nullptr, nullptr, ff1);
  gemm_bt<5, 2><<<2 * 32 * 8, 256, 0, stream>>>(ff1, W2_t, 4096, 1024, 2048, 4096, 4096,
                                                bias2, res1, p1, p0);
  ff2_reduce<<<4096, 256, 0, stream>>>(p0, p1, res1);
}